// Round 1
// baseline (1654.409 us; speedup 1.0000x reference)
//
#include <hip/hip_runtime.h>
#include <math.h>

#define N_USER 50000
#define N_ITEM 100000
#define E_UI   1000000
#define E_UU   800000
#define NEG_SLOPE 0.2f

// ---------------- CSR build ----------------

__global__ void zero_i32(int* __restrict__ p, int n) {
  int i = blockIdx.x * blockDim.x + threadIdx.x;
  if (i < n) p[i] = 0;
}

__global__ void hist_kernel(const int* __restrict__ dst, int E, int* __restrict__ counts) {
  for (int i = blockIdx.x * blockDim.x + threadIdx.x; i < E; i += gridDim.x * blockDim.x)
    atomicAdd(&counts[dst[i]], 1);
}

// single-block exclusive scan: counts[0..n) -> row_ptr[0..n], cursor copy
__global__ __launch_bounds__(1024) void scan_kernel(const int* __restrict__ counts, int n,
                                                    int* __restrict__ row_ptr, int* __restrict__ cursor) {
  __shared__ int sums[1024];
  int t = threadIdx.x;
  int chunk = (n + 1023) >> 10;
  int b = t * chunk;
  int e = min(b + chunk, n);
  int s = 0;
  for (int i = b; i < e; ++i) s += counts[i];
  sums[t] = s;
  __syncthreads();
  for (int off = 1; off < 1024; off <<= 1) {
    int v = (t >= off) ? sums[t - off] : 0;
    __syncthreads();
    sums[t] += v;
    __syncthreads();
  }
  int prefix = (t == 0) ? 0 : sums[t - 1];
  for (int i = b; i < e; ++i) {
    row_ptr[i] = prefix;
    cursor[i] = prefix;
    prefix += counts[i];
  }
  if (t == 1023) row_ptr[n] = sums[1023];
}

__global__ void scatter_kernel(const int* __restrict__ src, const int* __restrict__ dst, int E,
                               int* __restrict__ cursor, int* __restrict__ col) {
  for (int i = blockIdx.x * blockDim.x + threadIdx.x; i < E; i += gridDim.x * blockDim.x) {
    int p = atomicAdd(&cursor[dst[i]], 1);
    col[p] = src[i];
  }
}

// ---------------- node GEMM: Y[N,64] = X[N,64] @ W[64,64] ----------------

__global__ __launch_bounds__(256) void gemm64(const float* __restrict__ X, const float* __restrict__ W,
                                              float* __restrict__ Y, int N) {
  __shared__ float Ws[64 * 64];
  for (int i = threadIdx.x; i < 64 * 64; i += 256) Ws[i] = W[i];
  __syncthreads();
  int c  = threadIdx.x & 63;
  int rs = threadIdx.x >> 6;  // 0..3
  int base = blockIdx.x * 64;
  for (int r0 = 0; r0 < 64; r0 += 4) {
    int row = base + r0 + rs;
    if (row < N) {
      float acc = 0.f;
      const float* xr = X + (size_t)row * 64;
      #pragma unroll
      for (int k = 0; k < 64; ++k) acc = fmaf(xr[k], Ws[k * 64 + c], acc);
      Y[(size_t)row * 64 + c] = acc;
    }
  }
}

// ---------------- GATv2 edge aggregation: one wave64 per dst node ----------------
// lane = feature dim; online softmax over incoming edges.

__global__ __launch_bounds__(256) void gat_kernel(const float* __restrict__ hs, const float* __restrict__ hd,
                                                  const int* __restrict__ row_ptr, const int* __restrict__ col,
                                                  const float* __restrict__ attn, const float* __restrict__ bias,
                                                  float* __restrict__ out, int Nd) {
  int wave = (blockIdx.x * blockDim.x + threadIdx.x) >> 6;
  int lane = threadIdx.x & 63;
  if (wave >= Nd) return;
  int node = wave;
  int s0 = row_ptr[node];
  int s1 = row_ptr[node + 1];
  float hd_l = hd[(size_t)node * 64 + lane];
  float a_l  = attn[lane];
  float b_l  = bias[lane];

  float m = -INFINITY, den = 0.f, num = 0.f;
  for (int e = s0; e < s1; ++e) {
    int s = col[e];
    float hs_l = hs[(size_t)s * 64 + lane];
    float pre = hs_l + hd_l;
    pre = pre > 0.f ? pre : NEG_SLOPE * pre;
    float v = pre * a_l;
    #pragma unroll
    for (int off = 1; off < 64; off <<= 1) v += __shfl_xor(v, off);
    float mn = fmaxf(m, v);
    float scale = __expf(m - mn);   // first iter: exp(-inf) = 0
    float p = __expf(v - mn);
    den = den * scale + p;
    num = num * scale + hs_l * p;
    m = mn;
  }
  // empty segment: num=0, den=0 -> 0/1e-9 + bias = bias (matches reference)
  out[(size_t)node * 64 + lane] = num / fmaxf(den, 1e-9f) + b_l;
}

// ---------------- final: out = [A|B] @ Wout + bout ----------------

__global__ __launch_bounds__(256) void final_kernel(const float* __restrict__ A, const float* __restrict__ B,
                                                    const float* __restrict__ W, const float* __restrict__ bias,
                                                    float* __restrict__ Y, int N) {
  __shared__ float Ws[128 * 64];  // 32 KiB
  for (int i = threadIdx.x; i < 128 * 64; i += 256) Ws[i] = W[i];
  __syncthreads();
  int c  = threadIdx.x & 63;
  int rs = threadIdx.x >> 6;
  int base = blockIdx.x * 64;
  for (int r0 = 0; r0 < 64; r0 += 4) {
    int row = base + r0 + rs;
    if (row < N) {
      float acc = bias[c];
      const float* ar = A + (size_t)row * 64;
      const float* br = B + (size_t)row * 64;
      #pragma unroll
      for (int k = 0; k < 64; ++k) acc = fmaf(ar[k], Ws[k * 64 + c], acc);
      #pragma unroll
      for (int k = 0; k < 64; ++k) acc = fmaf(br[k], Ws[(64 + k) * 64 + c], acc);
      Y[(size_t)row * 64 + c] = acc;
    }
  }
}

// ---------------- launch ----------------

extern "C" void kernel_launch(void* const* d_in, const int* in_sizes, int n_in,
                              void* d_out, int out_size, void* d_ws, size_t ws_size,
                              hipStream_t stream) {
  const float* h_user   = (const float*)d_in[0];
  const float* h_item   = (const float*)d_in[1];
  const int* rate_src   = (const int*)d_in[2];
  const int* rate_dst   = (const int*)d_in[3];
  const int* rb_src     = (const int*)d_in[4];
  const int* rb_dst     = (const int*)d_in[5];
  const int* link_src   = (const int*)d_in[6];
  const int* link_dst   = (const int*)d_in[7];
  const float* w_src_r1  = (const float*)d_in[8];
  const float* w_dst_r1  = (const float*)d_in[9];
  const float* a_r1      = (const float*)d_in[10];
  const float* b_r1      = (const float*)d_in[11];
  const float* w_src_rb1 = (const float*)d_in[12];
  const float* w_dst_rb1 = (const float*)d_in[13];
  const float* a_rb1     = (const float*)d_in[14];
  const float* b_rb1     = (const float*)d_in[15];
  const float* w_src_rb2 = (const float*)d_in[16];
  const float* w_dst_rb2 = (const float*)d_in[17];
  const float* a_rb2     = (const float*)d_in[18];
  const float* b_rb2     = (const float*)d_in[19];
  const float* w_src_l2  = (const float*)d_in[20];
  const float* w_dst_l2  = (const float*)d_in[21];
  const float* a_l2      = (const float*)d_in[22];
  const float* b_l2      = (const float*)d_in[23];
  const float* w_out     = (const float*)d_in[24];
  const float* b_out     = (const float*)d_in[25];
  float* out = (float*)d_out;

  char* ws = (char*)d_ws;
  size_t off = 0;
  auto alloc = [&](size_t bytes) -> void* {
    void* p = ws + off;
    off += (bytes + 255) & ~(size_t)255;
    return p;
  };

  float* hs_buf  = (float*)alloc((size_t)N_ITEM * 64 * 4);
  float* hd_buf  = (float*)alloc((size_t)N_ITEM * 64 * 4);
  float* h1_item = (float*)alloc((size_t)N_ITEM * 64 * 4);
  float* h2_user = (float*)alloc((size_t)N_USER * 64 * 4);
  float* infl    = (float*)alloc((size_t)N_USER * 64 * 4);
  float* social  = (float*)alloc((size_t)N_USER * 64 * 4);
  int* counts    = (int*)alloc((size_t)(N_ITEM + 1) * 4);
  int* cursor    = (int*)alloc((size_t)(N_ITEM + 1) * 4);
  int* rp_rate   = (int*)alloc((size_t)(N_ITEM + 1) * 4);
  int* rp_rb     = (int*)alloc((size_t)(N_USER + 1) * 4);
  int* rp_link   = (int*)alloc((size_t)(N_USER + 1) * 4);
  int* col_rate  = (int*)alloc((size_t)E_UI * 4);
  int* col_rb    = (int*)alloc((size_t)E_UI * 4);
  int* col_link  = (int*)alloc((size_t)E_UU * 4);

  auto build_csr = [&](const int* src, const int* dst, int E, int n, int* rp, int* colv) {
    zero_i32<<<(n + 255) / 256, 256, 0, stream>>>(counts, n);
    hist_kernel<<<1024, 256, 0, stream>>>(dst, E, counts);
    scan_kernel<<<1, 1024, 0, stream>>>(counts, n, rp, cursor);
    scatter_kernel<<<1024, 256, 0, stream>>>(src, dst, E, cursor, colv);
  };

  build_csr(rate_src, rate_dst, E_UI, N_ITEM, rp_rate, col_rate);
  build_csr(rb_src,   rb_dst,   E_UI, N_USER, rp_rb,   col_rb);
  build_csr(link_src, link_dst, E_UU, N_USER, rp_link, col_link);

  auto gemm = [&](const float* X, const float* W, float* Y, int N) {
    gemm64<<<(N + 63) / 64, 256, 0, stream>>>(X, W, Y, N);
  };
  auto gat = [&](const float* hs, const float* hd, const int* rp, const int* colv,
                 const float* a, const float* b, float* o, int Nd) {
    gat_kernel<<<(Nd + 3) / 4, 256, 0, stream>>>(hs, hd, rp, colv, a, b, o, Nd);
  };

  // layer1 'rate': user -> item
  gemm(h_user, w_src_r1, hs_buf, N_USER);
  gemm(h_item, w_dst_r1, hd_buf, N_ITEM);
  gat(hs_buf, hd_buf, rp_rate, col_rate, a_r1, b_r1, h1_item, N_ITEM);

  // layer1 'rated-by': item -> user
  gemm(h_item, w_src_rb1, hs_buf, N_ITEM);
  gemm(h_user, w_dst_rb1, hd_buf, N_USER);
  gat(hs_buf, hd_buf, rp_rb, col_rb, a_rb1, b_rb1, h2_user, N_USER);

  // layer2 'rated-by': item(h1) -> user
  gemm(h1_item, w_src_rb2, hs_buf, N_ITEM);
  gemm(h_user, w_dst_rb2, hd_buf, N_USER);
  gat(hs_buf, hd_buf, rp_rb, col_rb, a_rb2, b_rb2, infl, N_USER);

  // layer2 'link': user(h2) -> user
  gemm(h2_user, w_src_l2, hs_buf, N_USER);
  gemm(h_user, w_dst_l2, hd_buf, N_USER);
  gat(hs_buf, hd_buf, rp_link, col_link, a_l2, b_l2, social, N_USER);

  final_kernel<<<(N_USER + 63) / 64, 256, 0, stream>>>(infl, social, w_out, b_out, out, N_USER);
}

// Round 2
// 1203.587 us; speedup vs baseline: 1.3746x; 1.3746x over previous
//
#include <hip/hip_runtime.h>
#include <math.h>

#define N_USER 50000
#define N_ITEM 100000
#define E_UI   1000000
#define E_UU   800000
#define NEG_SLOPE 0.2f

// ---------------- CSR build ----------------

__global__ void zero_i32(int* __restrict__ p, int n) {
  int i = blockIdx.x * blockDim.x + threadIdx.x;
  if (i < n) p[i] = 0;
}

__global__ void hist_kernel(const int* __restrict__ dst, int E, int* __restrict__ counts) {
  for (int i = blockIdx.x * blockDim.x + threadIdx.x; i < E; i += gridDim.x * blockDim.x)
    atomicAdd(&counts[dst[i]], 1);
}

// ---- hierarchical scan: counts[0..n) -> exclusive row_ptr[0..n] + cursor copy ----
// tile = 1024 elements per block (4 per thread via int4)

__global__ __launch_bounds__(256) void partial_kernel(const int* __restrict__ counts, int n,
                                                      int* __restrict__ partials) {
  int t = threadIdx.x;
  int base = blockIdx.x * 1024 + t * 4;
  int s = 0;
  if (base + 3 < n) {
    int4 v = *(const int4*)(counts + base);
    s = v.x + v.y + v.z + v.w;
  } else {
    for (int i = base; i < n && i < base + 4; ++i) s += counts[i];
  }
  #pragma unroll
  for (int off = 1; off < 64; off <<= 1) s += __shfl_xor(s, off);
  __shared__ int ws[4];
  if ((t & 63) == 0) ws[t >> 6] = s;
  __syncthreads();
  if (t == 0) partials[blockIdx.x] = ws[0] + ws[1] + ws[2] + ws[3];
}

// single tiny block: exclusive-scan partials (nb <= 128), write row_ptr[n] = total
__global__ __launch_bounds__(128) void scan_partials_kernel(int* __restrict__ partials, int nb,
                                                            int* __restrict__ row_ptr, int n) {
  __shared__ int s[128];
  int t = threadIdx.x;
  s[t] = (t < nb) ? partials[t] : 0;
  __syncthreads();
  for (int off = 1; off < 128; off <<= 1) {
    int v = (t >= off) ? s[t - off] : 0;
    __syncthreads();
    s[t] += v;
    __syncthreads();
  }
  if (t < nb) partials[t] = (t == 0) ? 0 : s[t - 1];
  if (t == 0) row_ptr[n] = s[127];
}

__global__ __launch_bounds__(256) void scan_apply_kernel(const int* __restrict__ counts, int n,
                                                         const int* __restrict__ partials,
                                                         int* __restrict__ row_ptr, int* __restrict__ cursor) {
  int t = threadIdx.x;
  int base = blockIdx.x * 1024 + t * 4;
  int4 v = make_int4(0, 0, 0, 0);
  if (base + 3 < n) {
    v = *(const int4*)(counts + base);
  } else {
    int* pv = &v.x;
    for (int i = 0; i < 4; ++i) if (base + i < n) pv[i] = counts[base + i];
  }
  int s = v.x + v.y + v.z + v.w;
  int lane = t & 63;
  int wv = t >> 6;
  int inc = s;
  #pragma unroll
  for (int off = 1; off < 64; off <<= 1) {
    int u = __shfl_up(inc, off);
    if (lane >= off) inc += u;
  }
  __shared__ int wsum[4];
  if (lane == 63) wsum[wv] = inc;
  __syncthreads();
  int woff = 0;
  for (int i = 0; i < wv; ++i) woff += wsum[i];
  int excl = woff + (inc - s) + partials[blockIdx.x];
  int4 rp;
  rp.x = excl;
  rp.y = rp.x + v.x;
  rp.z = rp.y + v.y;
  rp.w = rp.z + v.z;
  if (base + 3 < n) {
    *(int4*)(row_ptr + base) = rp;
    *(int4*)(cursor + base) = rp;
  } else {
    int* pr = &rp.x;
    for (int i = 0; i < 4; ++i) if (base + i < n) { row_ptr[base + i] = pr[i]; cursor[base + i] = pr[i]; }
  }
}

__global__ void scatter_kernel(const int* __restrict__ src, const int* __restrict__ dst, int E,
                               int* __restrict__ cursor, int* __restrict__ col) {
  for (int i = blockIdx.x * blockDim.x + threadIdx.x; i < E; i += gridDim.x * blockDim.x) {
    int p = atomicAdd(&cursor[dst[i]], 1);
    col[p] = src[i];
  }
}

// ---------------- node GEMM: Y[N,64] = X[N,64] @ W[64,64] ----------------

__global__ __launch_bounds__(256) void gemm64(const float* __restrict__ X, const float* __restrict__ W,
                                              float* __restrict__ Y, int N) {
  __shared__ float Ws[64 * 64];
  for (int i = threadIdx.x; i < 64 * 64; i += 256) Ws[i] = W[i];
  __syncthreads();
  int c  = threadIdx.x & 63;
  int rs = threadIdx.x >> 6;  // 0..3
  int base = blockIdx.x * 64;
  for (int r0 = 0; r0 < 64; r0 += 4) {
    int row = base + r0 + rs;
    if (row < N) {
      float acc = 0.f;
      const float* xr = X + (size_t)row * 64;
      #pragma unroll
      for (int k = 0; k < 64; ++k) acc = fmaf(xr[k], Ws[k * 64 + c], acc);
      Y[(size_t)row * 64 + c] = acc;
    }
  }
}

// ---------------- GATv2 edge aggregation: one wave64 per dst node ----------------

__global__ __launch_bounds__(256) void gat_kernel(const float* __restrict__ hs, const float* __restrict__ hd,
                                                  const int* __restrict__ row_ptr, const int* __restrict__ col,
                                                  const float* __restrict__ attn, const float* __restrict__ bias,
                                                  float* __restrict__ out, int Nd) {
  int wave = (blockIdx.x * blockDim.x + threadIdx.x) >> 6;
  int lane = threadIdx.x & 63;
  if (wave >= Nd) return;
  int node = wave;
  int s0 = row_ptr[node];
  int s1 = row_ptr[node + 1];
  float hd_l = hd[(size_t)node * 64 + lane];
  float a_l  = attn[lane];
  float b_l  = bias[lane];

  float m = -INFINITY, den = 0.f, num = 0.f;
  for (int e = s0; e < s1; ++e) {
    int s = col[e];
    float hs_l = hs[(size_t)s * 64 + lane];
    float pre = hs_l + hd_l;
    pre = pre > 0.f ? pre : NEG_SLOPE * pre;
    float v = pre * a_l;
    #pragma unroll
    for (int off = 1; off < 64; off <<= 1) v += __shfl_xor(v, off);
    float mn = fmaxf(m, v);
    float scale = __expf(m - mn);   // first iter: exp(-inf) = 0
    float p = __expf(v - mn);
    den = den * scale + p;
    num = num * scale + hs_l * p;
    m = mn;
  }
  out[(size_t)node * 64 + lane] = num / fmaxf(den, 1e-9f) + b_l;
}

// ---------------- final: out = [A|B] @ Wout + bout ----------------

__global__ __launch_bounds__(256) void final_kernel(const float* __restrict__ A, const float* __restrict__ B,
                                                    const float* __restrict__ W, const float* __restrict__ bias,
                                                    float* __restrict__ Y, int N) {
  __shared__ float Ws[128 * 64];  // 32 KiB
  for (int i = threadIdx.x; i < 128 * 64; i += 256) Ws[i] = W[i];
  __syncthreads();
  int c  = threadIdx.x & 63;
  int rs = threadIdx.x >> 6;
  int base = blockIdx.x * 64;
  for (int r0 = 0; r0 < 64; r0 += 4) {
    int row = base + r0 + rs;
    if (row < N) {
      float acc = bias[c];
      const float* ar = A + (size_t)row * 64;
      const float* br = B + (size_t)row * 64;
      #pragma unroll
      for (int k = 0; k < 64; ++k) acc = fmaf(ar[k], Ws[k * 64 + c], acc);
      #pragma unroll
      for (int k = 0; k < 64; ++k) acc = fmaf(br[k], Ws[(64 + k) * 64 + c], acc);
      Y[(size_t)row * 64 + c] = acc;
    }
  }
}

// ---------------- launch ----------------

extern "C" void kernel_launch(void* const* d_in, const int* in_sizes, int n_in,
                              void* d_out, int out_size, void* d_ws, size_t ws_size,
                              hipStream_t stream) {
  const float* h_user   = (const float*)d_in[0];
  const float* h_item   = (const float*)d_in[1];
  const int* rate_src   = (const int*)d_in[2];
  const int* rate_dst   = (const int*)d_in[3];
  const int* rb_src     = (const int*)d_in[4];
  const int* rb_dst     = (const int*)d_in[5];
  const int* link_src   = (const int*)d_in[6];
  const int* link_dst   = (const int*)d_in[7];
  const float* w_src_r1  = (const float*)d_in[8];
  const float* w_dst_r1  = (const float*)d_in[9];
  const float* a_r1      = (const float*)d_in[10];
  const float* b_r1      = (const float*)d_in[11];
  const float* w_src_rb1 = (const float*)d_in[12];
  const float* w_dst_rb1 = (const float*)d_in[13];
  const float* a_rb1     = (const float*)d_in[14];
  const float* b_rb1     = (const float*)d_in[15];
  const float* w_src_rb2 = (const float*)d_in[16];
  const float* w_dst_rb2 = (const float*)d_in[17];
  const float* a_rb2     = (const float*)d_in[18];
  const float* b_rb2     = (const float*)d_in[19];
  const float* w_src_l2  = (const float*)d_in[20];
  const float* w_dst_l2  = (const float*)d_in[21];
  const float* a_l2      = (const float*)d_in[22];
  const float* b_l2      = (const float*)d_in[23];
  const float* w_out     = (const float*)d_in[24];
  const float* b_out     = (const float*)d_in[25];
  float* out = (float*)d_out;

  char* ws = (char*)d_ws;
  size_t off = 0;
  auto alloc = [&](size_t bytes) -> void* {
    void* p = ws + off;
    off += (bytes + 255) & ~(size_t)255;
    return p;
  };

  float* hs_buf  = (float*)alloc((size_t)N_ITEM * 64 * 4);
  float* hd_buf  = (float*)alloc((size_t)N_ITEM * 64 * 4);
  float* h1_item = (float*)alloc((size_t)N_ITEM * 64 * 4);
  float* h2_user = (float*)alloc((size_t)N_USER * 64 * 4);
  float* infl    = (float*)alloc((size_t)N_USER * 64 * 4);
  float* social  = (float*)alloc((size_t)N_USER * 64 * 4);
  int* counts    = (int*)alloc((size_t)(N_ITEM + 1) * 4);
  int* cursor    = (int*)alloc((size_t)(N_ITEM + 1) * 4);
  int* partials  = (int*)alloc(256 * 4);
  int* rp_rate   = (int*)alloc((size_t)(N_ITEM + 1) * 4);
  int* rp_rb     = (int*)alloc((size_t)(N_USER + 1) * 4);
  int* rp_link   = (int*)alloc((size_t)(N_USER + 1) * 4);
  int* col_rate  = (int*)alloc((size_t)E_UI * 4);
  int* col_rb    = (int*)alloc((size_t)E_UI * 4);
  int* col_link  = (int*)alloc((size_t)E_UU * 4);

  auto build_csr = [&](const int* src, const int* dst, int E, int n, int* rp, int* colv) {
    int nb = (n + 1023) / 1024;
    zero_i32<<<(n + 255) / 256, 256, 0, stream>>>(counts, n);
    hist_kernel<<<1024, 256, 0, stream>>>(dst, E, counts);
    partial_kernel<<<nb, 256, 0, stream>>>(counts, n, partials);
    scan_partials_kernel<<<1, 128, 0, stream>>>(partials, nb, rp, n);
    scan_apply_kernel<<<nb, 256, 0, stream>>>(counts, n, partials, rp, cursor);
    scatter_kernel<<<1024, 256, 0, stream>>>(src, dst, E, cursor, colv);
  };

  build_csr(rate_src, rate_dst, E_UI, N_ITEM, rp_rate, col_rate);
  build_csr(rb_src,   rb_dst,   E_UI, N_USER, rp_rb,   col_rb);
  build_csr(link_src, link_dst, E_UU, N_USER, rp_link, col_link);

  auto gemm = [&](const float* X, const float* W, float* Y, int N) {
    gemm64<<<(N + 63) / 64, 256, 0, stream>>>(X, W, Y, N);
  };
  auto gat = [&](const float* hs, const float* hd, const int* rp, const int* colv,
                 const float* a, const float* b, float* o, int Nd) {
    gat_kernel<<<(Nd + 3) / 4, 256, 0, stream>>>(hs, hd, rp, colv, a, b, o, Nd);
  };

  // layer1 'rate': user -> item
  gemm(h_user, w_src_r1, hs_buf, N_USER);
  gemm(h_item, w_dst_r1, hd_buf, N_ITEM);
  gat(hs_buf, hd_buf, rp_rate, col_rate, a_r1, b_r1, h1_item, N_ITEM);

  // layer1 'rated-by': item -> user
  gemm(h_item, w_src_rb1, hs_buf, N_ITEM);
  gemm(h_user, w_dst_rb1, hd_buf, N_USER);
  gat(hs_buf, hd_buf, rp_rb, col_rb, a_rb1, b_rb1, h2_user, N_USER);

  // layer2 'rated-by': item(h1) -> user
  gemm(h1_item, w_src_rb2, hs_buf, N_ITEM);
  gemm(h_user, w_dst_rb2, hd_buf, N_USER);
  gat(hs_buf, hd_buf, rp_rb, col_rb, a_rb2, b_rb2, infl, N_USER);

  // layer2 'link': user(h2) -> user
  gemm(h2_user, w_src_l2, hs_buf, N_USER);
  gemm(h_user, w_dst_l2, hd_buf, N_USER);
  gat(hs_buf, hd_buf, rp_link, col_link, a_l2, b_l2, social, N_USER);

  final_kernel<<<(N_USER + 63) / 64, 256, 0, stream>>>(infl, social, w_out, b_out, out, N_USER);
}

// Round 3
// 1136.474 us; speedup vs baseline: 1.4557x; 1.0591x over previous
//
#include <hip/hip_runtime.h>
#include <math.h>

#define N_USER 50000
#define N_ITEM 100000
#define E_UI   1000000
#define E_UU   800000
#define NEG_SLOPE 0.2f

// ---------------- CSR build ----------------

__global__ void zero_all(int* __restrict__ p, int n) {
  for (int i = blockIdx.x * blockDim.x + threadIdx.x; i < n; i += gridDim.x * blockDim.x)
    p[i] = 0;
}

__global__ void hist_all(const int* __restrict__ d0, int E0, int* __restrict__ c0,
                         const int* __restrict__ d1, int E1, int* __restrict__ c1,
                         const int* __restrict__ d2, int E2, int* __restrict__ c2) {
  int total = E0 + E1 + E2;
  for (int i = blockIdx.x * blockDim.x + threadIdx.x; i < total; i += gridDim.x * blockDim.x) {
    if (i < E0) atomicAdd(&c0[d0[i]], 1);
    else if (i < E0 + E1) atomicAdd(&c1[d1[i - E0]], 1);
    else atomicAdd(&c2[d2[i - E0 - E1]], 1);
  }
}

__global__ __launch_bounds__(256) void partial_kernel(const int* __restrict__ counts, int n,
                                                      int* __restrict__ partials) {
  int t = threadIdx.x;
  int base = blockIdx.x * 1024 + t * 4;
  int s = 0;
  if (base + 3 < n) {
    int4 v = *(const int4*)(counts + base);
    s = v.x + v.y + v.z + v.w;
  } else {
    for (int i = base; i < n && i < base + 4; ++i) s += counts[i];
  }
  #pragma unroll
  for (int off = 1; off < 64; off <<= 1) s += __shfl_xor(s, off);
  __shared__ int ws[4];
  if ((t & 63) == 0) ws[t >> 6] = s;
  __syncthreads();
  if (t == 0) partials[blockIdx.x] = ws[0] + ws[1] + ws[2] + ws[3];
}

__global__ __launch_bounds__(128) void scan_partials_kernel(int* __restrict__ partials, int nb,
                                                            int* __restrict__ row_ptr, int n) {
  __shared__ int s[128];
  int t = threadIdx.x;
  s[t] = (t < nb) ? partials[t] : 0;
  __syncthreads();
  for (int off = 1; off < 128; off <<= 1) {
    int v = (t >= off) ? s[t - off] : 0;
    __syncthreads();
    s[t] += v;
    __syncthreads();
  }
  if (t < nb) partials[t] = (t == 0) ? 0 : s[t - 1];
  if (t == 0) row_ptr[n] = s[127];
}

__global__ __launch_bounds__(256) void scan_apply_kernel(const int* __restrict__ counts, int n,
                                                         const int* __restrict__ partials,
                                                         int* __restrict__ row_ptr, int* __restrict__ cursor) {
  int t = threadIdx.x;
  int base = blockIdx.x * 1024 + t * 4;
  int4 v = make_int4(0, 0, 0, 0);
  if (base + 3 < n) {
    v = *(const int4*)(counts + base);
  } else {
    int* pv = &v.x;
    for (int i = 0; i < 4; ++i) if (base + i < n) pv[i] = counts[base + i];
  }
  int s = v.x + v.y + v.z + v.w;
  int lane = t & 63;
  int wv = t >> 6;
  int inc = s;
  #pragma unroll
  for (int off = 1; off < 64; off <<= 1) {
    int u = __shfl_up(inc, off);
    if (lane >= off) inc += u;
  }
  __shared__ int wsum[4];
  if (lane == 63) wsum[wv] = inc;
  __syncthreads();
  int woff = 0;
  for (int i = 0; i < wv; ++i) woff += wsum[i];
  int excl = woff + (inc - s) + partials[blockIdx.x];
  int4 rp;
  rp.x = excl;
  rp.y = rp.x + v.x;
  rp.z = rp.y + v.y;
  rp.w = rp.z + v.z;
  if (base + 3 < n) {
    *(int4*)(row_ptr + base) = rp;
    *(int4*)(cursor + base) = rp;
  } else {
    int* pr = &rp.x;
    for (int i = 0; i < 4; ++i) if (base + i < n) { row_ptr[base + i] = pr[i]; cursor[base + i] = pr[i]; }
  }
}

__global__ void scatter_all(const int* __restrict__ s0v, const int* __restrict__ d0, int E0,
                            int* __restrict__ cu0, int* __restrict__ co0,
                            const int* __restrict__ s1v, const int* __restrict__ d1, int E1,
                            int* __restrict__ cu1, int* __restrict__ co1,
                            const int* __restrict__ s2v, const int* __restrict__ d2, int E2,
                            int* __restrict__ cu2, int* __restrict__ co2) {
  int total = E0 + E1 + E2;
  for (int i = blockIdx.x * blockDim.x + threadIdx.x; i < total; i += gridDim.x * blockDim.x) {
    if (i < E0) {
      int p = atomicAdd(&cu0[d0[i]], 1);
      co0[p] = s0v[i];
    } else if (i < E0 + E1) {
      int j = i - E0;
      int p = atomicAdd(&cu1[d1[j]], 1);
      co1[p] = s1v[j];
    } else {
      int j = i - E0 - E1;
      int p = atomicAdd(&cu2[d2[j]], 1);
      co2[p] = s2v[j];
    }
  }
}

// ---------------- batched node GEMM: Yj[N,64] = X[N,64] @ Wj[64,64] ----------------
// 64 rows/block; thread = (16 col-groups x 16 row-lanes); 4 rows x 4 cols per thread.

template<int NW>
__global__ __launch_bounds__(256) void gemm64_multi(const float* __restrict__ X,
                                                    const float* __restrict__ W0, const float* __restrict__ W1,
                                                    const float* __restrict__ W2, const float* __restrict__ W3,
                                                    float* __restrict__ Y0, float* __restrict__ Y1,
                                                    float* __restrict__ Y2, float* __restrict__ Y3, int N) {
  __shared__ float Ws[64 * 64];
  const float* Wp[4] = {W0, W1, W2, W3};
  float* Yp[4] = {Y0, Y1, Y2, Y3};
  int c4 = (threadIdx.x & 15) * 4;
  int rl = threadIdx.x >> 4;           // 0..15
  int base = blockIdx.x * 64;

  int row[4];
  const float* xr[4];
  #pragma unroll
  for (int rr = 0; rr < 4; ++rr) {
    row[rr] = base + rr * 16 + rl;
    int rc = row[rr] < N ? row[rr] : (N - 1);
    xr[rr] = X + (size_t)rc * 64;
  }

  for (int j = 0; j < NW; ++j) {
    __syncthreads();
    for (int i = threadIdx.x * 4; i < 64 * 64; i += 1024)
      *(float4*)(Ws + i) = *(const float4*)(Wp[j] + i);
    __syncthreads();

    float4 acc[4];
    #pragma unroll
    for (int rr = 0; rr < 4; ++rr) acc[rr] = make_float4(0.f, 0.f, 0.f, 0.f);

    #pragma unroll
    for (int k4 = 0; k4 < 64; k4 += 4) {
      float4 x[4];
      #pragma unroll
      for (int rr = 0; rr < 4; ++rr) x[rr] = *(const float4*)(xr[rr] + k4);
      #pragma unroll
      for (int kk = 0; kk < 4; ++kk) {
        float4 w = *(const float4*)(Ws + (k4 + kk) * 64 + c4);
        #pragma unroll
        for (int rr = 0; rr < 4; ++rr) {
          float xs = (&x[rr].x)[kk];
          acc[rr].x = fmaf(xs, w.x, acc[rr].x);
          acc[rr].y = fmaf(xs, w.y, acc[rr].y);
          acc[rr].z = fmaf(xs, w.z, acc[rr].z);
          acc[rr].w = fmaf(xs, w.w, acc[rr].w);
        }
      }
    }
    #pragma unroll
    for (int rr = 0; rr < 4; ++rr)
      if (row[rr] < N) *(float4*)(Yp[j] + (size_t)row[rr] * 64 + c4) = acc[rr];
  }
}

// ---------------- GATv2: wave per dst node, 4x16-lane groups, 4 edges/iter ----------------
// Safe with out == hd (wave only touches row `wid` of hd/out).

__global__ __launch_bounds__(256) void gat_kernel(const float* __restrict__ hs, const float* __restrict__ hd,
                                                  const int* __restrict__ row_ptr, const int* __restrict__ col,
                                                  const float* __restrict__ attn, const float* __restrict__ bias,
                                                  float* __restrict__ out, int Nd) {
  int wid = (blockIdx.x * blockDim.x + threadIdx.x) >> 6;
  int lane = threadIdx.x & 63;
  if (wid >= Nd) return;
  int g = lane >> 4;        // edge group 0..3
  int sl = lane & 15;       // dim group: dims sl*4 .. sl*4+3
  int s0 = row_ptr[wid];
  int s1 = row_ptr[wid + 1];

  float4 hd4 = *(const float4*)(hd + (size_t)wid * 64 + sl * 4);
  float4 a4  = *(const float4*)(attn + sl * 4);

  float m = -INFINITY, den = 0.f;
  float4 num = make_float4(0.f, 0.f, 0.f, 0.f);

  for (int e = s0 + g; e < s1; e += 4) {
    int s = col[e];
    float4 h4 = *(const float4*)(hs + (size_t)s * 64 + sl * 4);
    float px = h4.x + hd4.x; px = px > 0.f ? px : NEG_SLOPE * px;
    float py = h4.y + hd4.y; py = py > 0.f ? py : NEG_SLOPE * py;
    float pz = h4.z + hd4.z; pz = pz > 0.f ? pz : NEG_SLOPE * pz;
    float pw = h4.w + hd4.w; pw = pw > 0.f ? pw : NEG_SLOPE * pw;
    float t = a4.x * px;
    t = fmaf(a4.y, py, t);
    t = fmaf(a4.z, pz, t);
    t = fmaf(a4.w, pw, t);
    #pragma unroll
    for (int off = 1; off < 16; off <<= 1) t += __shfl_xor(t, off);

    float mn = fmaxf(m, t);
    float sc = (m == mn) ? 1.f : __expf(m - mn);   // m=-inf,first edge -> exp(-inf)=0
    float p  = __expf(t - mn);
    den = den * sc + p;
    num.x = fmaf(num.x, sc, h4.x * p);
    num.y = fmaf(num.y, sc, h4.y * p);
    num.z = fmaf(num.z, sc, h4.z * p);
    num.w = fmaf(num.w, sc, h4.w * p);
    m = mn;
  }

  // merge the 4 groups (flash-combine); equality guard keeps empty groups (m=-inf) NaN-free
  #pragma unroll
  for (int off = 16; off <= 32; off <<= 1) {
    float m2 = __shfl_xor(m, off);
    float d2 = __shfl_xor(den, off);
    float nx = __shfl_xor(num.x, off);
    float ny = __shfl_xor(num.y, off);
    float nz = __shfl_xor(num.z, off);
    float nw = __shfl_xor(num.w, off);
    float mn = fmaxf(m, m2);
    float sA = (m == mn) ? 1.f : __expf(m - mn);
    float sB = (m2 == mn) ? 1.f : __expf(m2 - mn);
    den = den * sA + d2 * sB;
    num.x = num.x * sA + nx * sB;
    num.y = num.y * sA + ny * sB;
    num.z = num.z * sA + nz * sB;
    num.w = num.w * sA + nw * sB;
    m = mn;
  }

  if (g == 0) {
    float inv = 1.f / fmaxf(den, 1e-9f);
    float4 b4 = *(const float4*)(bias + sl * 4);
    float4 o;
    o.x = fmaf(num.x, inv, b4.x);
    o.y = fmaf(num.y, inv, b4.y);
    o.z = fmaf(num.z, inv, b4.z);
    o.w = fmaf(num.w, inv, b4.w);
    *(float4*)(out + (size_t)wid * 64 + sl * 4) = o;
  }
}

// ---------------- final: out = [A|B] @ Wout + bout ----------------

__global__ __launch_bounds__(256) void final_kernel(const float* __restrict__ A, const float* __restrict__ B,
                                                    const float* __restrict__ W, const float* __restrict__ bias,
                                                    float* __restrict__ Y, int N) {
  __shared__ float Ws[128 * 64];  // 32 KiB
  for (int i = threadIdx.x * 4; i < 128 * 64; i += 1024)
    *(float4*)(Ws + i) = *(const float4*)(W + i);
  __syncthreads();
  int c4 = (threadIdx.x & 15) * 4;
  int rl = threadIdx.x >> 4;
  int base = blockIdx.x * 64;

  float4 b4 = *(const float4*)(bias + c4);

  #pragma unroll
  for (int rr = 0; rr < 4; ++rr) {
    int row = base + rr * 16 + rl;
    if (row >= N) continue;
    const float* ar = A + (size_t)row * 64;
    const float* br = B + (size_t)row * 64;
    float4 acc = b4;
    #pragma unroll
    for (int k4 = 0; k4 < 64; k4 += 4) {
      float4 xa = *(const float4*)(ar + k4);
      float4 xb = *(const float4*)(br + k4);
      #pragma unroll
      for (int kk = 0; kk < 4; ++kk) {
        float4 wa = *(const float4*)(Ws + (k4 + kk) * 64 + c4);
        float4 wb = *(const float4*)(Ws + (64 + k4 + kk) * 64 + c4);
        float xsa = (&xa.x)[kk], xsb = (&xb.x)[kk];
        acc.x = fmaf(xsa, wa.x, acc.x); acc.x = fmaf(xsb, wb.x, acc.x);
        acc.y = fmaf(xsa, wa.y, acc.y); acc.y = fmaf(xsb, wb.y, acc.y);
        acc.z = fmaf(xsa, wa.z, acc.z); acc.z = fmaf(xsb, wb.z, acc.z);
        acc.w = fmaf(xsa, wa.w, acc.w); acc.w = fmaf(xsb, wb.w, acc.w);
      }
    }
    *(float4*)(Y + (size_t)row * 64 + c4) = acc;
  }
}

// ---------------- launch ----------------

extern "C" void kernel_launch(void* const* d_in, const int* in_sizes, int n_in,
                              void* d_out, int out_size, void* d_ws, size_t ws_size,
                              hipStream_t stream) {
  const float* h_user   = (const float*)d_in[0];
  const float* h_item   = (const float*)d_in[1];
  const int* rate_src   = (const int*)d_in[2];
  const int* rate_dst   = (const int*)d_in[3];
  const int* rb_src     = (const int*)d_in[4];
  const int* rb_dst     = (const int*)d_in[5];
  const int* link_src   = (const int*)d_in[6];
  const int* link_dst   = (const int*)d_in[7];
  const float* w_src_r1  = (const float*)d_in[8];
  const float* w_dst_r1  = (const float*)d_in[9];
  const float* a_r1      = (const float*)d_in[10];
  const float* b_r1      = (const float*)d_in[11];
  const float* w_src_rb1 = (const float*)d_in[12];
  const float* w_dst_rb1 = (const float*)d_in[13];
  const float* a_rb1     = (const float*)d_in[14];
  const float* b_rb1     = (const float*)d_in[15];
  const float* w_src_rb2 = (const float*)d_in[16];
  const float* w_dst_rb2 = (const float*)d_in[17];
  const float* a_rb2     = (const float*)d_in[18];
  const float* b_rb2     = (const float*)d_in[19];
  const float* w_src_l2  = (const float*)d_in[20];
  const float* w_dst_l2  = (const float*)d_in[21];
  const float* a_l2      = (const float*)d_in[22];
  const float* b_l2      = (const float*)d_in[23];
  const float* w_out     = (const float*)d_in[24];
  const float* b_out     = (const float*)d_in[25];
  float* out = (float*)d_out;

  char* ws = (char*)d_ws;
  size_t off = 0;
  auto alloc = [&](size_t bytes) -> void* {
    void* p = ws + off;
    off += (bytes + 255) & ~(size_t)255;
    return p;
  };

  // user-sized (50000x64) and item-sized (100000x64) feature buffers
  float* u0 = (float*)alloc((size_t)N_USER * 64 * 4);
  float* u1 = (float*)alloc((size_t)N_USER * 64 * 4);
  float* u2 = (float*)alloc((size_t)N_USER * 64 * 4);
  float* u3 = (float*)alloc((size_t)N_USER * 64 * 4);
  float* i0 = (float*)alloc((size_t)N_ITEM * 64 * 4);
  float* i1 = (float*)alloc((size_t)N_ITEM * 64 * 4);

  // CSR scratch
  int* counts  = (int*)alloc((size_t)(N_ITEM + 2 * N_USER) * 4);
  int* cursor  = (int*)alloc((size_t)(N_ITEM + 2 * N_USER) * 4);
  int* partials = (int*)alloc(256 * 4);
  int* rp_rate = (int*)alloc((size_t)(N_ITEM + 1) * 4);
  int* rp_rb   = (int*)alloc((size_t)(N_USER + 1) * 4);
  int* rp_link = (int*)alloc((size_t)(N_USER + 1) * 4);
  int* col_rate = (int*)alloc((size_t)E_UI * 4);
  int* col_rb   = (int*)alloc((size_t)E_UI * 4);
  int* col_link = (int*)alloc((size_t)E_UU * 4);

  int* c_rate = counts;
  int* c_rb   = counts + N_ITEM;
  int* c_link = counts + N_ITEM + N_USER;
  int* cu_rate = cursor;
  int* cu_rb   = cursor + N_ITEM;
  int* cu_link = cursor + N_ITEM + N_USER;

  // ---- CSR builds ----
  zero_all<<<256, 256, 0, stream>>>(counts, N_ITEM + 2 * N_USER);
  hist_all<<<2048, 256, 0, stream>>>(rate_dst, E_UI, c_rate,
                                     rb_dst,   E_UI, c_rb,
                                     link_dst, E_UU, c_link);
  auto scan = [&](const int* cnt, int n, int* rp, int* cur) {
    int nb = (n + 1023) / 1024;
    partial_kernel<<<nb, 256, 0, stream>>>(cnt, n, partials);
    scan_partials_kernel<<<1, 128, 0, stream>>>(partials, nb, rp, n);
    scan_apply_kernel<<<nb, 256, 0, stream>>>(cnt, n, partials, rp, cur);
  };
  scan(c_rate, N_ITEM, rp_rate, cu_rate);
  scan(c_rb,   N_USER, rp_rb,   cu_rb);
  scan(c_link, N_USER, rp_link, cu_link);
  scatter_all<<<2048, 256, 0, stream>>>(rate_src, rate_dst, E_UI, cu_rate, col_rate,
                                        rb_src,   rb_dst,   E_UI, cu_rb,   col_rb,
                                        link_src, link_dst, E_UU, cu_link, col_link);

  // ---- batched node GEMMs ----
  // h_user @ {w_src_r1, w_dst_rb1, w_dst_rb2, w_dst_l2} -> u0..u3
  gemm64_multi<4><<<(N_USER + 63) / 64, 256, 0, stream>>>(
      h_user, w_src_r1, w_dst_rb1, w_dst_rb2, w_dst_l2, u0, u1, u2, u3, N_USER);
  // h_item @ {w_dst_r1, w_src_rb1} -> i0, i1
  gemm64_multi<2><<<(N_ITEM + 63) / 64, 256, 0, stream>>>(
      h_item, w_dst_r1, w_src_rb1, nullptr, nullptr, i0, i1, nullptr, nullptr, N_ITEM);

  // ---- GAT layers (out aliases hd: safe, wave-local row) ----
  // layer1 'rate': user -> item ; h1_item := i0
  gat_kernel<<<(N_ITEM + 3) / 4, 256, 0, stream>>>(u0, i0, rp_rate, col_rate, a_r1, b_r1, i0, N_ITEM);
  // layer1 'rated-by': item -> user ; h2_user := u1
  gat_kernel<<<(N_USER + 3) / 4, 256, 0, stream>>>(i1, u1, rp_rb, col_rb, a_rb1, b_rb1, u1, N_USER);
  // layer2 'rated-by' src transform: i1 := h1_item @ w_src_rb2   (i1 free after gat2)
  gemm64_multi<1><<<(N_ITEM + 63) / 64, 256, 0, stream>>>(
      i0, w_src_rb2, nullptr, nullptr, nullptr, i1, nullptr, nullptr, nullptr, N_ITEM);
  // layer2 'rated-by': item -> user ; infl := u2
  gat_kernel<<<(N_USER + 3) / 4, 256, 0, stream>>>(i1, u2, rp_rb, col_rb, a_rb2, b_rb2, u2, N_USER);
  // layer2 'link' src transform: u0 := h2_user @ w_src_l2        (u0 free after gat1)
  gemm64_multi<1><<<(N_USER + 63) / 64, 256, 0, stream>>>(
      u1, w_src_l2, nullptr, nullptr, nullptr, u0, nullptr, nullptr, nullptr, N_USER);
  // layer2 'link': user -> user ; social := u3
  gat_kernel<<<(N_USER + 3) / 4, 256, 0, stream>>>(u0, u3, rp_link, col_link, a_l2, b_l2, u3, N_USER);

  // ---- output projection ----
  final_kernel<<<(N_USER + 63) / 64, 256, 0, stream>>>(u2, u3, w_out, b_out, out, N_USER);
}

// Round 4
// 847.507 us; speedup vs baseline: 1.9521x; 1.3410x over previous
//
#include <hip/hip_runtime.h>
#include <math.h>

#define N_USER 50000
#define N_ITEM 100000
#define E_UI   1000000
#define E_UU   800000
#define NEG_SLOPE 0.2f

// ---------------- CSR build ----------------

__global__ void zero_all(int* __restrict__ p, int n) {
  for (int i = blockIdx.x * blockDim.x + threadIdx.x; i < n; i += gridDim.x * blockDim.x)
    p[i] = 0;
}

__global__ void hist_all(const int* __restrict__ d0, int E0, int* __restrict__ c0,
                         const int* __restrict__ d1, int E1, int* __restrict__ c1,
                         const int* __restrict__ d2, int E2, int* __restrict__ c2) {
  int total = E0 + E1 + E2;
  for (int i = blockIdx.x * blockDim.x + threadIdx.x; i < total; i += gridDim.x * blockDim.x) {
    if (i < E0) atomicAdd(&c0[d0[i]], 1);
    else if (i < E0 + E1) atomicAdd(&c1[d1[i - E0]], 1);
    else atomicAdd(&c2[d2[i - E0 - E1]], 1);
  }
}

__global__ __launch_bounds__(256) void partial_kernel(const int* __restrict__ counts, int n,
                                                      int* __restrict__ partials) {
  int t = threadIdx.x;
  int base = blockIdx.x * 1024 + t * 4;
  int s = 0;
  if (base + 3 < n) {
    int4 v = *(const int4*)(counts + base);
    s = v.x + v.y + v.z + v.w;
  } else {
    for (int i = base; i < n && i < base + 4; ++i) s += counts[i];
  }
  #pragma unroll
  for (int off = 1; off < 64; off <<= 1) s += __shfl_xor(s, off);
  __shared__ int ws[4];
  if ((t & 63) == 0) ws[t >> 6] = s;
  __syncthreads();
  if (t == 0) partials[blockIdx.x] = ws[0] + ws[1] + ws[2] + ws[3];
}

__global__ __launch_bounds__(128) void scan_partials_kernel(int* __restrict__ partials, int nb,
                                                            int* __restrict__ row_ptr, int n) {
  __shared__ int s[128];
  int t = threadIdx.x;
  s[t] = (t < nb) ? partials[t] : 0;
  __syncthreads();
  for (int off = 1; off < 128; off <<= 1) {
    int v = (t >= off) ? s[t - off] : 0;
    __syncthreads();
    s[t] += v;
    __syncthreads();
  }
  if (t < nb) partials[t] = (t == 0) ? 0 : s[t - 1];
  if (t == 0) row_ptr[n] = s[127];
}

__global__ __launch_bounds__(256) void scan_apply_kernel(const int* __restrict__ counts, int n,
                                                         const int* __restrict__ partials,
                                                         int* __restrict__ row_ptr, int* __restrict__ cursor) {
  int t = threadIdx.x;
  int base = blockIdx.x * 1024 + t * 4;
  int4 v = make_int4(0, 0, 0, 0);
  if (base + 3 < n) {
    v = *(const int4*)(counts + base);
  } else {
    int* pv = &v.x;
    for (int i = 0; i < 4; ++i) if (base + i < n) pv[i] = counts[base + i];
  }
  int s = v.x + v.y + v.z + v.w;
  int lane = t & 63;
  int wv = t >> 6;
  int inc = s;
  #pragma unroll
  for (int off = 1; off < 64; off <<= 1) {
    int u = __shfl_up(inc, off);
    if (lane >= off) inc += u;
  }
  __shared__ int wsum[4];
  if (lane == 63) wsum[wv] = inc;
  __syncthreads();
  int woff = 0;
  for (int i = 0; i < wv; ++i) woff += wsum[i];
  int excl = woff + (inc - s) + partials[blockIdx.x];
  int4 rp;
  rp.x = excl;
  rp.y = rp.x + v.x;
  rp.z = rp.y + v.y;
  rp.w = rp.z + v.z;
  if (base + 3 < n) {
    *(int4*)(row_ptr + base) = rp;
    *(int4*)(cursor + base) = rp;
  } else {
    int* pr = &rp.x;
    for (int i = 0; i < 4; ++i) if (base + i < n) { row_ptr[base + i] = pr[i]; cursor[base + i] = pr[i]; }
  }
}

__global__ void scatter_all(const int* __restrict__ s0v, const int* __restrict__ d0, int E0,
                            int* __restrict__ cu0, int* __restrict__ co0,
                            const int* __restrict__ s1v, const int* __restrict__ d1, int E1,
                            int* __restrict__ cu1, int* __restrict__ co1,
                            const int* __restrict__ s2v, const int* __restrict__ d2, int E2,
                            int* __restrict__ cu2, int* __restrict__ co2) {
  int total = E0 + E1 + E2;
  for (int i = blockIdx.x * blockDim.x + threadIdx.x; i < total; i += gridDim.x * blockDim.x) {
    if (i < E0) {
      int p = atomicAdd(&cu0[d0[i]], 1);
      co0[p] = s0v[i];
    } else if (i < E0 + E1) {
      int j = i - E0;
      int p = atomicAdd(&cu1[d1[j]], 1);
      co1[p] = s1v[j];
    } else {
      int j = i - E0 - E1;
      int p = atomicAdd(&cu2[d2[j]], 1);
      co2[p] = s2v[j];
    }
  }
}

// ---------------- node GEMM: Y[N,64] = X[N,64] @ W[64,64] ----------------
// 64 rows/block; thread = (16 col-groups x 16 row-lanes); 4 rows x 4 cols per thread.
// All indices compile-time static (no pointer arrays -> no scratch).

__global__ __launch_bounds__(256) void gemm64(const float* __restrict__ X, const float* __restrict__ W,
                                              float* __restrict__ Y, int N) {
  __shared__ float Ws[64 * 64];
  #pragma unroll
  for (int i = 0; i < 4; ++i) {
    int idx = threadIdx.x * 4 + i * 1024;
    *(float4*)(Ws + idx) = *(const float4*)(W + idx);
  }
  __syncthreads();
  int c4 = (threadIdx.x & 15) * 4;
  int rl = threadIdx.x >> 4;
  int base = blockIdx.x * 64;
  int r0 = base + rl, r1 = r0 + 16, r2 = r0 + 32, r3 = r0 + 48;
  const float* x0 = X + (size_t)(r0 < N ? r0 : N - 1) * 64;
  const float* x1 = X + (size_t)(r1 < N ? r1 : N - 1) * 64;
  const float* x2 = X + (size_t)(r2 < N ? r2 : N - 1) * 64;
  const float* x3 = X + (size_t)(r3 < N ? r3 : N - 1) * 64;
  float4 acc0 = make_float4(0.f, 0.f, 0.f, 0.f);
  float4 acc1 = acc0, acc2 = acc0, acc3 = acc0;

  #pragma unroll
  for (int k4 = 0; k4 < 64; k4 += 4) {
    float4 xa = *(const float4*)(x0 + k4);
    float4 xb = *(const float4*)(x1 + k4);
    float4 xc = *(const float4*)(x2 + k4);
    float4 xd = *(const float4*)(x3 + k4);
    #pragma unroll
    for (int kk = 0; kk < 4; ++kk) {
      float4 w = *(const float4*)(Ws + (k4 + kk) * 64 + c4);
      float sa = (&xa.x)[kk], sb = (&xb.x)[kk], sc = (&xc.x)[kk], sd = (&xd.x)[kk];
      acc0.x = fmaf(sa, w.x, acc0.x); acc0.y = fmaf(sa, w.y, acc0.y);
      acc0.z = fmaf(sa, w.z, acc0.z); acc0.w = fmaf(sa, w.w, acc0.w);
      acc1.x = fmaf(sb, w.x, acc1.x); acc1.y = fmaf(sb, w.y, acc1.y);
      acc1.z = fmaf(sb, w.z, acc1.z); acc1.w = fmaf(sb, w.w, acc1.w);
      acc2.x = fmaf(sc, w.x, acc2.x); acc2.y = fmaf(sc, w.y, acc2.y);
      acc2.z = fmaf(sc, w.z, acc2.z); acc2.w = fmaf(sc, w.w, acc2.w);
      acc3.x = fmaf(sd, w.x, acc3.x); acc3.y = fmaf(sd, w.y, acc3.y);
      acc3.z = fmaf(sd, w.z, acc3.z); acc3.w = fmaf(sd, w.w, acc3.w);
    }
  }
  if (r0 < N) *(float4*)(Y + (size_t)r0 * 64 + c4) = acc0;
  if (r1 < N) *(float4*)(Y + (size_t)r1 * 64 + c4) = acc1;
  if (r2 < N) *(float4*)(Y + (size_t)r2 * 64 + c4) = acc2;
  if (r3 < N) *(float4*)(Y + (size_t)r3 * 64 + c4) = acc3;
}

// ---------------- GATv2: wave per dst node, 4x16-lane groups, 4 edges/iter ----------------
// Safe with out == hd (wave only touches row `wid` of hd/out).

__global__ __launch_bounds__(256) void gat_kernel(const float* __restrict__ hs, const float* __restrict__ hd,
                                                  const int* __restrict__ row_ptr, const int* __restrict__ col,
                                                  const float* __restrict__ attn, const float* __restrict__ bias,
                                                  float* __restrict__ out, int Nd) {
  int wid = (blockIdx.x * blockDim.x + threadIdx.x) >> 6;
  int lane = threadIdx.x & 63;
  if (wid >= Nd) return;
  int g = lane >> 4;        // edge group 0..3
  int sl = lane & 15;       // dim group: dims sl*4 .. sl*4+3
  int s0 = row_ptr[wid];
  int s1 = row_ptr[wid + 1];

  float4 hd4 = *(const float4*)(hd + (size_t)wid * 64 + sl * 4);
  float4 a4  = *(const float4*)(attn + sl * 4);

  float m = -INFINITY, den = 0.f;
  float4 num = make_float4(0.f, 0.f, 0.f, 0.f);

  for (int e = s0 + g; e < s1; e += 4) {
    int s = col[e];
    float4 h4 = *(const float4*)(hs + (size_t)s * 64 + sl * 4);
    float px = h4.x + hd4.x; px = px > 0.f ? px : NEG_SLOPE * px;
    float py = h4.y + hd4.y; py = py > 0.f ? py : NEG_SLOPE * py;
    float pz = h4.z + hd4.z; pz = pz > 0.f ? pz : NEG_SLOPE * pz;
    float pw = h4.w + hd4.w; pw = pw > 0.f ? pw : NEG_SLOPE * pw;
    float t = a4.x * px;
    t = fmaf(a4.y, py, t);
    t = fmaf(a4.z, pz, t);
    t = fmaf(a4.w, pw, t);
    #pragma unroll
    for (int off = 1; off < 16; off <<= 1) t += __shfl_xor(t, off);

    float mn = fmaxf(m, t);
    float sc = (m == mn) ? 1.f : __expf(m - mn);   // m=-inf,first edge -> exp(-inf)=0
    float p  = __expf(t - mn);
    den = den * sc + p;
    num.x = fmaf(num.x, sc, h4.x * p);
    num.y = fmaf(num.y, sc, h4.y * p);
    num.z = fmaf(num.z, sc, h4.z * p);
    num.w = fmaf(num.w, sc, h4.w * p);
    m = mn;
  }

  // merge the 4 groups (flash-combine); equality guard keeps empty groups (m=-inf) NaN-free
  #pragma unroll
  for (int off = 16; off <= 32; off <<= 1) {
    float m2 = __shfl_xor(m, off);
    float d2 = __shfl_xor(den, off);
    float nx = __shfl_xor(num.x, off);
    float ny = __shfl_xor(num.y, off);
    float nz = __shfl_xor(num.z, off);
    float nw = __shfl_xor(num.w, off);
    float mn = fmaxf(m, m2);
    float sA = (m == mn) ? 1.f : __expf(m - mn);
    float sB = (m2 == mn) ? 1.f : __expf(m2 - mn);
    den = den * sA + d2 * sB;
    num.x = num.x * sA + nx * sB;
    num.y = num.y * sA + ny * sB;
    num.z = num.z * sA + nz * sB;
    num.w = num.w * sA + nw * sB;
    m = mn;
  }

  if (g == 0) {
    float inv = 1.f / fmaxf(den, 1e-9f);
    float4 b4 = *(const float4*)(bias + sl * 4);
    float4 o;
    o.x = fmaf(num.x, inv, b4.x);
    o.y = fmaf(num.y, inv, b4.y);
    o.z = fmaf(num.z, inv, b4.z);
    o.w = fmaf(num.w, inv, b4.w);
    *(float4*)(out + (size_t)wid * 64 + sl * 4) = o;
  }
}

// ---------------- final: out = [A|B] @ Wout + bout ----------------

__global__ __launch_bounds__(256) void final_kernel(const float* __restrict__ A, const float* __restrict__ B,
                                                    const float* __restrict__ W, const float* __restrict__ bias,
                                                    float* __restrict__ Y, int N) {
  __shared__ float Ws[128 * 64];  // 32 KiB
  #pragma unroll
  for (int i = 0; i < 8; ++i) {
    int idx = threadIdx.x * 4 + i * 1024;
    *(float4*)(Ws + idx) = *(const float4*)(W + idx);
  }
  __syncthreads();
  int c4 = (threadIdx.x & 15) * 4;
  int rl = threadIdx.x >> 4;
  int base = blockIdx.x * 64;

  float4 b4 = *(const float4*)(bias + c4);

  #pragma unroll
  for (int rr = 0; rr < 4; ++rr) {
    int row = base + rr * 16 + rl;
    if (row >= N) continue;
    const float* ar = A + (size_t)row * 64;
    const float* br = B + (size_t)row * 64;
    float4 acc = b4;
    #pragma unroll
    for (int k4 = 0; k4 < 64; k4 += 4) {
      float4 xa = *(const float4*)(ar + k4);
      float4 xb = *(const float4*)(br + k4);
      #pragma unroll
      for (int kk = 0; kk < 4; ++kk) {
        float4 wa = *(const float4*)(Ws + (k4 + kk) * 64 + c4);
        float4 wb = *(const float4*)(Ws + (64 + k4 + kk) * 64 + c4);
        float xsa = (&xa.x)[kk], xsb = (&xb.x)[kk];
        acc.x = fmaf(xsa, wa.x, acc.x); acc.x = fmaf(xsb, wb.x, acc.x);
        acc.y = fmaf(xsa, wa.y, acc.y); acc.y = fmaf(xsb, wb.y, acc.y);
        acc.z = fmaf(xsa, wa.z, acc.z); acc.z = fmaf(xsb, wb.z, acc.z);
        acc.w = fmaf(xsa, wa.w, acc.w); acc.w = fmaf(xsb, wb.w, acc.w);
      }
    }
    *(float4*)(Y + (size_t)row * 64 + c4) = acc;
  }
}

// ---------------- launch ----------------

extern "C" void kernel_launch(void* const* d_in, const int* in_sizes, int n_in,
                              void* d_out, int out_size, void* d_ws, size_t ws_size,
                              hipStream_t stream) {
  const float* h_user   = (const float*)d_in[0];
  const float* h_item   = (const float*)d_in[1];
  const int* rate_src   = (const int*)d_in[2];
  const int* rate_dst   = (const int*)d_in[3];
  const int* rb_src     = (const int*)d_in[4];
  const int* rb_dst     = (const int*)d_in[5];
  const int* link_src   = (const int*)d_in[6];
  const int* link_dst   = (const int*)d_in[7];
  const float* w_src_r1  = (const float*)d_in[8];
  const float* w_dst_r1  = (const float*)d_in[9];
  const float* a_r1      = (const float*)d_in[10];
  const float* b_r1      = (const float*)d_in[11];
  const float* w_src_rb1 = (const float*)d_in[12];
  const float* w_dst_rb1 = (const float*)d_in[13];
  const float* a_rb1     = (const float*)d_in[14];
  const float* b_rb1     = (const float*)d_in[15];
  const float* w_src_rb2 = (const float*)d_in[16];
  const float* w_dst_rb2 = (const float*)d_in[17];
  const float* a_rb2     = (const float*)d_in[18];
  const float* b_rb2     = (const float*)d_in[19];
  const float* w_src_l2  = (const float*)d_in[20];
  const float* w_dst_l2  = (const float*)d_in[21];
  const float* a_l2      = (const float*)d_in[22];
  const float* b_l2      = (const float*)d_in[23];
  const float* w_out     = (const float*)d_in[24];
  const float* b_out     = (const float*)d_in[25];
  float* out = (float*)d_out;

  char* ws = (char*)d_ws;
  size_t off = 0;
  auto alloc = [&](size_t bytes) -> void* {
    void* p = ws + off;
    off += (bytes + 255) & ~(size_t)255;
    return p;
  };

  // user-sized (50000x64) and item-sized (100000x64) feature buffers
  float* u0 = (float*)alloc((size_t)N_USER * 64 * 4);
  float* u1 = (float*)alloc((size_t)N_USER * 64 * 4);
  float* u2 = (float*)alloc((size_t)N_USER * 64 * 4);
  float* u3 = (float*)alloc((size_t)N_USER * 64 * 4);
  float* i0 = (float*)alloc((size_t)N_ITEM * 64 * 4);
  float* i1 = (float*)alloc((size_t)N_ITEM * 64 * 4);

  // CSR scratch
  int* counts  = (int*)alloc((size_t)(N_ITEM + 2 * N_USER) * 4);
  int* cursor  = (int*)alloc((size_t)(N_ITEM + 2 * N_USER) * 4);
  int* partials = (int*)alloc(256 * 4);
  int* rp_rate = (int*)alloc((size_t)(N_ITEM + 1) * 4);
  int* rp_rb   = (int*)alloc((size_t)(N_USER + 1) * 4);
  int* rp_link = (int*)alloc((size_t)(N_USER + 1) * 4);
  int* col_rate = (int*)alloc((size_t)E_UI * 4);
  int* col_rb   = (int*)alloc((size_t)E_UI * 4);
  int* col_link = (int*)alloc((size_t)E_UU * 4);

  int* c_rate = counts;
  int* c_rb   = counts + N_ITEM;
  int* c_link = counts + N_ITEM + N_USER;
  int* cu_rate = cursor;
  int* cu_rb   = cursor + N_ITEM;
  int* cu_link = cursor + N_ITEM + N_USER;

  // ---- CSR builds ----
  zero_all<<<256, 256, 0, stream>>>(counts, N_ITEM + 2 * N_USER);
  hist_all<<<2048, 256, 0, stream>>>(rate_dst, E_UI, c_rate,
                                     rb_dst,   E_UI, c_rb,
                                     link_dst, E_UU, c_link);
  auto scan = [&](const int* cnt, int n, int* rp, int* cur) {
    int nb = (n + 1023) / 1024;
    partial_kernel<<<nb, 256, 0, stream>>>(cnt, n, partials);
    scan_partials_kernel<<<1, 128, 0, stream>>>(partials, nb, rp, n);
    scan_apply_kernel<<<nb, 256, 0, stream>>>(cnt, n, partials, rp, cur);
  };
  scan(c_rate, N_ITEM, rp_rate, cu_rate);
  scan(c_rb,   N_USER, rp_rb,   cu_rb);
  scan(c_link, N_USER, rp_link, cu_link);
  scatter_all<<<2048, 256, 0, stream>>>(rate_src, rate_dst, E_UI, cu_rate, col_rate,
                                        rb_src,   rb_dst,   E_UI, cu_rb,   col_rb,
                                        link_src, link_dst, E_UU, cu_link, col_link);

  // ---- node GEMMs (lean, no scratch) ----
  auto gemm = [&](const float* X, const float* W, float* Y, int N) {
    gemm64<<<(N + 63) / 64, 256, 0, stream>>>(X, W, Y, N);
  };
  gemm(h_user, w_src_r1,  u0, N_USER);
  gemm(h_user, w_dst_rb1, u1, N_USER);
  gemm(h_user, w_dst_rb2, u2, N_USER);
  gemm(h_user, w_dst_l2,  u3, N_USER);
  gemm(h_item, w_dst_r1,  i0, N_ITEM);
  gemm(h_item, w_src_rb1, i1, N_ITEM);

  // ---- GAT layers (out aliases hd: safe, wave-local row) ----
  // layer1 'rate': user -> item ; h1_item := i0
  gat_kernel<<<(N_ITEM + 3) / 4, 256, 0, stream>>>(u0, i0, rp_rate, col_rate, a_r1, b_r1, i0, N_ITEM);
  // layer1 'rated-by': item -> user ; h2_user := u1
  gat_kernel<<<(N_USER + 3) / 4, 256, 0, stream>>>(i1, u1, rp_rb, col_rb, a_rb1, b_rb1, u1, N_USER);
  // layer2 'rated-by' src transform: i1 := h1_item @ w_src_rb2   (i1 free after gat2)
  gemm(i0, w_src_rb2, i1, N_ITEM);
  // layer2 'rated-by': item -> user ; infl := u2
  gat_kernel<<<(N_USER + 3) / 4, 256, 0, stream>>>(i1, u2, rp_rb, col_rb, a_rb2, b_rb2, u2, N_USER);
  // layer2 'link' src transform: u0 := h2_user @ w_src_l2        (u0 free after gat1)
  gemm(u1, w_src_l2, u0, N_USER);
  // layer2 'link': user -> user ; social := u3
  gat_kernel<<<(N_USER + 3) / 4, 256, 0, stream>>>(u0, u3, rp_link, col_link, a_l2, b_l2, u3, N_USER);

  // ---- output projection ----
  final_kernel<<<(N_USER + 63) / 64, 256, 0, stream>>>(u2, u3, w_out, b_out, out, N_USER);
}

// Round 5
// 528.649 us; speedup vs baseline: 3.1295x; 1.6032x over previous
//
#include <hip/hip_runtime.h>
#include <math.h>

#define N_USER 50000
#define N_ITEM 100000
#define E_UI   1000000
#define E_UU   800000
#define E_TOT  (E_UI + E_UI + E_UU)
#define NEG_SLOPE 0.2f

// Bucketed CSR build: bucket = dst >> 8 (256 nodes/bucket).
// graph0 rate: n=100000 -> 391 buckets, graph1 rb / graph2 link: n=50000 -> 196 each.
#define NB0 391
#define NB1 196
#define NB2 196
#define NBTOT (NB0 + NB1 + NB2)   // 783
#define GPB 256                   // blocks per graph in hist/scatter
#define MATN (NBTOT * 256)        // 200448

// ---------------- bucket histogram: mat[(boff+b)*256 + g] = count ----------------

__global__ __launch_bounds__(256) void bucket_hist(const int* __restrict__ d0, const int* __restrict__ d1,
                                                   const int* __restrict__ d2, int* __restrict__ mat) {
  int gid = blockIdx.x >> 8;
  int g   = blockIdx.x & 255;
  const int* dst = gid == 0 ? d0 : (gid == 1 ? d1 : d2);
  int E    = (gid == 2) ? E_UU : E_UI;
  int NB   = (gid == 0) ? NB0 : NB1;
  int boff = (gid == 0) ? 0 : (gid == 1 ? NB0 : NB0 + NB1);
  __shared__ int cnt[NB0];
  for (int b = threadIdx.x; b < NB; b += 256) cnt[b] = 0;
  __syncthreads();
  int chunk = (E + 255) >> 8;
  int lo = g * chunk, hi = min(lo + chunk, E);
  for (int i = lo + threadIdx.x; i < hi; i += 256)
    atomicAdd(&cnt[dst[i] >> 8], 1);
  __syncthreads();
  for (int b = threadIdx.x; b < NB; b += 256)
    mat[(boff + b) * 256 + g] = cnt[b];
}

// ---------------- hierarchical exclusive scan over mat (MATN elements) ----------------

__global__ __launch_bounds__(256) void partial_kernel(const int* __restrict__ counts, int n,
                                                      int* __restrict__ partials) {
  int t = threadIdx.x;
  int base = blockIdx.x * 1024 + t * 4;
  int s = 0;
  if (base + 3 < n) {
    int4 v = *(const int4*)(counts + base);
    s = v.x + v.y + v.z + v.w;
  } else {
    for (int i = base; i < n && i < base + 4; ++i) s += counts[i];
  }
  #pragma unroll
  for (int off = 1; off < 64; off <<= 1) s += __shfl_xor(s, off);
  __shared__ int ws[4];
  if ((t & 63) == 0) ws[t >> 6] = s;
  __syncthreads();
  if (t == 0) partials[blockIdx.x] = ws[0] + ws[1] + ws[2] + ws[3];
}

__global__ __launch_bounds__(256) void scan_partials256(int* __restrict__ partials, int nb) {
  __shared__ int s[256];
  int t = threadIdx.x;
  s[t] = (t < nb) ? partials[t] : 0;
  __syncthreads();
  for (int off = 1; off < 256; off <<= 1) {
    int v = (t >= off) ? s[t - off] : 0;
    __syncthreads();
    s[t] += v;
    __syncthreads();
  }
  if (t < nb) partials[t] = (t == 0) ? 0 : s[t - 1];
}

__global__ __launch_bounds__(256) void scan_apply_one(const int* __restrict__ counts, int n,
                                                      const int* __restrict__ partials,
                                                      int* __restrict__ outp) {
  int t = threadIdx.x;
  int base = blockIdx.x * 1024 + t * 4;
  int4 v = make_int4(0, 0, 0, 0);
  if (base + 3 < n) {
    v = *(const int4*)(counts + base);
  } else {
    int* pv = &v.x;
    for (int i = 0; i < 4; ++i) if (base + i < n) pv[i] = counts[base + i];
  }
  int s = v.x + v.y + v.z + v.w;
  int lane = t & 63;
  int wv = t >> 6;
  int inc = s;
  #pragma unroll
  for (int off = 1; off < 64; off <<= 1) {
    int u = __shfl_up(inc, off);
    if (lane >= off) inc += u;
  }
  __shared__ int wsum[4];
  if (lane == 63) wsum[wv] = inc;
  __syncthreads();
  int woff = 0;
  for (int i = 0; i < wv; ++i) woff += wsum[i];
  int excl = woff + (inc - s) + partials[blockIdx.x];
  int4 rp;
  rp.x = excl;
  rp.y = rp.x + v.x;
  rp.z = rp.y + v.y;
  rp.w = rp.z + v.z;
  if (base + 3 < n) {
    *(int4*)(outp + base) = rp;
  } else {
    int* pr = &rp.x;
    for (int i = 0; i < 4; ++i) if (base + i < n) outp[base + i] = pr[i];
  }
}

// ---------------- bucket scatter: pairs[pos] = (dst&255)<<24 | src ----------------

__global__ __launch_bounds__(256) void bucket_scatter(const int* __restrict__ s0v, const int* __restrict__ d0,
                                                      const int* __restrict__ s1v, const int* __restrict__ d1,
                                                      const int* __restrict__ s2v, const int* __restrict__ d2,
                                                      const int* __restrict__ mscan, unsigned int* __restrict__ pairs) {
  int gid = blockIdx.x >> 8;
  int g   = blockIdx.x & 255;
  const int* src = gid == 0 ? s0v : (gid == 1 ? s1v : s2v);
  const int* dst = gid == 0 ? d0  : (gid == 1 ? d1  : d2);
  int E    = (gid == 2) ? E_UU : E_UI;
  int NB   = (gid == 0) ? NB0 : NB1;
  int boff = (gid == 0) ? 0 : (gid == 1 ? NB0 : NB0 + NB1);
  __shared__ int cur[NB0];
  for (int b = threadIdx.x; b < NB; b += 256) cur[b] = mscan[(boff + b) * 256 + g];
  __syncthreads();
  int chunk = (E + 255) >> 8;
  int lo = g * chunk, hi = min(lo + chunk, E);
  for (int i = lo + threadIdx.x; i < hi; i += 256) {
    int d = dst[i], s = src[i];
    int pos = atomicAdd(&cur[d >> 8], 1);
    pairs[pos] = ((unsigned)(d & 255) << 24) | (unsigned)s;
  }
}

// ---------------- bucket finalize: emit rp + scatter col within bucket ----------------
// one block per global bucket; nodes of bucket = 256 consecutive local ids.

__global__ __launch_bounds__(256) void bucket_finalize(const unsigned int* __restrict__ pairs,
                                                       const int* __restrict__ mscan,
                                                       int* __restrict__ rp, int* __restrict__ col) {
  int gb = blockIdx.x;
  int t  = threadIdx.x;
  int gid  = (gb < NB0) ? 0 : (gb < NB0 + NB1 ? 1 : 2);
  int boff = (gid == 0) ? 0 : (gid == 1 ? NB0 : NB0 + NB1);
  int node_goff = (gid == 0) ? 0 : (gid == 1 ? N_ITEM : N_ITEM + N_USER);
  int n    = (gid == 0) ? N_ITEM : N_USER;
  int b_local = gb - boff;
  int bs = mscan[gb * 256];
  int be = (gb + 1 < NBTOT) ? mscan[(gb + 1) * 256] : E_TOT;

  __shared__ int cnt[256];
  __shared__ int curb[256];
  __shared__ int wsum[4];
  cnt[t] = 0;
  __syncthreads();
  for (int i = bs + t; i < be; i += 256)
    atomicAdd(&cnt[pairs[i] >> 24], 1);
  __syncthreads();

  int v = cnt[t];
  int lane = t & 63, wv = t >> 6;
  int inc = v;
  #pragma unroll
  for (int off = 1; off < 64; off <<= 1) {
    int u = __shfl_up(inc, off);
    if (lane >= off) inc += u;
  }
  if (lane == 63) wsum[wv] = inc;
  __syncthreads();
  int woff = 0;
  for (int i = 0; i < wv; ++i) woff += wsum[i];
  int base = bs + woff + (inc - v);   // exclusive prefix within bucket, global edge position

  int node_local = b_local * 256 + t;
  if (node_local < n) rp[node_goff + node_local] = base;
  if (gb == NBTOT - 1 && t == 255) rp[N_ITEM + 2 * N_USER] = E_TOT;
  curb[t] = base;
  __syncthreads();

  for (int i = bs + t; i < be; i += 256) {
    unsigned u = pairs[i];
    int p = atomicAdd(&curb[u >> 24], 1);
    col[p] = (int)(u & 0xFFFFFFu);
  }
}

// ---------------- node GEMM: Y[N,64] = X[N,64] @ W[64,64] ----------------

__global__ __launch_bounds__(256) void gemm64(const float* __restrict__ X, const float* __restrict__ W,
                                              float* __restrict__ Y, int N) {
  __shared__ float Ws[64 * 64];
  #pragma unroll
  for (int i = 0; i < 4; ++i) {
    int idx = threadIdx.x * 4 + i * 1024;
    *(float4*)(Ws + idx) = *(const float4*)(W + idx);
  }
  __syncthreads();
  int c4 = (threadIdx.x & 15) * 4;
  int rl = threadIdx.x >> 4;
  int base = blockIdx.x * 64;
  int r0 = base + rl, r1 = r0 + 16, r2 = r0 + 32, r3 = r0 + 48;
  const float* x0 = X + (size_t)(r0 < N ? r0 : N - 1) * 64;
  const float* x1 = X + (size_t)(r1 < N ? r1 : N - 1) * 64;
  const float* x2 = X + (size_t)(r2 < N ? r2 : N - 1) * 64;
  const float* x3 = X + (size_t)(r3 < N ? r3 : N - 1) * 64;
  float4 acc0 = make_float4(0.f, 0.f, 0.f, 0.f);
  float4 acc1 = acc0, acc2 = acc0, acc3 = acc0;

  #pragma unroll
  for (int k4 = 0; k4 < 64; k4 += 4) {
    float4 xa = *(const float4*)(x0 + k4);
    float4 xb = *(const float4*)(x1 + k4);
    float4 xc = *(const float4*)(x2 + k4);
    float4 xd = *(const float4*)(x3 + k4);
    #pragma unroll
    for (int kk = 0; kk < 4; ++kk) {
      float4 w = *(const float4*)(Ws + (k4 + kk) * 64 + c4);
      float sa = (&xa.x)[kk], sb = (&xb.x)[kk], sc = (&xc.x)[kk], sd = (&xd.x)[kk];
      acc0.x = fmaf(sa, w.x, acc0.x); acc0.y = fmaf(sa, w.y, acc0.y);
      acc0.z = fmaf(sa, w.z, acc0.z); acc0.w = fmaf(sa, w.w, acc0.w);
      acc1.x = fmaf(sb, w.x, acc1.x); acc1.y = fmaf(sb, w.y, acc1.y);
      acc1.z = fmaf(sb, w.z, acc1.z); acc1.w = fmaf(sb, w.w, acc1.w);
      acc2.x = fmaf(sc, w.x, acc2.x); acc2.y = fmaf(sc, w.y, acc2.y);
      acc2.z = fmaf(sc, w.z, acc2.z); acc2.w = fmaf(sc, w.w, acc2.w);
      acc3.x = fmaf(sd, w.x, acc3.x); acc3.y = fmaf(sd, w.y, acc3.y);
      acc3.z = fmaf(sd, w.z, acc3.z); acc3.w = fmaf(sd, w.w, acc3.w);
    }
  }
  if (r0 < N) *(float4*)(Y + (size_t)r0 * 64 + c4) = acc0;
  if (r1 < N) *(float4*)(Y + (size_t)r1 * 64 + c4) = acc1;
  if (r2 < N) *(float4*)(Y + (size_t)r2 * 64 + c4) = acc2;
  if (r3 < N) *(float4*)(Y + (size_t)r3 * 64 + c4) = acc3;
}

// ---------------- GATv2: wave per dst node, 4x16-lane groups, 4 edges/iter ----------------
// Safe with out == hd (wave only touches row `wid` of hd/out).

__global__ __launch_bounds__(256) void gat_kernel(const float* __restrict__ hs, const float* __restrict__ hd,
                                                  const int* __restrict__ row_ptr, const int* __restrict__ col,
                                                  const float* __restrict__ attn, const float* __restrict__ bias,
                                                  float* __restrict__ out, int Nd) {
  int wid = (blockIdx.x * blockDim.x + threadIdx.x) >> 6;
  int lane = threadIdx.x & 63;
  if (wid >= Nd) return;
  int g = lane >> 4;        // edge group 0..3
  int sl = lane & 15;       // dim group: dims sl*4 .. sl*4+3
  int s0 = row_ptr[wid];
  int s1 = row_ptr[wid + 1];

  float4 hd4 = *(const float4*)(hd + (size_t)wid * 64 + sl * 4);
  float4 a4  = *(const float4*)(attn + sl * 4);

  float m = -INFINITY, den = 0.f;
  float4 num = make_float4(0.f, 0.f, 0.f, 0.f);

  for (int e = s0 + g; e < s1; e += 4) {
    int s = col[e];
    float4 h4 = *(const float4*)(hs + (size_t)s * 64 + sl * 4);
    float px = h4.x + hd4.x; px = px > 0.f ? px : NEG_SLOPE * px;
    float py = h4.y + hd4.y; py = py > 0.f ? py : NEG_SLOPE * py;
    float pz = h4.z + hd4.z; pz = pz > 0.f ? pz : NEG_SLOPE * pz;
    float pw = h4.w + hd4.w; pw = pw > 0.f ? pw : NEG_SLOPE * pw;
    float t = a4.x * px;
    t = fmaf(a4.y, py, t);
    t = fmaf(a4.z, pz, t);
    t = fmaf(a4.w, pw, t);
    #pragma unroll
    for (int off = 1; off < 16; off <<= 1) t += __shfl_xor(t, off);

    float mn = fmaxf(m, t);
    float sc = (m == mn) ? 1.f : __expf(m - mn);
    float p  = __expf(t - mn);
    den = den * sc + p;
    num.x = fmaf(num.x, sc, h4.x * p);
    num.y = fmaf(num.y, sc, h4.y * p);
    num.z = fmaf(num.z, sc, h4.z * p);
    num.w = fmaf(num.w, sc, h4.w * p);
    m = mn;
  }

  #pragma unroll
  for (int off = 16; off <= 32; off <<= 1) {
    float m2 = __shfl_xor(m, off);
    float d2 = __shfl_xor(den, off);
    float nx = __shfl_xor(num.x, off);
    float ny = __shfl_xor(num.y, off);
    float nz = __shfl_xor(num.z, off);
    float nw = __shfl_xor(num.w, off);
    float mn = fmaxf(m, m2);
    float sA = (m == mn) ? 1.f : __expf(m - mn);
    float sB = (m2 == mn) ? 1.f : __expf(m2 - mn);
    den = den * sA + d2 * sB;
    num.x = num.x * sA + nx * sB;
    num.y = num.y * sA + ny * sB;
    num.z = num.z * sA + nz * sB;
    num.w = num.w * sA + nw * sB;
    m = mn;
  }

  if (g == 0) {
    float inv = 1.f / fmaxf(den, 1e-9f);
    float4 b4 = *(const float4*)(bias + sl * 4);
    float4 o;
    o.x = fmaf(num.x, inv, b4.x);
    o.y = fmaf(num.y, inv, b4.y);
    o.z = fmaf(num.z, inv, b4.z);
    o.w = fmaf(num.w, inv, b4.w);
    *(float4*)(out + (size_t)wid * 64 + sl * 4) = o;
  }
}

// ---------------- final: out = [A|B] @ Wout + bout ----------------

__global__ __launch_bounds__(256) void final_kernel(const float* __restrict__ A, const float* __restrict__ B,
                                                    const float* __restrict__ W, const float* __restrict__ bias,
                                                    float* __restrict__ Y, int N) {
  __shared__ float Ws[128 * 64];
  #pragma unroll
  for (int i = 0; i < 8; ++i) {
    int idx = threadIdx.x * 4 + i * 1024;
    *(float4*)(Ws + idx) = *(const float4*)(W + idx);
  }
  __syncthreads();
  int c4 = (threadIdx.x & 15) * 4;
  int rl = threadIdx.x >> 4;
  int base = blockIdx.x * 64;

  float4 b4 = *(const float4*)(bias + c4);

  #pragma unroll
  for (int rr = 0; rr < 4; ++rr) {
    int row = base + rr * 16 + rl;
    if (row >= N) continue;
    const float* ar = A + (size_t)row * 64;
    const float* br = B + (size_t)row * 64;
    float4 acc = b4;
    #pragma unroll
    for (int k4 = 0; k4 < 64; k4 += 4) {
      float4 xa = *(const float4*)(ar + k4);
      float4 xb = *(const float4*)(br + k4);
      #pragma unroll
      for (int kk = 0; kk < 4; ++kk) {
        float4 wa = *(const float4*)(Ws + (k4 + kk) * 64 + c4);
        float4 wb = *(const float4*)(Ws + (64 + k4 + kk) * 64 + c4);
        float xsa = (&xa.x)[kk], xsb = (&xb.x)[kk];
        acc.x = fmaf(xsa, wa.x, acc.x); acc.x = fmaf(xsb, wb.x, acc.x);
        acc.y = fmaf(xsa, wa.y, acc.y); acc.y = fmaf(xsb, wb.y, acc.y);
        acc.z = fmaf(xsa, wa.z, acc.z); acc.z = fmaf(xsb, wb.z, acc.z);
        acc.w = fmaf(xsa, wa.w, acc.w); acc.w = fmaf(xsb, wb.w, acc.w);
      }
    }
    *(float4*)(Y + (size_t)row * 64 + c4) = acc;
  }
}

// ---------------- launch ----------------

extern "C" void kernel_launch(void* const* d_in, const int* in_sizes, int n_in,
                              void* d_out, int out_size, void* d_ws, size_t ws_size,
                              hipStream_t stream) {
  const float* h_user   = (const float*)d_in[0];
  const float* h_item   = (const float*)d_in[1];
  const int* rate_src   = (const int*)d_in[2];
  const int* rate_dst   = (const int*)d_in[3];
  const int* rb_src     = (const int*)d_in[4];
  const int* rb_dst     = (const int*)d_in[5];
  const int* link_src   = (const int*)d_in[6];
  const int* link_dst   = (const int*)d_in[7];
  const float* w_src_r1  = (const float*)d_in[8];
  const float* w_dst_r1  = (const float*)d_in[9];
  const float* a_r1      = (const float*)d_in[10];
  const float* b_r1      = (const float*)d_in[11];
  const float* w_src_rb1 = (const float*)d_in[12];
  const float* w_dst_rb1 = (const float*)d_in[13];
  const float* a_rb1     = (const float*)d_in[14];
  const float* b_rb1     = (const float*)d_in[15];
  const float* w_src_rb2 = (const float*)d_in[16];
  const float* w_dst_rb2 = (const float*)d_in[17];
  const float* a_rb2     = (const float*)d_in[18];
  const float* b_rb2     = (const float*)d_in[19];
  const float* w_src_l2  = (const float*)d_in[20];
  const float* w_dst_l2  = (const float*)d_in[21];
  const float* a_l2      = (const float*)d_in[22];
  const float* b_l2      = (const float*)d_in[23];
  const float* w_out     = (const float*)d_in[24];
  const float* b_out     = (const float*)d_in[25];
  float* out = (float*)d_out;

  char* ws = (char*)d_ws;
  size_t off = 0;
  auto alloc = [&](size_t bytes) -> void* {
    void* p = ws + off;
    off += (bytes + 255) & ~(size_t)255;
    return p;
  };

  float* u0 = (float*)alloc((size_t)N_USER * 64 * 4);
  float* u1 = (float*)alloc((size_t)N_USER * 64 * 4);
  float* u2 = (float*)alloc((size_t)N_USER * 64 * 4);
  float* u3 = (float*)alloc((size_t)N_USER * 64 * 4);
  float* i0 = (float*)alloc((size_t)N_ITEM * 64 * 4);
  float* i1 = (float*)alloc((size_t)N_ITEM * 64 * 4);

  // CSR scratch (global/concatenated)
  int* mat     = (int*)alloc((size_t)MATN * 4);
  int* mscan   = (int*)alloc((size_t)MATN * 4);
  int* partials= (int*)alloc(256 * 4);
  int* grp     = (int*)alloc((size_t)(N_ITEM + 2 * N_USER + 1) * 4);  // global row_ptr
  unsigned int* pairs = (unsigned int*)alloc((size_t)E_TOT * 4);
  int* col_all = (int*)alloc((size_t)E_TOT * 4);

  // ---- bucketed CSR build ----
  bucket_hist<<<3 * GPB, 256, 0, stream>>>(rate_dst, rb_dst, link_dst, mat);
  {
    int nb = (MATN + 1023) / 1024;   // 196
    partial_kernel<<<nb, 256, 0, stream>>>(mat, MATN, partials);
    scan_partials256<<<1, 256, 0, stream>>>(partials, nb);
    scan_apply_one<<<nb, 256, 0, stream>>>(mat, MATN, partials, mscan);
  }
  bucket_scatter<<<3 * GPB, 256, 0, stream>>>(rate_src, rate_dst, rb_src, rb_dst,
                                              link_src, link_dst, mscan, pairs);
  bucket_finalize<<<NBTOT, 256, 0, stream>>>(pairs, mscan, grp, col_all);

  int* rp_rate = grp;                      // item-dst graph: global nodes [0,100000]
  int* rp_rb   = grp + N_ITEM;             // user-dst: [100000,150000]
  int* rp_link = grp + N_ITEM + N_USER;    // user-dst: [150000,200000]

  // ---- node GEMMs ----
  auto gemm = [&](const float* X, const float* W, float* Y, int N) {
    gemm64<<<(N + 63) / 64, 256, 0, stream>>>(X, W, Y, N);
  };
  gemm(h_user, w_src_r1,  u0, N_USER);
  gemm(h_user, w_dst_rb1, u1, N_USER);
  gemm(h_user, w_dst_rb2, u2, N_USER);
  gemm(h_user, w_dst_l2,  u3, N_USER);
  gemm(h_item, w_dst_r1,  i0, N_ITEM);
  gemm(h_item, w_src_rb1, i1, N_ITEM);

  // ---- GAT layers (out aliases hd: safe, wave-local row); col values are src ids ----
  // layer1 'rate': user -> item ; h1_item := i0
  gat_kernel<<<(N_ITEM + 3) / 4, 256, 0, stream>>>(u0, i0, rp_rate, col_all, a_r1, b_r1, i0, N_ITEM);
  // layer1 'rated-by': item -> user ; h2_user := u1
  gat_kernel<<<(N_USER + 3) / 4, 256, 0, stream>>>(i1, u1, rp_rb, col_all, a_rb1, b_rb1, u1, N_USER);
  // layer2 'rated-by' src transform: i1 := h1_item @ w_src_rb2
  gemm(i0, w_src_rb2, i1, N_ITEM);
  // layer2 'rated-by': item -> user ; infl := u2
  gat_kernel<<<(N_USER + 3) / 4, 256, 0, stream>>>(i1, u2, rp_rb, col_all, a_rb2, b_rb2, u2, N_USER);
  // layer2 'link' src transform: u0 := h2_user @ w_src_l2
  gemm(u1, w_src_l2, u0, N_USER);
  // layer2 'link': user -> user ; social := u3
  gat_kernel<<<(N_USER + 3) / 4, 256, 0, stream>>>(u0, u3, rp_link, col_all, a_l2, b_l2, u3, N_USER);

  // ---- output projection ----
  final_kernel<<<(N_USER + 63) / 64, 256, 0, stream>>>(u2, u3, w_out, b_out, out, N_USER);
}

// Round 7
// 478.413 us; speedup vs baseline: 3.4581x; 1.1050x over previous
//
#include <hip/hip_runtime.h>
#include <hip/hip_fp16.h>
#include <math.h>

#define N_USER 50000
#define N_ITEM 100000
#define E_UI   1000000
#define E_UU   800000
#define E_TOT  (E_UI + E_UI + E_UU)
#define NEG_SLOPE 0.2f

// Bucketed CSR build: bucket = dst >> 8 (256 nodes/bucket).
#define NB0 391
#define NB1 196
#define NB2 196
#define NBTOT (NB0 + NB1 + NB2)   // 783
#define GPB 256
#define MATN (NBTOT * 256)        // 200448

typedef _Float16 h2v __attribute__((ext_vector_type(2)));

#if defined(__has_builtin)
#if __has_builtin(__builtin_amdgcn_fdot2)
#define HAS_FDOT2 1
#endif
#if __has_builtin(__builtin_elementwise_max)
#define HAS_EW_MAX 1
#endif
#endif

__device__ __forceinline__ float fdot2acc(__half2 a, __half2 b, float c) {
#ifdef HAS_FDOT2
  return __builtin_amdgcn_fdot2(__builtin_bit_cast(h2v, a), __builtin_bit_cast(h2v, b), c, false);
#else
  float2 af = __half22float2(a), bf = __half22float2(b);
  return fmaf(af.x, bf.x, fmaf(af.y, bf.y, c));
#endif
}

__device__ __forceinline__ __half2 h2max(__half2 a, __half2 b) {
  h2v av = __builtin_bit_cast(h2v, a), bv = __builtin_bit_cast(h2v, b);
#ifdef HAS_EW_MAX
  h2v r = __builtin_elementwise_max(av, bv);
#else
  h2v r; r.x = av.x > bv.x ? av.x : bv.x; r.y = av.y > bv.y ? av.y : bv.y;
#endif
  return __builtin_bit_cast(__half2, r);
}

__device__ __forceinline__ __half2 h2min(__half2 a, __half2 b) {
  h2v av = __builtin_bit_cast(h2v, a), bv = __builtin_bit_cast(h2v, b);
#ifdef HAS_EW_MAX
  h2v r = __builtin_elementwise_min(av, bv);
#else
  h2v r; r.x = av.x < bv.x ? av.x : bv.x; r.y = av.y < bv.y ? av.y : bv.y;
#endif
  return __builtin_bit_cast(__half2, r);
}

// ---------------- bucket histogram ----------------

__global__ __launch_bounds__(256) void bucket_hist(const int* __restrict__ d0, const int* __restrict__ d1,
                                                   const int* __restrict__ d2, int* __restrict__ mat) {
  int gid = blockIdx.x >> 8;
  int g   = blockIdx.x & 255;
  const int* dst = gid == 0 ? d0 : (gid == 1 ? d1 : d2);
  int E    = (gid == 2) ? E_UU : E_UI;
  int NB   = (gid == 0) ? NB0 : NB1;
  int boff = (gid == 0) ? 0 : (gid == 1 ? NB0 : NB0 + NB1);
  __shared__ int cnt[NB0];
  for (int b = threadIdx.x; b < NB; b += 256) cnt[b] = 0;
  __syncthreads();
  int chunk = (E + 255) >> 8;
  int lo = g * chunk, hi = min(lo + chunk, E);
  for (int i = lo + threadIdx.x; i < hi; i += 256)
    atomicAdd(&cnt[dst[i] >> 8], 1);
  __syncthreads();
  for (int b = threadIdx.x; b < NB; b += 256)
    mat[(boff + b) * 256 + g] = cnt[b];
}

// ---------------- hierarchical exclusive scan over mat ----------------

__global__ __launch_bounds__(256) void partial_kernel(const int* __restrict__ counts, int n,
                                                      int* __restrict__ partials) {
  int t = threadIdx.x;
  int base = blockIdx.x * 1024 + t * 4;
  int s = 0;
  if (base + 3 < n) {
    int4 v = *(const int4*)(counts + base);
    s = v.x + v.y + v.z + v.w;
  } else {
    for (int i = base; i < n && i < base + 4; ++i) s += counts[i];
  }
  #pragma unroll
  for (int off = 1; off < 64; off <<= 1) s += __shfl_xor(s, off);
  __shared__ int ws[4];
  if ((t & 63) == 0) ws[t >> 6] = s;
  __syncthreads();
  if (t == 0) partials[blockIdx.x] = ws[0] + ws[1] + ws[2] + ws[3];
}

__global__ __launch_bounds__(256) void scan_partials256(int* __restrict__ partials, int nb) {
  __shared__ int s[256];
  int t = threadIdx.x;
  s[t] = (t < nb) ? partials[t] : 0;
  __syncthreads();
  for (int off = 1; off < 256; off <<= 1) {
    int v = (t >= off) ? s[t - off] : 0;
    __syncthreads();
    s[t] += v;
    __syncthreads();
  }
  if (t < nb) partials[t] = (t == 0) ? 0 : s[t - 1];
}

__global__ __launch_bounds__(256) void scan_apply_one(const int* __restrict__ counts, int n,
                                                      const int* __restrict__ partials,
                                                      int* __restrict__ outp) {
  int t = threadIdx.x;
  int base = blockIdx.x * 1024 + t * 4;
  int4 v = make_int4(0, 0, 0, 0);
  if (base + 3 < n) {
    v = *(const int4*)(counts + base);
  } else {
    int* pv = &v.x;
    for (int i = 0; i < 4; ++i) if (base + i < n) pv[i] = counts[base + i];
  }
  int s = v.x + v.y + v.z + v.w;
  int lane = t & 63;
  int wv = t >> 6;
  int inc = s;
  #pragma unroll
  for (int off = 1; off < 64; off <<= 1) {
    int u = __shfl_up(inc, off);
    if (lane >= off) inc += u;
  }
  __shared__ int wsum[4];
  if (lane == 63) wsum[wv] = inc;
  __syncthreads();
  int woff = 0;
  for (int i = 0; i < wv; ++i) woff += wsum[i];
  int excl = woff + (inc - s) + partials[blockIdx.x];
  int4 rp;
  rp.x = excl;
  rp.y = rp.x + v.x;
  rp.z = rp.y + v.y;
  rp.w = rp.z + v.z;
  if (base + 3 < n) {
    *(int4*)(outp + base) = rp;
  } else {
    int* pr = &rp.x;
    for (int i = 0; i < 4; ++i) if (base + i < n) outp[base + i] = pr[i];
  }
}

// ---------------- bucket scatter ----------------

__global__ __launch_bounds__(256) void bucket_scatter(const int* __restrict__ s0v, const int* __restrict__ d0,
                                                      const int* __restrict__ s1v, const int* __restrict__ d1,
                                                      const int* __restrict__ s2v, const int* __restrict__ d2,
                                                      const int* __restrict__ mscan, unsigned int* __restrict__ pairs) {
  int gid = blockIdx.x >> 8;
  int g   = blockIdx.x & 255;
  const int* src = gid == 0 ? s0v : (gid == 1 ? s1v : s2v);
  const int* dst = gid == 0 ? d0  : (gid == 1 ? d1  : d2);
  int E    = (gid == 2) ? E_UU : E_UI;
  int NB   = (gid == 0) ? NB0 : NB1;
  int boff = (gid == 0) ? 0 : (gid == 1 ? NB0 : NB0 + NB1);
  __shared__ int cur[NB0];
  for (int b = threadIdx.x; b < NB; b += 256) cur[b] = mscan[(boff + b) * 256 + g];
  __syncthreads();
  int chunk = (E + 255) >> 8;
  int lo = g * chunk, hi = min(lo + chunk, E);
  for (int i = lo + threadIdx.x; i < hi; i += 256) {
    int d = dst[i], s = src[i];
    int pos = atomicAdd(&cur[d >> 8], 1);
    pairs[pos] = ((unsigned)(d & 255) << 24) | (unsigned)s;
  }
}

// ---------------- bucket finalize ----------------

__global__ __launch_bounds__(256) void bucket_finalize(const unsigned int* __restrict__ pairs,
                                                       const int* __restrict__ mscan,
                                                       int* __restrict__ rp, int* __restrict__ col) {
  int gb = blockIdx.x;
  int t  = threadIdx.x;
  int gid  = (gb < NB0) ? 0 : (gb < NB0 + NB1 ? 1 : 2);
  int boff = (gid == 0) ? 0 : (gid == 1 ? NB0 : NB0 + NB1);
  int node_goff = (gid == 0) ? 0 : (gid == 1 ? N_ITEM : N_ITEM + N_USER);
  int n    = (gid == 0) ? N_ITEM : N_USER;
  int b_local = gb - boff;
  int bs = mscan[gb * 256];
  int be = (gb + 1 < NBTOT) ? mscan[(gb + 1) * 256] : E_TOT;

  __shared__ int cnt[256];
  __shared__ int curb[256];
  __shared__ int wsum[4];
  cnt[t] = 0;
  __syncthreads();
  for (int i = bs + t; i < be; i += 256)
    atomicAdd(&cnt[pairs[i] >> 24], 1);
  __syncthreads();

  int v = cnt[t];
  int lane = t & 63, wv = t >> 6;
  int inc = v;
  #pragma unroll
  for (int off = 1; off < 64; off <<= 1) {
    int u = __shfl_up(inc, off);
    if (lane >= off) inc += u;
  }
  if (lane == 63) wsum[wv] = inc;
  __syncthreads();
  int woff = 0;
  for (int i = 0; i < wv; ++i) woff += wsum[i];
  int base = bs + woff + (inc - v);

  int node_local = b_local * 256 + t;
  if (node_local < n) rp[node_goff + node_local] = base;
  if (gb == NBTOT - 1 && t == 255) rp[N_ITEM + 2 * N_USER] = E_TOT;
  curb[t] = base;
  __syncthreads();

  for (int i = bs + t; i < be; i += 256) {
    unsigned u = pairs[i];
    int p = atomicAdd(&curb[u >> 24], 1);
    col[p] = (int)(u & 0xFFFFFFu);
  }
}

// ---------------- node GEMM: Y[N,64] = X[N,64] @ W[64,64] (f32 out) ----------------

__global__ __launch_bounds__(256) void gemm64(const float* __restrict__ X, const float* __restrict__ W,
                                              float* __restrict__ Y, int N) {
  __shared__ float Ws[64 * 64];
  #pragma unroll
  for (int i = 0; i < 4; ++i) {
    int idx = threadIdx.x * 4 + i * 1024;
    *(float4*)(Ws + idx) = *(const float4*)(W + idx);
  }
  __syncthreads();
  int c4 = (threadIdx.x & 15) * 4;
  int rl = threadIdx.x >> 4;
  int base = blockIdx.x * 64;
  int r0 = base + rl, r1 = r0 + 16, r2 = r0 + 32, r3 = r0 + 48;
  const float* x0 = X + (size_t)(r0 < N ? r0 : N - 1) * 64;
  const float* x1 = X + (size_t)(r1 < N ? r1 : N - 1) * 64;
  const float* x2 = X + (size_t)(r2 < N ? r2 : N - 1) * 64;
  const float* x3 = X + (size_t)(r3 < N ? r3 : N - 1) * 64;
  float4 acc0 = make_float4(0.f, 0.f, 0.f, 0.f);
  float4 acc1 = acc0, acc2 = acc0, acc3 = acc0;

  #pragma unroll
  for (int k4 = 0; k4 < 64; k4 += 4) {
    float4 xa = *(const float4*)(x0 + k4);
    float4 xb = *(const float4*)(x1 + k4);
    float4 xc = *(const float4*)(x2 + k4);
    float4 xd = *(const float4*)(x3 + k4);
    #pragma unroll
    for (int kk = 0; kk < 4; ++kk) {
      float4 w = *(const float4*)(Ws + (k4 + kk) * 64 + c4);
      float sa = (&xa.x)[kk], sb = (&xb.x)[kk], sc = (&xc.x)[kk], sd = (&xd.x)[kk];
      acc0.x = fmaf(sa, w.x, acc0.x); acc0.y = fmaf(sa, w.y, acc0.y);
      acc0.z = fmaf(sa, w.z, acc0.z); acc0.w = fmaf(sa, w.w, acc0.w);
      acc1.x = fmaf(sb, w.x, acc1.x); acc1.y = fmaf(sb, w.y, acc1.y);
      acc1.z = fmaf(sb, w.z, acc1.z); acc1.w = fmaf(sb, w.w, acc1.w);
      acc2.x = fmaf(sc, w.x, acc2.x); acc2.y = fmaf(sc, w.y, acc2.y);
      acc2.z = fmaf(sc, w.z, acc2.z); acc2.w = fmaf(sc, w.w, acc2.w);
      acc3.x = fmaf(sd, w.x, acc3.x); acc3.y = fmaf(sd, w.y, acc3.y);
      acc3.z = fmaf(sd, w.z, acc3.z); acc3.w = fmaf(sd, w.w, acc3.w);
    }
  }
  if (r0 < N) *(float4*)(Y + (size_t)r0 * 64 + c4) = acc0;
  if (r1 < N) *(float4*)(Y + (size_t)r1 * 64 + c4) = acc1;
  if (r2 < N) *(float4*)(Y + (size_t)r2 * 64 + c4) = acc2;
  if (r3 < N) *(float4*)(Y + (size_t)r3 * 64 + c4) = acc3;
}

// ---------------- node GEMM with f16 output (hs buffers) ----------------

__global__ __launch_bounds__(256) void gemm64h(const float* __restrict__ X, const float* __restrict__ W,
                                               __half* __restrict__ Y, int N) {
  __shared__ float Ws[64 * 64];
  #pragma unroll
  for (int i = 0; i < 4; ++i) {
    int idx = threadIdx.x * 4 + i * 1024;
    *(float4*)(Ws + idx) = *(const float4*)(W + idx);
  }
  __syncthreads();
  int c4 = (threadIdx.x & 15) * 4;
  int rl = threadIdx.x >> 4;
  int base = blockIdx.x * 64;
  int r0 = base + rl, r1 = r0 + 16, r2 = r0 + 32, r3 = r0 + 48;
  const float* x0 = X + (size_t)(r0 < N ? r0 : N - 1) * 64;
  const float* x1 = X + (size_t)(r1 < N ? r1 : N - 1) * 64;
  const float* x2 = X + (size_t)(r2 < N ? r2 : N - 1) * 64;
  const float* x3 = X + (size_t)(r3 < N ? r3 : N - 1) * 64;
  float4 acc0 = make_float4(0.f, 0.f, 0.f, 0.f);
  float4 acc1 = acc0, acc2 = acc0, acc3 = acc0;

  #pragma unroll
  for (int k4 = 0; k4 < 64; k4 += 4) {
    float4 xa = *(const float4*)(x0 + k4);
    float4 xb = *(const float4*)(x1 + k4);
    float4 xc = *(const float4*)(x2 + k4);
    float4 xd = *(const float4*)(x3 + k4);
    #pragma unroll
    for (int kk = 0; kk < 4; ++kk) {
      float4 w = *(const float4*)(Ws + (k4 + kk) * 64 + c4);
      float sa = (&xa.x)[kk], sb = (&xb.x)[kk], sc = (&xc.x)[kk], sd = (&xd.x)[kk];
      acc0.x = fmaf(sa, w.x, acc0.x); acc0.y = fmaf(sa, w.y, acc0.y);
      acc0.z = fmaf(sa, w.z, acc0.z); acc0.w = fmaf(sa, w.w, acc0.w);
      acc1.x = fmaf(sb, w.x, acc1.x); acc1.y = fmaf(sb, w.y, acc1.y);
      acc1.z = fmaf(sb, w.z, acc1.z); acc1.w = fmaf(sb, w.w, acc1.w);
      acc2.x = fmaf(sc, w.x, acc2.x); acc2.y = fmaf(sc, w.y, acc2.y);
      acc2.z = fmaf(sc, w.z, acc2.z); acc2.w = fmaf(sc, w.w, acc2.w);
      acc3.x = fmaf(sd, w.x, acc3.x); acc3.y = fmaf(sd, w.y, acc3.y);
      acc3.z = fmaf(sd, w.z, acc3.z); acc3.w = fmaf(sd, w.w, acc3.w);
    }
  }
  uint2 st;
  if (r0 < N) {
    st.x = __builtin_bit_cast(unsigned int, __floats2half2_rn(acc0.x, acc0.y));
    st.y = __builtin_bit_cast(unsigned int, __floats2half2_rn(acc0.z, acc0.w));
    *(uint2*)(Y + (size_t)r0 * 64 + c4) = st;
  }
  if (r1 < N) {
    st.x = __builtin_bit_cast(unsigned int, __floats2half2_rn(acc1.x, acc1.y));
    st.y = __builtin_bit_cast(unsigned int, __floats2half2_rn(acc1.z, acc1.w));
    *(uint2*)(Y + (size_t)r1 * 64 + c4) = st;
  }
  if (r2 < N) {
    st.x = __builtin_bit_cast(unsigned int, __floats2half2_rn(acc2.x, acc2.y));
    st.y = __builtin_bit_cast(unsigned int, __floats2half2_rn(acc2.z, acc2.w));
    *(uint2*)(Y + (size_t)r2 * 64 + c4) = st;
  }
  if (r3 < N) {
    st.x = __builtin_bit_cast(unsigned int, __floats2half2_rn(acc3.x, acc3.y));
    st.y = __builtin_bit_cast(unsigned int, __floats2half2_rn(acc3.z, acc3.w));
    *(uint2*)(Y + (size_t)r3 * 64 + c4) = st;
  }
}

// ---------------- fused GATv2 (two independent graphs per dispatch) ----------------
// wave per dst node; 4 groups x 16 lanes; 2 edges per group per iteration; f16 hs;
// defer-max online softmax (rescale only when max grows by >8). out may alias hd.

__global__ __launch_bounds__(256) void gat2x_kernel(
    const __half* __restrict__ hsA, const float* __restrict__ hdAp,
    const int* __restrict__ rpA, const float* __restrict__ attnA, const float* __restrict__ biasA,
    float* __restrict__ outA, int NdA,
    const __half* __restrict__ hsB, const float* __restrict__ hdBp,
    const int* __restrict__ rpB, const float* __restrict__ attnB, const float* __restrict__ biasB,
    float* __restrict__ outB, int NdB,
    const int* __restrict__ col) {
  int wid = (blockIdx.x * blockDim.x + threadIdx.x) >> 6;
  int lane = threadIdx.x & 63;
  int g = lane >> 4;        // edge group 0..3
  int sl = lane & 15;       // dims sl*4 .. sl*4+3
  const __half* hs; const float* hd; const int* rp;
  const float* attn; const float* bias; float* outp; int node;
  if (wid < NdA) {
    hs = hsA; hd = hdAp; rp = rpA; attn = attnA; bias = biasA; outp = outA; node = wid;
  } else {
    if (wid >= NdA + NdB) return;
    hs = hsB; hd = hdBp; rp = rpB; attn = attnB; bias = biasB; outp = outB; node = wid - NdA;
  }
  int s0 = rp[node], s1 = rp[node + 1];

  float4 hdf = *(const float4*)(hd + (size_t)node * 64 + sl * 4);
  float4 af  = *(const float4*)(attn + sl * 4);
  __half2 hd2a = __floats2half2_rn(hdf.x, hdf.y);
  __half2 hd2b = __floats2half2_rn(hdf.z, hdf.w);
  __half2 a2a = __floats2half2_rn(af.x, af.y);
  __half2 a2b = __floats2half2_rn(af.z, af.w);
  const __half2 C02 = __floats2half2_rn(NEG_SLOPE, NEG_SLOPE);
  const __half2 Z   = __floats2half2_rn(0.f, 0.f);

  float m = -1e30f, den = 0.f;
  float n0 = 0.f, n1 = 0.f, n2 = 0.f, n3 = 0.f;

  for (int e = s0 + g; e < s1; e += 8) {
    int eb = e + 4;
    bool has2 = eb < s1;
    int sa = col[e];
    int sb = col[has2 ? eb : e];
    uint2 ra = *(const uint2*)(hs + (size_t)sa * 64 + sl * 4);
    uint2 rb = *(const uint2*)(hs + (size_t)sb * 64 + sl * 4);
    __half2 vaA = __builtin_bit_cast(__half2, ra.x);
    __half2 vaB = __builtin_bit_cast(__half2, ra.y);
    __half2 vbA = __builtin_bit_cast(__half2, rb.x);
    __half2 vbB = __builtin_bit_cast(__half2, rb.y);
    // scores (f16 packed): leaky = max(x,0) + 0.2*min(x,0)
    __half2 xaA = __hadd2(vaA, hd2a), xaB = __hadd2(vaB, hd2b);
    __half2 xbA = __hadd2(vbA, hd2a), xbB = __hadd2(vbB, hd2b);
    __half2 laA = __hfma2(C02, h2min(xaA, Z), h2max(xaA, Z));
    __half2 laB = __hfma2(C02, h2min(xaB, Z), h2max(xaB, Z));
    __half2 lbA = __hfma2(C02, h2min(xbA, Z), h2max(xbA, Z));
    __half2 lbB = __hfma2(C02, h2min(xbB, Z), h2max(xbB, Z));
    float ta = fdot2acc(a2a, laA, 0.f); ta = fdot2acc(a2b, laB, ta);
    float tb = fdot2acc(a2a, lbA, 0.f); tb = fdot2acc(a2b, lbB, tb);
    #pragma unroll
    for (int off = 1; off < 16; off <<= 1) {
      ta += __shfl_xor(ta, off);
      tb += __shfl_xor(tb, off);
    }
    if (!has2) tb = -1e30f;
    float tp = fmaxf(ta, tb);
    float d = tp - m;
    if (d > 8.f) {                 // rare: defer-max rescale (also handles first edge)
      float sc = __expf(-d);
      den *= sc; n0 *= sc; n1 *= sc; n2 *= sc; n3 *= sc;
      m = tp;
    }
    float pa = __expf(ta - m);
    float pb = __expf(tb - m);
    den += pa + pb;
    float2 fa0 = __half22float2(vaA), fa1 = __half22float2(vaB);
    float2 fb0 = __half22float2(vbA), fb1 = __half22float2(vbB);
    n0 = fmaf(pa, fa0.x, fmaf(pb, fb0.x, n0));
    n1 = fmaf(pa, fa0.y, fmaf(pb, fb0.y, n1));
    n2 = fmaf(pa, fa1.x, fmaf(pb, fb1.x, n2));
    n3 = fmaf(pa, fa1.y, fmaf(pb, fb1.y, n3));
  }

  // merge 4 groups (flash-combine with equality guards; -1e30 groups contribute 0)
  #pragma unroll
  for (int off = 16; off <= 32; off <<= 1) {
    float m2  = __shfl_xor(m, off);
    float den2 = __shfl_xor(den, off);
    float q0 = __shfl_xor(n0, off);
    float q1 = __shfl_xor(n1, off);
    float q2 = __shfl_xor(n2, off);
    float q3 = __shfl_xor(n3, off);
    float mn = fmaxf(m, m2);
    float sA = (m == mn) ? 1.f : __expf(m - mn);
    float sB = (m2 == mn) ? 1.f : __expf(m2 - mn);
    den = den * sA + den2 * sB;
    n0 = n0 * sA + q0 * sB;
    n1 = n1 * sA + q1 * sB;
    n2 = n2 * sA + q2 * sB;
    n3 = n3 * sA + q3 * sB;
    m = mn;
  }

  if (g == 0) {
    float inv = 1.f / fmaxf(den, 1e-9f);
    float4 b4 = *(const float4*)(bias + sl * 4);
    float4 o;
    o.x = fmaf(n0, inv, b4.x);
    o.y = fmaf(n1, inv, b4.y);
    o.z = fmaf(n2, inv, b4.z);
    o.w = fmaf(n3, inv, b4.w);
    *(float4*)(outp + (size_t)node * 64 + sl * 4) = o;
  }
}

// ---------------- final: out = [A|B] @ Wout + bout ----------------

__global__ __launch_bounds__(256) void final_kernel(const float* __restrict__ A, const float* __restrict__ B,
                                                    const float* __restrict__ W, const float* __restrict__ bias,
                                                    float* __restrict__ Y, int N) {
  __shared__ float Ws[128 * 64];
  #pragma unroll
  for (int i = 0; i < 8; ++i) {
    int idx = threadIdx.x * 4 + i * 1024;
    *(float4*)(Ws + idx) = *(const float4*)(W + idx);
  }
  __syncthreads();
  int c4 = (threadIdx.x & 15) * 4;
  int rl = threadIdx.x >> 4;
  int base = blockIdx.x * 64;

  float4 b4 = *(const float4*)(bias + c4);

  #pragma unroll
  for (int rr = 0; rr < 4; ++rr) {
    int row = base + rr * 16 + rl;
    if (row >= N) continue;
    const float* ar = A + (size_t)row * 64;
    const float* br = B + (size_t)row * 64;
    float4 acc = b4;
    #pragma unroll
    for (int k4 = 0; k4 < 64; k4 += 4) {
      float4 xa = *(const float4*)(ar + k4);
      float4 xb = *(const float4*)(br + k4);
      #pragma unroll
      for (int kk = 0; kk < 4; ++kk) {
        float4 wa = *(const float4*)(Ws + (k4 + kk) * 64 + c4);
        float4 wb = *(const float4*)(Ws + (64 + k4 + kk) * 64 + c4);
        float xsa = (&xa.x)[kk], xsb = (&xb.x)[kk];
        acc.x = fmaf(xsa, wa.x, acc.x); acc.x = fmaf(xsb, wb.x, acc.x);
        acc.y = fmaf(xsa, wa.y, acc.y); acc.y = fmaf(xsb, wb.y, acc.y);
        acc.z = fmaf(xsa, wa.z, acc.z); acc.z = fmaf(xsb, wb.z, acc.z);
        acc.w = fmaf(xsa, wa.w, acc.w); acc.w = fmaf(xsb, wb.w, acc.w);
      }
    }
    *(float4*)(Y + (size_t)row * 64 + c4) = acc;
  }
}

// ---------------- launch ----------------

extern "C" void kernel_launch(void* const* d_in, const int* in_sizes, int n_in,
                              void* d_out, int out_size, void* d_ws, size_t ws_size,
                              hipStream_t stream) {
  const float* h_user   = (const float*)d_in[0];
  const float* h_item   = (const float*)d_in[1];
  const int* rate_src   = (const int*)d_in[2];
  const int* rate_dst   = (const int*)d_in[3];
  const int* rb_src     = (const int*)d_in[4];
  const int* rb_dst     = (const int*)d_in[5];
  const int* link_src   = (const int*)d_in[6];
  const int* link_dst   = (const int*)d_in[7];
  const float* w_src_r1  = (const float*)d_in[8];
  const float* w_dst_r1  = (const float*)d_in[9];
  const float* a_r1      = (const float*)d_in[10];
  const float* b_r1      = (const float*)d_in[11];
  const float* w_src_rb1 = (const float*)d_in[12];
  const float* w_dst_rb1 = (const float*)d_in[13];
  const float* a_rb1     = (const float*)d_in[14];
  const float* b_rb1     = (const float*)d_in[15];
  const float* w_src_rb2 = (const float*)d_in[16];
  const float* w_dst_rb2 = (const float*)d_in[17];
  const float* a_rb2     = (const float*)d_in[18];
  const float* b_rb2     = (const float*)d_in[19];
  const float* w_src_l2  = (const float*)d_in[20];
  const float* w_dst_l2  = (const float*)d_in[21];
  const float* a_l2      = (const float*)d_in[22];
  const float* b_l2      = (const float*)d_in[23];
  const float* w_out     = (const float*)d_in[24];
  const float* b_out     = (const float*)d_in[25];
  float* out = (float*)d_out;

  char* ws = (char*)d_ws;
  size_t off = 0;
  auto alloc = [&](size_t bytes) -> void* {
    void* p = ws + off;
    off += (bytes + 255) & ~(size_t)255;
    return p;
  };

  // f32 hd/output buffers
  float* u1 = (float*)alloc((size_t)N_USER * 64 * 4);
  float* u2 = (float*)alloc((size_t)N_USER * 64 * 4);
  float* u3 = (float*)alloc((size_t)N_USER * 64 * 4);
  float* i0 = (float*)alloc((size_t)N_ITEM * 64 * 4);
  // f16 hs buffers
  __half* uh0 = (__half*)alloc((size_t)N_USER * 64 * 2);
  __half* ih1 = (__half*)alloc((size_t)N_ITEM * 64 * 2);

  // CSR scratch
  int* mat     = (int*)alloc((size_t)MATN * 4);
  int* mscan   = (int*)alloc((size_t)MATN * 4);
  int* partials= (int*)alloc(256 * 4);
  int* grp     = (int*)alloc((size_t)(N_ITEM + 2 * N_USER + 1) * 4);
  unsigned int* pairs = (unsigned int*)alloc((size_t)E_TOT * 4);
  int* col_all = (int*)alloc((size_t)E_TOT * 4);

  // ---- bucketed CSR build ----
  bucket_hist<<<3 * GPB, 256, 0, stream>>>(rate_dst, rb_dst, link_dst, mat);
  {
    int nb = (MATN + 1023) / 1024;
    partial_kernel<<<nb, 256, 0, stream>>>(mat, MATN, partials);
    scan_partials256<<<1, 256, 0, stream>>>(partials, nb);
    scan_apply_one<<<nb, 256, 0, stream>>>(mat, MATN, partials, mscan);
  }
  bucket_scatter<<<3 * GPB, 256, 0, stream>>>(rate_src, rate_dst, rb_src, rb_dst,
                                              link_src, link_dst, mscan, pairs);
  bucket_finalize<<<NBTOT, 256, 0, stream>>>(pairs, mscan, grp, col_all);

  int* rp_rate = grp;
  int* rp_rb   = grp + N_ITEM;
  int* rp_link = grp + N_ITEM + N_USER;

  // ---- node GEMMs ----
  gemm64h<<<(N_USER + 63) / 64, 256, 0, stream>>>(h_user, w_src_r1,  uh0, N_USER);
  gemm64 <<<(N_USER + 63) / 64, 256, 0, stream>>>(h_user, w_dst_rb1, u1,  N_USER);
  gemm64 <<<(N_USER + 63) / 64, 256, 0, stream>>>(h_user, w_dst_rb2, u2,  N_USER);
  gemm64 <<<(N_USER + 63) / 64, 256, 0, stream>>>(h_user, w_dst_l2,  u3,  N_USER);
  gemm64 <<<(N_ITEM + 63) / 64, 256, 0, stream>>>(h_item, w_dst_r1,  i0,  N_ITEM);
  gemm64h<<<(N_ITEM + 63) / 64, 256, 0, stream>>>(h_item, w_src_rb1, ih1, N_ITEM);

  // ---- layer1: rate (user->item) || rated-by (item->user), fused ----
  {
    int waves = N_ITEM + N_USER;
    gat2x_kernel<<<(waves + 3) / 4, 256, 0, stream>>>(
        uh0, i0, rp_rate, a_r1,  b_r1,  i0, N_ITEM,
        ih1, u1, rp_rb,   a_rb1, b_rb1, u1, N_USER,
        col_all);
  }

  // ---- layer2 src transforms ----
  gemm64h<<<(N_ITEM + 63) / 64, 256, 0, stream>>>(i0, w_src_rb2, ih1, N_ITEM);  // h1_item @ Wsrc
  gemm64h<<<(N_USER + 63) / 64, 256, 0, stream>>>(u1, w_src_l2,  uh0, N_USER);  // h2_user @ Wsrc

  // ---- layer2: rated-by (item->user) || link (user->user), fused ----
  {
    int waves = N_USER + N_USER;
    gat2x_kernel<<<(waves + 3) / 4, 256, 0, stream>>>(
        ih1, u2, rp_rb,   a_rb2, b_rb2, u2, N_USER,
        uh0, u3, rp_link, a_l2,  b_l2,  u3, N_USER,
        col_all);
  }

  // ---- output projection ----
  final_kernel<<<(N_USER + 63) / 64, 256, 0, stream>>>(u2, u3, w_out, b_out, out, N_USER);
}

// Round 8
// 453.851 us; speedup vs baseline: 3.6453x; 1.0541x over previous
//
#include <hip/hip_runtime.h>
#include <hip/hip_fp16.h>
#include <math.h>

#define N_USER 50000
#define N_ITEM 100000
#define E_UI   1000000
#define E_UU   800000
#define E_TOT  (E_UI + E_UI + E_UU)
#define NEG_SLOPE 0.2f

#define NB0 391
#define NB1 196
#define NB2 196
#define NBTOT (NB0 + NB1 + NB2)   // 783
#define GPB 256
#define MATN (NBTOT * 256)        // 200448

typedef _Float16 h2v __attribute__((ext_vector_type(2)));

#if defined(__has_builtin)
#if __has_builtin(__builtin_amdgcn_fdot2)
#define HAS_FDOT2 1
#endif
#if __has_builtin(__builtin_elementwise_max)
#define HAS_EW_MAX 1
#endif
#endif

__device__ __forceinline__ float fdot2acc(__half2 a, __half2 b, float c) {
#ifdef HAS_FDOT2
  return __builtin_amdgcn_fdot2(__builtin_bit_cast(h2v, a), __builtin_bit_cast(h2v, b), c, false);
#else
  float2 af = __half22float2(a), bf = __half22float2(b);
  return fmaf(af.x, bf.x, fmaf(af.y, bf.y, c));
#endif
}

__device__ __forceinline__ __half2 h2max(__half2 a, __half2 b) {
  h2v av = __builtin_bit_cast(h2v, a), bv = __builtin_bit_cast(h2v, b);
#ifdef HAS_EW_MAX
  h2v r = __builtin_elementwise_max(av, bv);
#else
  h2v r; r.x = av.x > bv.x ? av.x : bv.x; r.y = av.y > bv.y ? av.y : bv.y;
#endif
  return __builtin_bit_cast(__half2, r);
}

__device__ __forceinline__ __half2 h2min(__half2 a, __half2 b) {
  h2v av = __builtin_bit_cast(h2v, a), bv = __builtin_bit_cast(h2v, b);
#ifdef HAS_EW_MAX
  h2v r = __builtin_elementwise_min(av, bv);
#else
  h2v r; r.x = av.x < bv.x ? av.x : bv.x; r.y = av.y < bv.y ? av.y : bv.y;
#endif
  return __builtin_bit_cast(__half2, r);
}

// ---------------- bucket histogram ----------------

__global__ __launch_bounds__(256) void bucket_hist(const int* __restrict__ d0, const int* __restrict__ d1,
                                                   const int* __restrict__ d2, int* __restrict__ mat) {
  int gid = blockIdx.x >> 8;
  int g   = blockIdx.x & 255;
  const int* dst = gid == 0 ? d0 : (gid == 1 ? d1 : d2);
  int E    = (gid == 2) ? E_UU : E_UI;
  int NB   = (gid == 0) ? NB0 : NB1;
  int boff = (gid == 0) ? 0 : (gid == 1 ? NB0 : NB0 + NB1);
  __shared__ int cnt[NB0];
  for (int b = threadIdx.x; b < NB; b += 256) cnt[b] = 0;
  __syncthreads();
  int chunk = (E + 255) >> 8;
  int lo = g * chunk, hi = min(lo + chunk, E);
  for (int i = lo + threadIdx.x; i < hi; i += 256)
    atomicAdd(&cnt[dst[i] >> 8], 1);
  __syncthreads();
  for (int b = threadIdx.x; b < NB; b += 256)
    mat[(boff + b) * 256 + g] = cnt[b];
}

// ---------------- hierarchical exclusive scan over mat ----------------

__global__ __launch_bounds__(256) void partial_kernel(const int* __restrict__ counts, int n,
                                                      int* __restrict__ partials) {
  int t = threadIdx.x;
  int base = blockIdx.x * 1024 + t * 4;
  int s = 0;
  if (base + 3 < n) {
    int4 v = *(const int4*)(counts + base);
    s = v.x + v.y + v.z + v.w;
  } else {
    for (int i = base; i < n && i < base + 4; ++i) s += counts[i];
  }
  #pragma unroll
  for (int off = 1; off < 64; off <<= 1) s += __shfl_xor(s, off);
  __shared__ int ws[4];
  if ((t & 63) == 0) ws[t >> 6] = s;
  __syncthreads();
  if (t == 0) partials[blockIdx.x] = ws[0] + ws[1] + ws[2] + ws[3];
}

__global__ __launch_bounds__(256) void scan_partials256(int* __restrict__ partials, int nb) {
  __shared__ int s[256];
  int t = threadIdx.x;
  s[t] = (t < nb) ? partials[t] : 0;
  __syncthreads();
  for (int off = 1; off < 256; off <<= 1) {
    int v = (t >= off) ? s[t - off] : 0;
    __syncthreads();
    s[t] += v;
    __syncthreads();
  }
  if (t < nb) partials[t] = (t == 0) ? 0 : s[t - 1];
}

__global__ __launch_bounds__(256) void scan_apply_one(const int* __restrict__ counts, int n,
                                                      const int* __restrict__ partials,
                                                      int* __restrict__ outp) {
  int t = threadIdx.x;
  int base = blockIdx.x * 1024 + t * 4;
  int4 v = make_int4(0, 0, 0, 0);
  if (base + 3 < n) {
    v = *(const int4*)(counts + base);
  } else {
    int* pv = &v.x;
    for (int i = 0; i < 4; ++i) if (base + i < n) pv[i] = counts[base + i];
  }
  int s = v.x + v.y + v.z + v.w;
  int lane = t & 63;
  int wv = t >> 6;
  int inc = s;
  #pragma unroll
  for (int off = 1; off < 64; off <<= 1) {
    int u = __shfl_up(inc, off);
    if (lane >= off) inc += u;
  }
  __shared__ int wsum[4];
  if (lane == 63) wsum[wv] = inc;
  __syncthreads();
  int woff = 0;
  for (int i = 0; i < wv; ++i) woff += wsum[i];
  int excl = woff + (inc - s) + partials[blockIdx.x];
  int4 rp;
  rp.x = excl;
  rp.y = rp.x + v.x;
  rp.z = rp.y + v.y;
  rp.w = rp.z + v.z;
  if (base + 3 < n) {
    *(int4*)(outp + base) = rp;
  } else {
    int* pr = &rp.x;
    for (int i = 0; i < 4; ++i) if (base + i < n) outp[base + i] = pr[i];
  }
}

// ---------------- bucket scatter ----------------

__global__ __launch_bounds__(256) void bucket_scatter(const int* __restrict__ s0v, const int* __restrict__ d0,
                                                      const int* __restrict__ s1v, const int* __restrict__ d1,
                                                      const int* __restrict__ s2v, const int* __restrict__ d2,
                                                      const int* __restrict__ mscan, unsigned int* __restrict__ pairs) {
  int gid = blockIdx.x >> 8;
  int g   = blockIdx.x & 255;
  const int* src = gid == 0 ? s0v : (gid == 1 ? s1v : s2v);
  const int* dst = gid == 0 ? d0  : (gid == 1 ? d1  : d2);
  int E    = (gid == 2) ? E_UU : E_UI;
  int NB   = (gid == 0) ? NB0 : NB1;
  int boff = (gid == 0) ? 0 : (gid == 1 ? NB0 : NB0 + NB1);
  __shared__ int cur[NB0];
  for (int b = threadIdx.x; b < NB; b += 256) cur[b] = mscan[(boff + b) * 256 + g];
  __syncthreads();
  int chunk = (E + 255) >> 8;
  int lo = g * chunk, hi = min(lo + chunk, E);
  for (int i = lo + threadIdx.x; i < hi; i += 256) {
    int d = dst[i], s = src[i];
    int pos = atomicAdd(&cur[d >> 8], 1);
    pairs[pos] = ((unsigned)(d & 255) << 24) | (unsigned)s;
  }
}

// ---------------- bucket finalize ----------------

__global__ __launch_bounds__(256) void bucket_finalize(const unsigned int* __restrict__ pairs,
                                                       const int* __restrict__ mscan,
                                                       int* __restrict__ rp, int* __restrict__ col) {
  int gb = blockIdx.x;
  int t  = threadIdx.x;
  int gid  = (gb < NB0) ? 0 : (gb < NB0 + NB1 ? 1 : 2);
  int boff = (gid == 0) ? 0 : (gid == 1 ? NB0 : NB0 + NB1);
  int node_goff = (gid == 0) ? 0 : (gid == 1 ? N_ITEM : N_ITEM + N_USER);
  int n    = (gid == 0) ? N_ITEM : N_USER;
  int b_local = gb - boff;
  int bs = mscan[gb * 256];
  int be = (gb + 1 < NBTOT) ? mscan[(gb + 1) * 256] : E_TOT;

  __shared__ int cnt[256];
  __shared__ int curb[256];
  __shared__ int wsum[4];
  cnt[t] = 0;
  __syncthreads();
  for (int i = bs + t; i < be; i += 256)
    atomicAdd(&cnt[pairs[i] >> 24], 1);
  __syncthreads();

  int v = cnt[t];
  int lane = t & 63, wv = t >> 6;
  int inc = v;
  #pragma unroll
  for (int off = 1; off < 64; off <<= 1) {
    int u = __shfl_up(inc, off);
    if (lane >= off) inc += u;
  }
  if (lane == 63) wsum[wv] = inc;
  __syncthreads();
  int woff = 0;
  for (int i = 0; i < wv; ++i) woff += wsum[i];
  int base = bs + woff + (inc - v);

  int node_local = b_local * 256 + t;
  if (node_local < n) rp[node_goff + node_local] = base;
  if (gb == NBTOT - 1 && t == 255) rp[N_ITEM + 2 * N_USER] = E_TOT;
  curb[t] = base;
  __syncthreads();

  for (int i = bs + t; i < be; i += 256) {
    unsigned u = pairs[i];
    int p = atomicAdd(&curb[u >> 24], 1);
    col[p] = (int)(u & 0xFFFFFFu);
  }
}

// ---------------- GEMM building blocks (all-static, no arrays) ----------------

// stage W (64x64 f32) into Ws and compute 4 rows x 4 cols into acc0..acc3
__device__ __forceinline__ void gemm_phase(const float* __restrict__ Wsrc, float* Ws,
                                           const float* x0, const float* x1,
                                           const float* x2, const float* x3, int c4,
                                           float4& acc0, float4& acc1, float4& acc2, float4& acc3) {
  __syncthreads();
  #pragma unroll
  for (int i = 0; i < 4; ++i) {
    int idx = threadIdx.x * 4 + i * 1024;
    *(float4*)(Ws + idx) = *(const float4*)(Wsrc + idx);
  }
  __syncthreads();
  acc0 = make_float4(0.f, 0.f, 0.f, 0.f);
  acc1 = acc0; acc2 = acc0; acc3 = acc0;
  #pragma unroll
  for (int k4 = 0; k4 < 64; k4 += 4) {
    float4 xa = *(const float4*)(x0 + k4);
    float4 xb = *(const float4*)(x1 + k4);
    float4 xc = *(const float4*)(x2 + k4);
    float4 xd = *(const float4*)(x3 + k4);
    #pragma unroll
    for (int kk = 0; kk < 4; ++kk) {
      float4 w = *(const float4*)(Ws + (k4 + kk) * 64 + c4);
      float sa = (&xa.x)[kk], sb = (&xb.x)[kk], sc = (&xc.x)[kk], sd = (&xd.x)[kk];
      acc0.x = fmaf(sa, w.x, acc0.x); acc0.y = fmaf(sa, w.y, acc0.y);
      acc0.z = fmaf(sa, w.z, acc0.z); acc0.w = fmaf(sa, w.w, acc0.w);
      acc1.x = fmaf(sb, w.x, acc1.x); acc1.y = fmaf(sb, w.y, acc1.y);
      acc1.z = fmaf(sb, w.z, acc1.z); acc1.w = fmaf(sb, w.w, acc1.w);
      acc2.x = fmaf(sc, w.x, acc2.x); acc2.y = fmaf(sc, w.y, acc2.y);
      acc2.z = fmaf(sc, w.z, acc2.z); acc2.w = fmaf(sc, w.w, acc2.w);
      acc3.x = fmaf(sd, w.x, acc3.x); acc3.y = fmaf(sd, w.y, acc3.y);
      acc3.z = fmaf(sd, w.z, acc3.z); acc3.w = fmaf(sd, w.w, acc3.w);
    }
  }
}

__device__ __forceinline__ void store4_f32(float* __restrict__ Y, int r0, int r1, int r2, int r3,
                                           int N, int c4,
                                           const float4& a0, const float4& a1,
                                           const float4& a2, const float4& a3) {
  if (r0 < N) *(float4*)(Y + (size_t)r0 * 64 + c4) = a0;
  if (r1 < N) *(float4*)(Y + (size_t)r1 * 64 + c4) = a1;
  if (r2 < N) *(float4*)(Y + (size_t)r2 * 64 + c4) = a2;
  if (r3 < N) *(float4*)(Y + (size_t)r3 * 64 + c4) = a3;
}

__device__ __forceinline__ void store4_f16(__half* __restrict__ Y, int r0, int r1, int r2, int r3,
                                           int N, int c4,
                                           const float4& a0, const float4& a1,
                                           const float4& a2, const float4& a3) {
  uint2 st;
  if (r0 < N) {
    st.x = __builtin_bit_cast(unsigned int, __floats2half2_rn(a0.x, a0.y));
    st.y = __builtin_bit_cast(unsigned int, __floats2half2_rn(a0.z, a0.w));
    *(uint2*)(Y + (size_t)r0 * 64 + c4) = st;
  }
  if (r1 < N) {
    st.x = __builtin_bit_cast(unsigned int, __floats2half2_rn(a1.x, a1.y));
    st.y = __builtin_bit_cast(unsigned int, __floats2half2_rn(a1.z, a1.w));
    *(uint2*)(Y + (size_t)r1 * 64 + c4) = st;
  }
  if (r2 < N) {
    st.x = __builtin_bit_cast(unsigned int, __floats2half2_rn(a2.x, a2.y));
    st.y = __builtin_bit_cast(unsigned int, __floats2half2_rn(a2.z, a2.w));
    *(uint2*)(Y + (size_t)r2 * 64 + c4) = st;
  }
  if (r3 < N) {
    st.x = __builtin_bit_cast(unsigned int, __floats2half2_rn(a3.x, a3.y));
    st.y = __builtin_bit_cast(unsigned int, __floats2half2_rn(a3.z, a3.w));
    *(uint2*)(Y + (size_t)r3 * 64 + c4) = st;
  }
}

// h_user -> uh0(f16, W0), u1(W1), u2(W2), u3(W3): X read from HBM once
__global__ __launch_bounds__(256) void gemm_user4(const float* __restrict__ X,
                                                  const float* __restrict__ W0, const float* __restrict__ W1,
                                                  const float* __restrict__ W2, const float* __restrict__ W3,
                                                  __half* __restrict__ Y0h, float* __restrict__ Y1,
                                                  float* __restrict__ Y2, float* __restrict__ Y3, int N) {
  __shared__ float Ws[64 * 64];
  int c4 = (threadIdx.x & 15) * 4;
  int rl = threadIdx.x >> 4;
  int base = blockIdx.x * 64;
  int r0 = base + rl, r1 = r0 + 16, r2 = r0 + 32, r3 = r0 + 48;
  const float* x0 = X + (size_t)(r0 < N ? r0 : N - 1) * 64;
  const float* x1 = X + (size_t)(r1 < N ? r1 : N - 1) * 64;
  const float* x2 = X + (size_t)(r2 < N ? r2 : N - 1) * 64;
  const float* x3 = X + (size_t)(r3 < N ? r3 : N - 1) * 64;
  float4 a0, a1, a2, a3;
  gemm_phase(W0, Ws, x0, x1, x2, x3, c4, a0, a1, a2, a3);
  store4_f16(Y0h, r0, r1, r2, r3, N, c4, a0, a1, a2, a3);
  gemm_phase(W1, Ws, x0, x1, x2, x3, c4, a0, a1, a2, a3);
  store4_f32(Y1, r0, r1, r2, r3, N, c4, a0, a1, a2, a3);
  gemm_phase(W2, Ws, x0, x1, x2, x3, c4, a0, a1, a2, a3);
  store4_f32(Y2, r0, r1, r2, r3, N, c4, a0, a1, a2, a3);
  gemm_phase(W3, Ws, x0, x1, x2, x3, c4, a0, a1, a2, a3);
  store4_f32(Y3, r0, r1, r2, r3, N, c4, a0, a1, a2, a3);
}

// h_item -> i0(f32, W0), ih1(f16, W1)
__global__ __launch_bounds__(256) void gemm_item2(const float* __restrict__ X,
                                                  const float* __restrict__ W0, const float* __restrict__ W1,
                                                  float* __restrict__ Y0, __half* __restrict__ Y1h, int N) {
  __shared__ float Ws[64 * 64];
  int c4 = (threadIdx.x & 15) * 4;
  int rl = threadIdx.x >> 4;
  int base = blockIdx.x * 64;
  int r0 = base + rl, r1 = r0 + 16, r2 = r0 + 32, r3 = r0 + 48;
  const float* x0 = X + (size_t)(r0 < N ? r0 : N - 1) * 64;
  const float* x1 = X + (size_t)(r1 < N ? r1 : N - 1) * 64;
  const float* x2 = X + (size_t)(r2 < N ? r2 : N - 1) * 64;
  const float* x3 = X + (size_t)(r3 < N ? r3 : N - 1) * 64;
  float4 a0, a1, a2, a3;
  gemm_phase(W0, Ws, x0, x1, x2, x3, c4, a0, a1, a2, a3);
  store4_f32(Y0, r0, r1, r2, r3, N, c4, a0, a1, a2, a3);
  gemm_phase(W1, Ws, x0, x1, x2, x3, c4, a0, a1, a2, a3);
  store4_f16(Y1h, r0, r1, r2, r3, N, c4, a0, a1, a2, a3);
}

// two independent f16-output GEMMs in one dispatch (block-range split)
__global__ __launch_bounds__(256) void gemm_mid2x(const float* __restrict__ XA, const float* __restrict__ WA,
                                                  __half* __restrict__ YA, int NA, int nbA,
                                                  const float* __restrict__ XB, const float* __restrict__ WB,
                                                  __half* __restrict__ YB, int NB_) {
  __shared__ float Ws[64 * 64];
  const float* X; const float* W; __half* Y; int N; int base;
  if ((int)blockIdx.x < nbA) {
    X = XA; W = WA; Y = YA; N = NA; base = blockIdx.x * 64;
  } else {
    X = XB; W = WB; Y = YB; N = NB_; base = (blockIdx.x - nbA) * 64;
  }
  int c4 = (threadIdx.x & 15) * 4;
  int rl = threadIdx.x >> 4;
  int r0 = base + rl, r1 = r0 + 16, r2 = r0 + 32, r3 = r0 + 48;
  const float* x0 = X + (size_t)(r0 < N ? r0 : N - 1) * 64;
  const float* x1 = X + (size_t)(r1 < N ? r1 : N - 1) * 64;
  const float* x2 = X + (size_t)(r2 < N ? r2 : N - 1) * 64;
  const float* x3 = X + (size_t)(r3 < N ? r3 : N - 1) * 64;
  float4 a0, a1, a2, a3;
  gemm_phase(W, Ws, x0, x1, x2, x3, c4, a0, a1, a2, a3);
  store4_f16(Y, r0, r1, r2, r3, N, c4, a0, a1, a2, a3);
}

// ---------------- fused GATv2 (two independent graphs per dispatch) ----------------

__global__ __launch_bounds__(256) void gat2x_kernel(
    const __half* __restrict__ hsA, const float* __restrict__ hdAp,
    const int* __restrict__ rpA, const float* __restrict__ attnA, const float* __restrict__ biasA,
    float* __restrict__ outA, int NdA,
    const __half* __restrict__ hsB, const float* __restrict__ hdBp,
    const int* __restrict__ rpB, const float* __restrict__ attnB, const float* __restrict__ biasB,
    float* __restrict__ outB, int NdB,
    const int* __restrict__ col) {
  int wid = (blockIdx.x * blockDim.x + threadIdx.x) >> 6;
  int lane = threadIdx.x & 63;
  int g = lane >> 4;        // edge group 0..3
  int sl = lane & 15;       // dims sl*4 .. sl*4+3
  const __half* hs; const float* hd; const int* rp;
  const float* attn; const float* bias; float* outp; int node;
  if (wid < NdA) {
    hs = hsA; hd = hdAp; rp = rpA; attn = attnA; bias = biasA; outp = outA; node = wid;
  } else {
    if (wid >= NdA + NdB) return;
    hs = hsB; hd = hdBp; rp = rpB; attn = attnB; bias = biasB; outp = outB; node = wid - NdA;
  }
  int s0 = rp[node], s1 = rp[node + 1];

  float4 hdf = *(const float4*)(hd + (size_t)node * 64 + sl * 4);
  float4 af  = *(const float4*)(attn + sl * 4);
  __half2 hd2a = __floats2half2_rn(hdf.x, hdf.y);
  __half2 hd2b = __floats2half2_rn(hdf.z, hdf.w);
  __half2 a2a = __floats2half2_rn(af.x, af.y);
  __half2 a2b = __floats2half2_rn(af.z, af.w);
  const __half2 C02 = __floats2half2_rn(NEG_SLOPE, NEG_SLOPE);
  const __half2 Z   = __floats2half2_rn(0.f, 0.f);

  float m = -1e30f, den = 0.f;
  float n0 = 0.f, n1 = 0.f, n2 = 0.f, n3 = 0.f;

  for (int e = s0 + g; e < s1; e += 8) {
    int eb = e + 4;
    bool has2 = eb < s1;
    int sa = col[e];
    int sb = col[has2 ? eb : e];
    uint2 ra = *(const uint2*)(hs + (size_t)sa * 64 + sl * 4);
    uint2 rb = *(const uint2*)(hs + (size_t)sb * 64 + sl * 4);
    __half2 vaA = __builtin_bit_cast(__half2, ra.x);
    __half2 vaB = __builtin_bit_cast(__half2, ra.y);
    __half2 vbA = __builtin_bit_cast(__half2, rb.x);
    __half2 vbB = __builtin_bit_cast(__half2, rb.y);
    __half2 xaA = __hadd2(vaA, hd2a), xaB = __hadd2(vaB, hd2b);
    __half2 xbA = __hadd2(vbA, hd2a), xbB = __hadd2(vbB, hd2b);
    __half2 laA = __hfma2(C02, h2min(xaA, Z), h2max(xaA, Z));
    __half2 laB = __hfma2(C02, h2min(xaB, Z), h2max(xaB, Z));
    __half2 lbA = __hfma2(C02, h2min(xbA, Z), h2max(xbA, Z));
    __half2 lbB = __hfma2(C02, h2min(xbB, Z), h2max(xbB, Z));
    float ta = fdot2acc(a2a, laA, 0.f); ta = fdot2acc(a2b, laB, ta);
    float tb = fdot2acc(a2a, lbA, 0.f); tb = fdot2acc(a2b, lbB, tb);
    #pragma unroll
    for (int off = 1; off < 16; off <<= 1) {
      ta += __shfl_xor(ta, off);
      tb += __shfl_xor(tb, off);
    }
    if (!has2) tb = -1e30f;
    float tp = fmaxf(ta, tb);
    float d = tp - m;
    if (d > 8.f) {
      float sc = __expf(-d);
      den *= sc; n0 *= sc; n1 *= sc; n2 *= sc; n3 *= sc;
      m = tp;
    }
    float pa = __expf(ta - m);
    float pb = __expf(tb - m);
    den += pa + pb;
    float2 fa0 = __half22float2(vaA), fa1 = __half22float2(vaB);
    float2 fb0 = __half22float2(vbA), fb1 = __half22float2(vbB);
    n0 = fmaf(pa, fa0.x, fmaf(pb, fb0.x, n0));
    n1 = fmaf(pa, fa0.y, fmaf(pb, fb0.y, n1));
    n2 = fmaf(pa, fa1.x, fmaf(pb, fb1.x, n2));
    n3 = fmaf(pa, fa1.y, fmaf(pb, fb1.y, n3));
  }

  #pragma unroll
  for (int off = 16; off <= 32; off <<= 1) {
    float m2  = __shfl_xor(m, off);
    float den2 = __shfl_xor(den, off);
    float q0 = __shfl_xor(n0, off);
    float q1 = __shfl_xor(n1, off);
    float q2 = __shfl_xor(n2, off);
    float q3 = __shfl_xor(n3, off);
    float mn = fmaxf(m, m2);
    float sA = (m == mn) ? 1.f : __expf(m - mn);
    float sB = (m2 == mn) ? 1.f : __expf(m2 - mn);
    den = den * sA + den2 * sB;
    n0 = n0 * sA + q0 * sB;
    n1 = n1 * sA + q1 * sB;
    n2 = n2 * sA + q2 * sB;
    n3 = n3 * sA + q3 * sB;
    m = mn;
  }

  if (g == 0) {
    float inv = 1.f / fmaxf(den, 1e-9f);
    float4 b4 = *(const float4*)(bias + sl * 4);
    float4 o;
    o.x = fmaf(n0, inv, b4.x);
    o.y = fmaf(n1, inv, b4.y);
    o.z = fmaf(n2, inv, b4.z);
    o.w = fmaf(n3, inv, b4.w);
    *(float4*)(outp + (size_t)node * 64 + sl * 4) = o;
  }
}

// ---------------- final: out = [A|B] @ Wout + bout ----------------

__global__ __launch_bounds__(256) void final_kernel(const float* __restrict__ A, const float* __restrict__ B,
                                                    const float* __restrict__ W, const float* __restrict__ bias,
                                                    float* __restrict__ Y, int N) {
  __shared__ float Ws[128 * 64];
  #pragma unroll
  for (int i = 0; i < 8; ++i) {
    int idx = threadIdx.x * 4 + i * 1024;
    *(float4*)(Ws + idx) = *(const float4*)(W + idx);
  }
  __syncthreads();
  int c4 = (threadIdx.x & 15) * 4;
  int rl = threadIdx.x >> 4;
  int base = blockIdx.x * 64;

  float4 b4 = *(const float4*)(bias + c4);

  #pragma unroll
  for (int rr = 0; rr < 4; ++rr) {
    int row = base + rr * 16 + rl;
    if (row >= N) continue;
    const float* ar = A + (size_t)row * 64;
    const float* br = B + (size_t)row * 64;
    float4 acc = b4;
    #pragma unroll
    for (int k4 = 0; k4 < 64; k4 += 4) {
      float4 xa = *(const float4*)(ar + k4);
      float4 xb = *(const float4*)(br + k4);
      #pragma unroll
      for (int kk = 0; kk < 4; ++kk) {
        float4 wa = *(const float4*)(Ws + (k4 + kk) * 64 + c4);
        float4 wb = *(const float4*)(Ws + (64 + k4 + kk) * 64 + c4);
        float xsa = (&xa.x)[kk], xsb = (&xb.x)[kk];
        acc.x = fmaf(xsa, wa.x, acc.x); acc.x = fmaf(xsb, wb.x, acc.x);
        acc.y = fmaf(xsa, wa.y, acc.y); acc.y = fmaf(xsb, wb.y, acc.y);
        acc.z = fmaf(xsa, wa.z, acc.z); acc.z = fmaf(xsb, wb.z, acc.z);
        acc.w = fmaf(xsa, wa.w, acc.w); acc.w = fmaf(xsb, wb.w, acc.w);
      }
    }
    *(float4*)(Y + (size_t)row * 64 + c4) = acc;
  }
}

// ---------------- launch ----------------

extern "C" void kernel_launch(void* const* d_in, const int* in_sizes, int n_in,
                              void* d_out, int out_size, void* d_ws, size_t ws_size,
                              hipStream_t stream) {
  const float* h_user   = (const float*)d_in[0];
  const float* h_item   = (const float*)d_in[1];
  const int* rate_src   = (const int*)d_in[2];
  const int* rate_dst   = (const int*)d_in[3];
  const int* rb_src     = (const int*)d_in[4];
  const int* rb_dst     = (const int*)d_in[5];
  const int* link_src   = (const int*)d_in[6];
  const int* link_dst   = (const int*)d_in[7];
  const float* w_src_r1  = (const float*)d_in[8];
  const float* w_dst_r1  = (const float*)d_in[9];
  const float* a_r1      = (const float*)d_in[10];
  const float* b_r1      = (const float*)d_in[11];
  const float* w_src_rb1 = (const float*)d_in[12];
  const float* w_dst_rb1 = (const float*)d_in[13];
  const float* a_rb1     = (const float*)d_in[14];
  const float* b_rb1     = (const float*)d_in[15];
  const float* w_src_rb2 = (const float*)d_in[16];
  const float* w_dst_rb2 = (const float*)d_in[17];
  const float* a_rb2     = (const float*)d_in[18];
  const float* b_rb2     = (const float*)d_in[19];
  const float* w_src_l2  = (const float*)d_in[20];
  const float* w_dst_l2  = (const float*)d_in[21];
  const float* a_l2      = (const float*)d_in[22];
  const float* b_l2      = (const float*)d_in[23];
  const float* w_out     = (const float*)d_in[24];
  const float* b_out     = (const float*)d_in[25];
  float* out = (float*)d_out;

  char* ws = (char*)d_ws;
  size_t off = 0;
  auto alloc = [&](size_t bytes) -> void* {
    void* p = ws + off;
    off += (bytes + 255) & ~(size_t)255;
    return p;
  };

  float* u1 = (float*)alloc((size_t)N_USER * 64 * 4);
  float* u2 = (float*)alloc((size_t)N_USER * 64 * 4);
  float* u3 = (float*)alloc((size_t)N_USER * 64 * 4);
  float* i0 = (float*)alloc((size_t)N_ITEM * 64 * 4);
  __half* uh0 = (__half*)alloc((size_t)N_USER * 64 * 2);
  __half* ih1 = (__half*)alloc((size_t)N_ITEM * 64 * 2);

  int* mat     = (int*)alloc((size_t)MATN * 4);
  int* mscan   = (int*)alloc((size_t)MATN * 4);
  int* partials= (int*)alloc(256 * 4);
  int* grp     = (int*)alloc((size_t)(N_ITEM + 2 * N_USER + 1) * 4);
  unsigned int* pairs = (unsigned int*)alloc((size_t)E_TOT * 4);
  int* col_all = (int*)alloc((size_t)E_TOT * 4);

  // ---- bucketed CSR build ----
  bucket_hist<<<3 * GPB, 256, 0, stream>>>(rate_dst, rb_dst, link_dst, mat);
  {
    int nb = (MATN + 1023) / 1024;
    partial_kernel<<<nb, 256, 0, stream>>>(mat, MATN, partials);
    scan_partials256<<<1, 256, 0, stream>>>(partials, nb);
    scan_apply_one<<<nb, 256, 0, stream>>>(mat, MATN, partials, mscan);
  }
  bucket_scatter<<<3 * GPB, 256, 0, stream>>>(rate_src, rate_dst, rb_src, rb_dst,
                                              link_src, link_dst, mscan, pairs);
  bucket_finalize<<<NBTOT, 256, 0, stream>>>(pairs, mscan, grp, col_all);

  int* rp_rate = grp;
  int* rp_rb   = grp + N_ITEM;
  int* rp_link = grp + N_ITEM + N_USER;

  // ---- fused node GEMMs ----
  gemm_user4<<<(N_USER + 63) / 64, 256, 0, stream>>>(
      h_user, w_src_r1, w_dst_rb1, w_dst_rb2, w_dst_l2, uh0, u1, u2, u3, N_USER);
  gemm_item2<<<(N_ITEM + 63) / 64, 256, 0, stream>>>(
      h_item, w_dst_r1, w_src_rb1, i0, ih1, N_ITEM);

  // ---- layer1: rate (user->item) || rated-by (item->user), fused ----
  {
    int waves = N_ITEM + N_USER;
    gat2x_kernel<<<(waves + 3) / 4, 256, 0, stream>>>(
        uh0, i0, rp_rate, a_r1,  b_r1,  i0, N_ITEM,
        ih1, u1, rp_rb,   a_rb1, b_rb1, u1, N_USER,
        col_all);
  }

  // ---- layer2 src transforms (fused pair) ----
  {
    int nbA = (N_ITEM + 63) / 64;
    int nbB = (N_USER + 63) / 64;
    gemm_mid2x<<<nbA + nbB, 256, 0, stream>>>(
        i0, w_src_rb2, ih1, N_ITEM, nbA,
        u1, w_src_l2,  uh0, N_USER);
  }

  // ---- layer2: rated-by (item->user) || link (user->user), fused ----
  {
    int waves = N_USER + N_USER;
    gat2x_kernel<<<(waves + 3) / 4, 256, 0, stream>>>(
        ih1, u2, rp_rb,   a_rb2, b_rb2, u2, N_USER,
        uh0, u3, rp_link, a_l2,  b_l2,  u3, N_USER,
        col_all);
  }

  // ---- output projection ----
  final_kernel<<<(N_USER + 63) / 64, 256, 0, stream>>>(u2, u3, w_out, b_out, out, N_USER);
}

// Round 9
// 438.116 us; speedup vs baseline: 3.7762x; 1.0359x over previous
//
#include <hip/hip_runtime.h>
#include <hip/hip_fp16.h>
#include <math.h>

#define N_USER 50000
#define N_ITEM 100000
#define E_UI   1000000
#define E_UU   800000
#define E_TOT  (E_UI + E_UI + E_UU)
#define NEG_SLOPE 0.2f

#define NB0 391
#define NB1 196
#define NB2 196
#define NBTOT (NB0 + NB1 + NB2)   // 783
#define GPB 256
#define MATN (NBTOT * 256)        // 200448

#define XS_STRIDE 68  // padded LDS row stride (floats): 16B-aligned, banks spread by 4/row

typedef _Float16 h2v __attribute__((ext_vector_type(2)));

#if defined(__has_builtin)
#if __has_builtin(__builtin_amdgcn_fdot2)
#define HAS_FDOT2 1
#endif
#if __has_builtin(__builtin_elementwise_max)
#define HAS_EW_MAX 1
#endif
#endif

__device__ __forceinline__ float fdot2acc(__half2 a, __half2 b, float c) {
#ifdef HAS_FDOT2
  return __builtin_amdgcn_fdot2(__builtin_bit_cast(h2v, a), __builtin_bit_cast(h2v, b), c, false);
#else
  float2 af = __half22float2(a), bf = __half22float2(b);
  return fmaf(af.x, bf.x, fmaf(af.y, bf.y, c));
#endif
}

__device__ __forceinline__ __half2 h2max(__half2 a, __half2 b) {
  h2v av = __builtin_bit_cast(h2v, a), bv = __builtin_bit_cast(h2v, b);
#ifdef HAS_EW_MAX
  h2v r = __builtin_elementwise_max(av, bv);
#else
  h2v r; r.x = av.x > bv.x ? av.x : bv.x; r.y = av.y > bv.y ? av.y : bv.y;
#endif
  return __builtin_bit_cast(__half2, r);
}

__device__ __forceinline__ __half2 h2min(__half2 a, __half2 b) {
  h2v av = __builtin_bit_cast(h2v, a), bv = __builtin_bit_cast(h2v, b);
#ifdef HAS_EW_MAX
  h2v r = __builtin_elementwise_min(av, bv);
#else
  h2v r; r.x = av.x < bv.x ? av.x : bv.x; r.y = av.y < bv.y ? av.y : bv.y;
#endif
  return __builtin_bit_cast(__half2, r);
}

// ---------------- bucket histogram ----------------

__global__ __launch_bounds__(256) void bucket_hist(const int* __restrict__ d0, const int* __restrict__ d1,
                                                   const int* __restrict__ d2, int* __restrict__ mat) {
  int gid = blockIdx.x >> 8;
  int g   = blockIdx.x & 255;
  const int* dst = gid == 0 ? d0 : (gid == 1 ? d1 : d2);
  int E    = (gid == 2) ? E_UU : E_UI;
  int NB   = (gid == 0) ? NB0 : NB1;
  int boff = (gid == 0) ? 0 : (gid == 1 ? NB0 : NB0 + NB1);
  __shared__ int cnt[NB0];
  for (int b = threadIdx.x; b < NB; b += 256) cnt[b] = 0;
  __syncthreads();
  int chunk = (E + 255) >> 8;
  int lo = g * chunk, hi = min(lo + chunk, E);
  for (int i = lo + threadIdx.x; i < hi; i += 256)
    atomicAdd(&cnt[dst[i] >> 8], 1);
  __syncthreads();
  for (int b = threadIdx.x; b < NB; b += 256)
    mat[(boff + b) * 256 + g] = cnt[b];
}

// ---------------- hierarchical exclusive scan over mat ----------------

__global__ __launch_bounds__(256) void partial_kernel(const int* __restrict__ counts, int n,
                                                      int* __restrict__ partials) {
  int t = threadIdx.x;
  int base = blockIdx.x * 1024 + t * 4;
  int s = 0;
  if (base + 3 < n) {
    int4 v = *(const int4*)(counts + base);
    s = v.x + v.y + v.z + v.w;
  } else {
    for (int i = base; i < n && i < base + 4; ++i) s += counts[i];
  }
  #pragma unroll
  for (int off = 1; off < 64; off <<= 1) s += __shfl_xor(s, off);
  __shared__ int ws[4];
  if ((t & 63) == 0) ws[t >> 6] = s;
  __syncthreads();
  if (t == 0) partials[blockIdx.x] = ws[0] + ws[1] + ws[2] + ws[3];
}

__global__ __launch_bounds__(256) void scan_partials256(int* __restrict__ partials, int nb) {
  __shared__ int s[256];
  int t = threadIdx.x;
  s[t] = (t < nb) ? partials[t] : 0;
  __syncthreads();
  for (int off = 1; off < 256; off <<= 1) {
    int v = (t >= off) ? s[t - off] : 0;
    __syncthreads();
    s[t] += v;
    __syncthreads();
  }
  if (t < nb) partials[t] = (t == 0) ? 0 : s[t - 1];
}

__global__ __launch_bounds__(256) void scan_apply_one(const int* __restrict__ counts, int n,
                                                      const int* __restrict__ partials,
                                                      int* __restrict__ outp) {
  int t = threadIdx.x;
  int base = blockIdx.x * 1024 + t * 4;
  int4 v = make_int4(0, 0, 0, 0);
  if (base + 3 < n) {
    v = *(const int4*)(counts + base);
  } else {
    int* pv = &v.x;
    for (int i = 0; i < 4; ++i) if (base + i < n) pv[i] = counts[base + i];
  }
  int s = v.x + v.y + v.z + v.w;
  int lane = t & 63;
  int wv = t >> 6;
  int inc = s;
  #pragma unroll
  for (int off = 1; off < 64; off <<= 1) {
    int u = __shfl_up(inc, off);
    if (lane >= off) inc += u;
  }
  __shared__ int wsum[4];
  if (lane == 63) wsum[wv] = inc;
  __syncthreads();
  int woff = 0;
  for (int i = 0; i < wv; ++i) woff += wsum[i];
  int excl = woff + (inc - s) + partials[blockIdx.x];
  int4 rp;
  rp.x = excl;
  rp.y = rp.x + v.x;
  rp.z = rp.y + v.y;
  rp.w = rp.z + v.z;
  if (base + 3 < n) {
    *(int4*)(outp + base) = rp;
  } else {
    int* pr = &rp.x;
    for (int i = 0; i < 4; ++i) if (base + i < n) outp[base + i] = pr[i];
  }
}

// ---------------- bucket scatter ----------------

__global__ __launch_bounds__(256) void bucket_scatter(const int* __restrict__ s0v, const int* __restrict__ d0,
                                                      const int* __restrict__ s1v, const int* __restrict__ d1,
                                                      const int* __restrict__ s2v, const int* __restrict__ d2,
                                                      const int* __restrict__ mscan, unsigned int* __restrict__ pairs) {
  int gid = blockIdx.x >> 8;
  int g   = blockIdx.x & 255;
  const int* src = gid == 0 ? s0v : (gid == 1 ? s1v : s2v);
  const int* dst = gid == 0 ? d0  : (gid == 1 ? d1  : d2);
  int E    = (gid == 2) ? E_UU : E_UI;
  int NB   = (gid == 0) ? NB0 : NB1;
  int boff = (gid == 0) ? 0 : (gid == 1 ? NB0 : NB0 + NB1);
  __shared__ int cur[NB0];
  for (int b = threadIdx.x; b < NB; b += 256) cur[b] = mscan[(boff + b) * 256 + g];
  __syncthreads();
  int chunk = (E + 255) >> 8;
  int lo = g * chunk, hi = min(lo + chunk, E);
  for (int i = lo + threadIdx.x; i < hi; i += 256) {
    int d = dst[i], s = src[i];
    int pos = atomicAdd(&cur[d >> 8], 1);
    pairs[pos] = ((unsigned)(d & 255) << 24) | (unsigned)s;
  }
}

// ---------------- bucket finalize ----------------

__global__ __launch_bounds__(256) void bucket_finalize(const unsigned int* __restrict__ pairs,
                                                       const int* __restrict__ mscan,
                                                       int* __restrict__ rp, int* __restrict__ col) {
  int gb = blockIdx.x;
  int t  = threadIdx.x;
  int gid  = (gb < NB0) ? 0 : (gb < NB0 + NB1 ? 1 : 2);
  int boff = (gid == 0) ? 0 : (gid == 1 ? NB0 : NB0 + NB1);
  int node_goff = (gid == 0) ? 0 : (gid == 1 ? N_ITEM : N_ITEM + N_USER);
  int n    = (gid == 0) ? N_ITEM : N_USER;
  int b_local = gb - boff;
  int bs = mscan[gb * 256];
  int be = (gb + 1 < NBTOT) ? mscan[(gb + 1) * 256] : E_TOT;

  __shared__ int cnt[256];
  __shared__ int curb[256];
  __shared__ int wsum[4];
  cnt[t] = 0;
  __syncthreads();
  for (int i = bs + t; i < be; i += 256)
    atomicAdd(&cnt[pairs[i] >> 24], 1);
  __syncthreads();

  int v = cnt[t];
  int lane = t & 63, wv = t >> 6;
  int inc = v;
  #pragma unroll
  for (int off = 1; off < 64; off <<= 1) {
    int u = __shfl_up(inc, off);
    if (lane >= off) inc += u;
  }
  if (lane == 63) wsum[wv] = inc;
  __syncthreads();
  int woff = 0;
  for (int i = 0; i < wv; ++i) woff += wsum[i];
  int base = bs + woff + (inc - v);

  int node_local = b_local * 256 + t;
  if (node_local < n) rp[node_goff + node_local] = base;
  if (gb == NBTOT - 1 && t == 255) rp[N_ITEM + 2 * N_USER] = E_TOT;
  curb[t] = base;
  __syncthreads();

  for (int i = bs + t; i < be; i += 256) {
    unsigned u = pairs[i];
    int p = atomicAdd(&curb[u >> 24], 1);
    col[p] = (int)(u & 0xFFFFFFu);
  }
}

// ---------------- GEMM building blocks ----------------
// LDS-staged X variant: X tile lives in Xs (padded stride); W staged per phase.
// x pointers point into LDS -> no cross-phase register liveness.

__device__ __forceinline__ void load_xtile(const float* __restrict__ X, float* Xs, int base, int N) {
  #pragma unroll
  for (int i = 0; i < 4; ++i) {
    int idx = threadIdx.x * 4 + i * 1024;   // linear over 64x64
    int row = idx >> 6, colc = idx & 63;
    int grow = base + row;
    const float* src = X + (size_t)(grow < N ? grow : N - 1) * 64 + colc;
    *(float4*)(Xs + row * XS_STRIDE + colc) = *(const float4*)src;
  }
}

__device__ __forceinline__ void gemm_phase(const float* __restrict__ Wsrc, float* Ws,
                                           const float* x0, const float* x1,
                                           const float* x2, const float* x3, int c4,
                                           float4& acc0, float4& acc1, float4& acc2, float4& acc3) {
  __syncthreads();
  #pragma unroll
  for (int i = 0; i < 4; ++i) {
    int idx = threadIdx.x * 4 + i * 1024;
    *(float4*)(Ws + idx) = *(const float4*)(Wsrc + idx);
  }
  __syncthreads();
  acc0 = make_float4(0.f, 0.f, 0.f, 0.f);
  acc1 = acc0; acc2 = acc0; acc3 = acc0;
  #pragma unroll
  for (int k4 = 0; k4 < 64; k4 += 4) {
    float4 xa = *(const float4*)(x0 + k4);
    float4 xb = *(const float4*)(x1 + k4);
    float4 xc = *(const float4*)(x2 + k4);
    float4 xd = *(const float4*)(x3 + k4);
    #pragma unroll
    for (int kk = 0; kk < 4; ++kk) {
      float4 w = *(const float4*)(Ws + (k4 + kk) * 64 + c4);
      float sa = (&xa.x)[kk], sb = (&xb.x)[kk], sc = (&xc.x)[kk], sd = (&xd.x)[kk];
      acc0.x = fmaf(sa, w.x, acc0.x); acc0.y = fmaf(sa, w.y, acc0.y);
      acc0.z = fmaf(sa, w.z, acc0.z); acc0.w = fmaf(sa, w.w, acc0.w);
      acc1.x = fmaf(sb, w.x, acc1.x); acc1.y = fmaf(sb, w.y, acc1.y);
      acc1.z = fmaf(sb, w.z, acc1.z); acc1.w = fmaf(sb, w.w, acc1.w);
      acc2.x = fmaf(sc, w.x, acc2.x); acc2.y = fmaf(sc, w.y, acc2.y);
      acc2.z = fmaf(sc, w.z, acc2.z); acc2.w = fmaf(sc, w.w, acc2.w);
      acc3.x = fmaf(sd, w.x, acc3.x); acc3.y = fmaf(sd, w.y, acc3.y);
      acc3.z = fmaf(sd, w.z, acc3.z); acc3.w = fmaf(sd, w.w, acc3.w);
    }
  }
}

__device__ __forceinline__ void store4_f32(float* __restrict__ Y, int r0, int r1, int r2, int r3,
                                           int N, int c4,
                                           const float4& a0, const float4& a1,
                                           const float4& a2, const float4& a3) {
  if (r0 < N) *(float4*)(Y + (size_t)r0 * 64 + c4) = a0;
  if (r1 < N) *(float4*)(Y + (size_t)r1 * 64 + c4) = a1;
  if (r2 < N) *(float4*)(Y + (size_t)r2 * 64 + c4) = a2;
  if (r3 < N) *(float4*)(Y + (size_t)r3 * 64 + c4) = a3;
}

__device__ __forceinline__ void store4_f16(__half* __restrict__ Y, int r0, int r1, int r2, int r3,
                                           int N, int c4,
                                           const float4& a0, const float4& a1,
                                           const float4& a2, const float4& a3) {
  uint2 st;
  if (r0 < N) {
    st.x = __builtin_bit_cast(unsigned int, __floats2half2_rn(a0.x, a0.y));
    st.y = __builtin_bit_cast(unsigned int, __floats2half2_rn(a0.z, a0.w));
    *(uint2*)(Y + (size_t)r0 * 64 + c4) = st;
  }
  if (r1 < N) {
    st.x = __builtin_bit_cast(unsigned int, __floats2half2_rn(a1.x, a1.y));
    st.y = __builtin_bit_cast(unsigned int, __floats2half2_rn(a1.z, a1.w));
    *(uint2*)(Y + (size_t)r1 * 64 + c4) = st;
  }
  if (r2 < N) {
    st.x = __builtin_bit_cast(unsigned int, __floats2half2_rn(a2.x, a2.y));
    st.y = __builtin_bit_cast(unsigned int, __floats2half2_rn(a2.z, a2.w));
    *(uint2*)(Y + (size_t)r2 * 64 + c4) = st;
  }
  if (r3 < N) {
    st.x = __builtin_bit_cast(unsigned int, __floats2half2_rn(a3.x, a3.y));
    st.y = __builtin_bit_cast(unsigned int, __floats2half2_rn(a3.z, a3.w));
    *(uint2*)(Y + (size_t)r3 * 64 + c4) = st;
  }
}

// h_user -> uh0(f16, W0), u1(W1), u2(W2), u3(W3): X staged in LDS once
__global__ __launch_bounds__(256) void gemm_user4(const float* __restrict__ X,
                                                  const float* __restrict__ W0, const float* __restrict__ W1,
                                                  const float* __restrict__ W2, const float* __restrict__ W3,
                                                  __half* __restrict__ Y0h, float* __restrict__ Y1,
                                                  float* __restrict__ Y2, float* __restrict__ Y3, int N) {
  __shared__ float Xs[64 * XS_STRIDE];
  __shared__ float Ws[64 * 64];
  int base = blockIdx.x * 64;
  load_xtile(X, Xs, base, N);
  int c4 = (threadIdx.x & 15) * 4;
  int rl = threadIdx.x >> 4;
  int r0 = base + rl, r1 = r0 + 16, r2 = r0 + 32, r3 = r0 + 48;
  const float* x0 = Xs + (rl +  0) * XS_STRIDE;
  const float* x1 = Xs + (rl + 16) * XS_STRIDE;
  const float* x2 = Xs + (rl + 32) * XS_STRIDE;
  const float* x3 = Xs + (rl + 48) * XS_STRIDE;
  float4 a0, a1, a2, a3;
  gemm_phase(W0, Ws, x0, x1, x2, x3, c4, a0, a1, a2, a3);
  store4_f16(Y0h, r0, r1, r2, r3, N, c4, a0, a1, a2, a3);
  gemm_phase(W1, Ws, x0, x1, x2, x3, c4, a0, a1, a2, a3);
  store4_f32(Y1, r0, r1, r2, r3, N, c4, a0, a1, a2, a3);
  gemm_phase(W2, Ws, x0, x1, x2, x3, c4, a0, a1, a2, a3);
  store4_f32(Y2, r0, r1, r2, r3, N, c4, a0, a1, a2, a3);
  gemm_phase(W3, Ws, x0, x1, x2, x3, c4, a0, a1, a2, a3);
  store4_f32(Y3, r0, r1, r2, r3, N, c4, a0, a1, a2, a3);
}

// h_item -> i0(f32, W0), ih1(f16, W1): X staged in LDS once
__global__ __launch_bounds__(256) void gemm_item2(const float* __restrict__ X,
                                                  const float* __restrict__ W0, const float* __restrict__ W1,
                                                  float* __restrict__ Y0, __half* __restrict__ Y1h, int N) {
  __shared__ float Xs[64 * XS_STRIDE];
  __shared__ float Ws[64 * 64];
  int base = blockIdx.x * 64;
  load_xtile(X, Xs, base, N);
  int c4 = (threadIdx.x & 15) * 4;
  int rl = threadIdx.x >> 4;
  int r0 = base + rl, r1 = r0 + 16, r2 = r0 + 32, r3 = r0 + 48;
  const float* x0 = Xs + (rl +  0) * XS_STRIDE;
  const float* x1 = Xs + (rl + 16) * XS_STRIDE;
  const float* x2 = Xs + (rl + 32) * XS_STRIDE;
  const float* x3 = Xs + (rl + 48) * XS_STRIDE;
  float4 a0, a1, a2, a3;
  gemm_phase(W0, Ws, x0, x1, x2, x3, c4, a0, a1, a2, a3);
  store4_f32(Y0, r0, r1, r2, r3, N, c4, a0, a1, a2, a3);
  gemm_phase(W1, Ws, x0, x1, x2, x3, c4, a0, a1, a2, a3);
  store4_f16(Y1h, r0, r1, r2, r3, N, c4, a0, a1, a2, a3);
}

// two independent f16-output GEMMs in one dispatch (block-range split; single phase, X direct)
__global__ __launch_bounds__(256) void gemm_mid2x(const float* __restrict__ XA, const float* __restrict__ WA,
                                                  __half* __restrict__ YA, int NA, int nbA,
                                                  const float* __restrict__ XB, const float* __restrict__ WB,
                                                  __half* __restrict__ YB, int NB_) {
  __shared__ float Ws[64 * 64];
  const float* X; const float* W; __half* Y; int N; int base;
  if ((int)blockIdx.x < nbA) {
    X = XA; W = WA; Y = YA; N = NA; base = blockIdx.x * 64;
  } else {
    X = XB; W = WB; Y = YB; N = NB_; base = (blockIdx.x - nbA) * 64;
  }
  int c4 = (threadIdx.x & 15) * 4;
  int rl = threadIdx.x >> 4;
  int r0 = base + rl, r1 = r0 + 16, r2 = r0 + 32, r3 = r0 + 48;
  const float* x0 = X + (size_t)(r0 < N ? r0 : N - 1) * 64;
  const float* x1 = X + (size_t)(r1 < N ? r1 : N - 1) * 64;
  const float* x2 = X + (size_t)(r2 < N ? r2 : N - 1) * 64;
  const float* x3 = X + (size_t)(r3 < N ? r3 : N - 1) * 64;
  float4 a0, a1, a2, a3;
  gemm_phase(W, Ws, x0, x1, x2, x3, c4, a0, a1, a2, a3);
  store4_f16(Y, r0, r1, r2, r3, N, c4, a0, a1, a2, a3);
}

// ---------------- fused GATv2 (two independent graphs per dispatch) ----------------

__global__ __launch_bounds__(256) void gat2x_kernel(
    const __half* __restrict__ hsA, const float* __restrict__ hdAp,
    const int* __restrict__ rpA, const float* __restrict__ attnA, const float* __restrict__ biasA,
    float* __restrict__ outA, int NdA,
    const __half* __restrict__ hsB, const float* __restrict__ hdBp,
    const int* __restrict__ rpB, const float* __restrict__ attnB, const float* __restrict__ biasB,
    float* __restrict__ outB, int NdB,
    const int* __restrict__ col) {
  int wid = (blockIdx.x * blockDim.x + threadIdx.x) >> 6;
  int lane = threadIdx.x & 63;
  int g = lane >> 4;        // edge group 0..3
  int sl = lane & 15;       // dims sl*4 .. sl*4+3
  const __half* hs; const float* hd; const int* rp;
  const float* attn; const float* bias; float* outp; int node;
  if (wid < NdA) {
    hs = hsA; hd = hdAp; rp = rpA; attn = attnA; bias = biasA; outp = outA; node = wid;
  } else {
    if (wid >= NdA + NdB) return;
    hs = hsB; hd = hdBp; rp = rpB; attn = attnB; bias = biasB; outp = outB; node = wid - NdA;
  }
  int s0 = rp[node], s1 = rp[node + 1];

  float4 hdf = *(const float4*)(hd + (size_t)node * 64 + sl * 4);
  float4 af  = *(const float4*)(attn + sl * 4);
  __half2 hd2a = __floats2half2_rn(hdf.x, hdf.y);
  __half2 hd2b = __floats2half2_rn(hdf.z, hdf.w);
  __half2 a2a = __floats2half2_rn(af.x, af.y);
  __half2 a2b = __floats2half2_rn(af.z, af.w);
  const __half2 C02 = __floats2half2_rn(NEG_SLOPE, NEG_SLOPE);
  const __half2 Z   = __floats2half2_rn(0.f, 0.f);

  float m = -1e30f, den = 0.f;
  float n0 = 0.f, n1 = 0.f, n2 = 0.f, n3 = 0.f;

  for (int e = s0 + g; e < s1; e += 8) {
    int eb = e + 4;
    bool has2 = eb < s1;
    int sa = col[e];
    int sb = col[has2 ? eb : e];
    uint2 ra = *(const uint2*)(hs + (size_t)sa * 64 + sl * 4);
    uint2 rb = *(const uint2*)(hs + (size_t)sb * 64 + sl * 4);
    __half2 vaA = __builtin_bit_cast(__half2, ra.x);
    __half2 vaB = __builtin_bit_cast(__half2, ra.y);
    __half2 vbA = __builtin_bit_cast(__half2, rb.x);
    __half2 vbB = __builtin_bit_cast(__half2, rb.y);
    __half2 xaA = __hadd2(vaA, hd2a), xaB = __hadd2(vaB, hd2b);
    __half2 xbA = __hadd2(vbA, hd2a), xbB = __hadd2(vbB, hd2b);
    __half2 laA = __hfma2(C02, h2min(xaA, Z), h2max(xaA, Z));
    __half2 laB = __hfma2(C02, h2min(xaB, Z), h2max(xaB, Z));
    __half2 lbA = __hfma2(C02, h2min(xbA, Z), h2max(xbA, Z));
    __half2 lbB = __hfma2(C02, h2min(xbB, Z), h2max(xbB, Z));
    float ta = fdot2acc(a2a, laA, 0.f); ta = fdot2acc(a2b, laB, ta);
    float tb = fdot2acc(a2a, lbA, 0.f); tb = fdot2acc(a2b, lbB, tb);
    #pragma unroll
    for (int off = 1; off < 16; off <<= 1) {
      ta += __shfl_xor(ta, off);
      tb += __shfl_xor(tb, off);
    }
    if (!has2) tb = -1e30f;
    float tp = fmaxf(ta, tb);
    float d = tp - m;
    if (d > 8.f) {
      float sc = __expf(-d);
      den *= sc; n0 *= sc; n1 *= sc; n2 *= sc; n3 *= sc;
      m = tp;
    }
    float pa = __expf(ta - m);
    float pb = __expf(tb - m);
    den += pa + pb;
    float2 fa0 = __half22float2(vaA), fa1 = __half22float2(vaB);
    float2 fb0 = __half22float2(vbA), fb1 = __half22float2(vbB);
    n0 = fmaf(pa, fa0.x, fmaf(pb, fb0.x, n0));
    n1 = fmaf(pa, fa0.y, fmaf(pb, fb0.y, n1));
    n2 = fmaf(pa, fa1.x, fmaf(pb, fb1.x, n2));
    n3 = fmaf(pa, fa1.y, fmaf(pb, fb1.y, n3));
  }

  #pragma unroll
  for (int off = 16; off <= 32; off <<= 1) {
    float m2  = __shfl_xor(m, off);
    float den2 = __shfl_xor(den, off);
    float q0 = __shfl_xor(n0, off);
    float q1 = __shfl_xor(n1, off);
    float q2 = __shfl_xor(n2, off);
    float q3 = __shfl_xor(n3, off);
    float mn = fmaxf(m, m2);
    float sA = (m == mn) ? 1.f : __expf(m - mn);
    float sB = (m2 == mn) ? 1.f : __expf(m2 - mn);
    den = den * sA + den2 * sB;
    n0 = n0 * sA + q0 * sB;
    n1 = n1 * sA + q1 * sB;
    n2 = n2 * sA + q2 * sB;
    n3 = n3 * sA + q3 * sB;
    m = mn;
  }

  if (g == 0) {
    float inv = 1.f / fmaxf(den, 1e-9f);
    float4 b4 = *(const float4*)(bias + sl * 4);
    float4 o;
    o.x = fmaf(n0, inv, b4.x);
    o.y = fmaf(n1, inv, b4.y);
    o.z = fmaf(n2, inv, b4.z);
    o.w = fmaf(n3, inv, b4.w);
    *(float4*)(outp + (size_t)node * 64 + sl * 4) = o;
  }
}

// ---------------- final: out = [A|B] @ Wout + bout ----------------

__global__ __launch_bounds__(256) void final_kernel(const float* __restrict__ A, const float* __restrict__ B,
                                                    const float* __restrict__ W, const float* __restrict__ bias,
                                                    float* __restrict__ Y, int N) {
  __shared__ float Ws[128 * 64];
  #pragma unroll
  for (int i = 0; i < 8; ++i) {
    int idx = threadIdx.x * 4 + i * 1024;
    *(float4*)(Ws + idx) = *(const float4*)(W + idx);
  }
  __syncthreads();
  int c4 = (threadIdx.x & 15) * 4;
  int rl = threadIdx.x >> 4;
  int base = blockIdx.x * 64;

  float4 b4 = *(const float4*)(bias + c4);

  #pragma unroll
  for (int rr = 0; rr < 4; ++rr) {
    int row = base + rr * 16 + rl;
    if (row >= N) continue;
    const float* ar = A + (size_t)row * 64;
    const float* br = B + (size_t)row * 64;
    float4 acc = b4;
    #pragma unroll
    for (int k4 = 0; k4 < 64; k4 += 4) {
      float4 xa = *(const float4*)(ar + k4);
      float4 xb = *(const float4*)(br + k4);
      #pragma unroll
      for (int kk = 0; kk < 4; ++kk) {
        float4 wa = *(const float4*)(Ws + (k4 + kk) * 64 + c4);
        float4 wb = *(const float4*)(Ws + (64 + k4 + kk) * 64 + c4);
        float xsa = (&xa.x)[kk], xsb = (&xb.x)[kk];
        acc.x = fmaf(xsa, wa.x, acc.x); acc.x = fmaf(xsb, wb.x, acc.x);
        acc.y = fmaf(xsa, wa.y, acc.y); acc.y = fmaf(xsb, wb.y, acc.y);
        acc.z = fmaf(xsa, wa.z, acc.z); acc.z = fmaf(xsb, wb.z, acc.z);
        acc.w = fmaf(xsa, wa.w, acc.w); acc.w = fmaf(xsb, wb.w, acc.w);
      }
    }
    *(float4*)(Y + (size_t)row * 64 + c4) = acc;
  }
}

// ---------------- launch ----------------

extern "C" void kernel_launch(void* const* d_in, const int* in_sizes, int n_in,
                              void* d_out, int out_size, void* d_ws, size_t ws_size,
                              hipStream_t stream) {
  const float* h_user   = (const float*)d_in[0];
  const float* h_item   = (const float*)d_in[1];
  const int* rate_src   = (const int*)d_in[2];
  const int* rate_dst   = (const int*)d_in[3];
  const int* rb_src     = (const int*)d_in[4];
  const int* rb_dst     = (const int*)d_in[5];
  const int* link_src   = (const int*)d_in[6];
  const int* link_dst   = (const int*)d_in[7];
  const float* w_src_r1  = (const float*)d_in[8];
  const float* w_dst_r1  = (const float*)d_in[9];
  const float* a_r1      = (const float*)d_in[10];
  const float* b_r1      = (const float*)d_in[11];
  const float* w_src_rb1 = (const float*)d_in[12];
  const float* w_dst_rb1 = (const float*)d_in[13];
  const float* a_rb1     = (const float*)d_in[14];
  const float* b_rb1     = (const float*)d_in[15];
  const float* w_src_rb2 = (const float*)d_in[16];
  const float* w_dst_rb2 = (const float*)d_in[17];
  const float* a_rb2     = (const float*)d_in[18];
  const float* b_rb2     = (const float*)d_in[19];
  const float* w_src_l2  = (const float*)d_in[20];
  const float* w_dst_l2  = (const float*)d_in[21];
  const float* a_l2      = (const float*)d_in[22];
  const float* b_l2      = (const float*)d_in[23];
  const float* w_out     = (const float*)d_in[24];
  const float* b_out     = (const float*)d_in[25];
  float* out = (float*)d_out;

  char* ws = (char*)d_ws;
  size_t off = 0;
  auto alloc = [&](size_t bytes) -> void* {
    void* p = ws + off;
    off += (bytes + 255) & ~(size_t)255;
    return p;
  };

  float* u1 = (float*)alloc((size_t)N_USER * 64 * 4);
  float* u2 = (float*)alloc((size_t)N_USER * 64 * 4);
  float* u3 = (float*)alloc((size_t)N_USER * 64 * 4);
  float* i0 = (float*)alloc((size_t)N_ITEM * 64 * 4);
  __half* uh0 = (__half*)alloc((size_t)N_USER * 64 * 2);
  __half* ih1 = (__half*)alloc((size_t)N_ITEM * 64 * 2);

  int* mat     = (int*)alloc((size_t)MATN * 4);
  int* mscan   = (int*)alloc((size_t)MATN * 4);
  int* partials= (int*)alloc(256 * 4);
  int* grp     = (int*)alloc((size_t)(N_ITEM + 2 * N_USER + 1) * 4);
  unsigned int* pairs = (unsigned int*)alloc((size_t)E_TOT * 4);
  int* col_all = (int*)alloc((size_t)E_TOT * 4);

  // ---- bucketed CSR build ----
  bucket_hist<<<3 * GPB, 256, 0, stream>>>(rate_dst, rb_dst, link_dst, mat);
  {
    int nb = (MATN + 1023) / 1024;
    partial_kernel<<<nb, 256, 0, stream>>>(mat, MATN, partials);
    scan_partials256<<<1, 256, 0, stream>>>(partials, nb);
    scan_apply_one<<<nb, 256, 0, stream>>>(mat, MATN, partials, mscan);
  }
  bucket_scatter<<<3 * GPB, 256, 0, stream>>>(rate_src, rate_dst, rb_src, rb_dst,
                                              link_src, link_dst, mscan, pairs);
  bucket_finalize<<<NBTOT, 256, 0, stream>>>(pairs, mscan, grp, col_all);

  int* rp_rate = grp;
  int* rp_rb   = grp + N_ITEM;
  int* rp_link = grp + N_ITEM + N_USER;

  // ---- fused node GEMMs (X staged in LDS) ----
  gemm_user4<<<(N_USER + 63) / 64, 256, 0, stream>>>(
      h_user, w_src_r1, w_dst_rb1, w_dst_rb2, w_dst_l2, uh0, u1, u2, u3, N_USER);
  gemm_item2<<<(N_ITEM + 63) / 64, 256, 0, stream>>>(
      h_item, w_dst_r1, w_src_rb1, i0, ih1, N_ITEM);

  // ---- layer1: rate (user->item) || rated-by (item->user), fused ----
  {
    int waves = N_ITEM + N_USER;
    gat2x_kernel<<<(waves + 3) / 4, 256, 0, stream>>>(
        uh0, i0, rp_rate, a_r1,  b_r1,  i0, N_ITEM,
        ih1, u1, rp_rb,   a_rb1, b_rb1, u1, N_USER,
        col_all);
  }

  // ---- layer2 src transforms (fused pair) ----
  {
    int nbA = (N_ITEM + 63) / 64;
    int nbB = (N_USER + 63) / 64;
    gemm_mid2x<<<nbA + nbB, 256, 0, stream>>>(
        i0, w_src_rb2, ih1, N_ITEM, nbA,
        u1, w_src_l2,  uh0, N_USER);
  }

  // ---- layer2: rated-by (item->user) || link (user->user), fused ----
  {
    int waves = N_USER + N_USER;
    gat2x_kernel<<<(waves + 3) / 4, 256, 0, stream>>>(
        ih1, u2, rp_rb,   a_rb2, b_rb2, u2, N_USER,
        uh0, u3, rp_link, a_l2,  b_l2,  u3, N_USER,
        col_all);
  }

  // ---- output projection ----
  final_kernel<<<(N_USER + 63) / 64, 256, 0, stream>>>(u2, u3, w_out, b_out, out, N_USER);
}

// Round 10
// 414.028 us; speedup vs baseline: 3.9959x; 1.0582x over previous
//
#include <hip/hip_runtime.h>
#include <hip/hip_fp16.h>
#include <math.h>

#define N_USER 50000
#define N_ITEM 100000
#define E_UI   1000000
#define E_UU   800000
#define E_TOT  (E_UI + E_UI + E_UU)
#define NEG_SLOPE 0.2f

#define NB0 391
#define NB1 196
#define NB2 196
#define NBTOT (NB0 + NB1 + NB2)   // 783
#define GPB 256
#define MATN (NBTOT * 256)        // 200448
#define NBP  ((MATN + 1023) / 1024)  // 196 partials

#define XS_STRIDE 68

typedef _Float16 h2v __attribute__((ext_vector_type(2)));

#if defined(__has_builtin)
#if __has_builtin(__builtin_amdgcn_fdot2)
#define HAS_FDOT2 1
#endif
#if __has_builtin(__builtin_elementwise_max)
#define HAS_EW_MAX 1
#endif
#endif

__device__ __forceinline__ float fdot2acc(__half2 a, __half2 b, float c) {
#ifdef HAS_FDOT2
  return __builtin_amdgcn_fdot2(__builtin_bit_cast(h2v, a), __builtin_bit_cast(h2v, b), c, false);
#else
  float2 af = __half22float2(a), bf = __half22float2(b);
  return fmaf(af.x, bf.x, fmaf(af.y, bf.y, c));
#endif
}

__device__ __forceinline__ __half2 h2max(__half2 a, __half2 b) {
  h2v av = __builtin_bit_cast(h2v, a), bv = __builtin_bit_cast(h2v, b);
#ifdef HAS_EW_MAX
  h2v r = __builtin_elementwise_max(av, bv);
#else
  h2v r; r.x = av.x > bv.x ? av.x : bv.x; r.y = av.y > bv.y ? av.y : bv.y;
#endif
  return __builtin_bit_cast(__half2, r);
}

__device__ __forceinline__ __half2 h2min(__half2 a, __half2 b) {
  h2v av = __builtin_bit_cast(h2v, a), bv = __builtin_bit_cast(h2v, b);
#ifdef HAS_EW_MAX
  h2v r = __builtin_elementwise_min(av, bv);
#else
  h2v r; r.x = av.x < bv.x ? av.x : bv.x; r.y = av.y < bv.y ? av.y : bv.y;
#endif
  return __builtin_bit_cast(__half2, r);
}

// ---------------- bucket histogram ----------------

__global__ __launch_bounds__(256) void bucket_hist(const int* __restrict__ d0, const int* __restrict__ d1,
                                                   const int* __restrict__ d2, int* __restrict__ mat) {
  int gid = blockIdx.x >> 8;
  int g   = blockIdx.x & 255;
  const int* dst = gid == 0 ? d0 : (gid == 1 ? d1 : d2);
  int E    = (gid == 2) ? E_UU : E_UI;
  int NB   = (gid == 0) ? NB0 : NB1;
  int boff = (gid == 0) ? 0 : (gid == 1 ? NB0 : NB0 + NB1);
  __shared__ int cnt[NB0];
  for (int b = threadIdx.x; b < NB; b += 256) cnt[b] = 0;
  __syncthreads();
  int chunk = (E + 255) >> 8;
  int lo = g * chunk, hi = min(lo + chunk, E);
  for (int i = lo + threadIdx.x; i < hi; i += 256)
    atomicAdd(&cnt[dst[i] >> 8], 1);
  __syncthreads();
  for (int b = threadIdx.x; b < NB; b += 256)
    mat[(boff + b) * 256 + g] = cnt[b];
}

// ---------------- scan: partials, then fused apply (scans partials redundantly per block) ----------------

__global__ __launch_bounds__(256) void partial_kernel(const int* __restrict__ counts, int n,
                                                      int* __restrict__ partials) {
  int t = threadIdx.x;
  int base = blockIdx.x * 1024 + t * 4;
  int s = 0;
  if (base + 3 < n) {
    int4 v = *(const int4*)(counts + base);
    s = v.x + v.y + v.z + v.w;
  } else {
    for (int i = base; i < n && i < base + 4; ++i) s += counts[i];
  }
  #pragma unroll
  for (int off = 1; off < 64; off <<= 1) s += __shfl_xor(s, off);
  __shared__ int ws[4];
  if ((t & 63) == 0) ws[t >> 6] = s;
  __syncthreads();
  if (t == 0) partials[blockIdx.x] = ws[0] + ws[1] + ws[2] + ws[3];
}

__global__ __launch_bounds__(256) void scan_apply_fused(const int* __restrict__ counts, int n,
                                                        const int* __restrict__ partials, int nbp,
                                                        int* __restrict__ outp) {
  __shared__ int sp[256];
  int t = threadIdx.x;
  sp[t] = (t < nbp) ? partials[t] : 0;
  __syncthreads();
  for (int off = 1; off < 256; off <<= 1) {
    int v = (t >= off) ? sp[t - off] : 0;
    __syncthreads();
    sp[t] += v;
    __syncthreads();
  }
  int block_off = (blockIdx.x == 0) ? 0 : sp[blockIdx.x - 1];

  int base = blockIdx.x * 1024 + t * 4;
  int4 v = make_int4(0, 0, 0, 0);
  if (base + 3 < n) {
    v = *(const int4*)(counts + base);
  } else {
    int* pv = &v.x;
    for (int i = 0; i < 4; ++i) if (base + i < n) pv[i] = counts[base + i];
  }
  int s = v.x + v.y + v.z + v.w;
  int lane = t & 63;
  int wv = t >> 6;
  int inc = s;
  #pragma unroll
  for (int off = 1; off < 64; off <<= 1) {
    int u = __shfl_up(inc, off);
    if (lane >= off) inc += u;
  }
  __shared__ int wsum[4];
  if (lane == 63) wsum[wv] = inc;
  __syncthreads();
  int woff = 0;
  for (int i = 0; i < wv; ++i) woff += wsum[i];
  int excl = woff + (inc - s) + block_off;
  int4 rp;
  rp.x = excl;
  rp.y = rp.x + v.x;
  rp.z = rp.y + v.y;
  rp.w = rp.z + v.z;
  if (base + 3 < n) {
    *(int4*)(outp + base) = rp;
  } else {
    int* pr = &rp.x;
    for (int i = 0; i < 4; ++i) if (base + i < n) outp[base + i] = pr[i];
  }
}

// ---------------- bucket scatter ----------------

__global__ __launch_bounds__(256) void bucket_scatter(const int* __restrict__ s0v, const int* __restrict__ d0,
                                                      const int* __restrict__ s1v, const int* __restrict__ d1,
                                                      const int* __restrict__ s2v, const int* __restrict__ d2,
                                                      const int* __restrict__ mscan, unsigned int* __restrict__ pairs) {
  int gid = blockIdx.x >> 8;
  int g   = blockIdx.x & 255;
  const int* src = gid == 0 ? s0v : (gid == 1 ? s1v : s2v);
  const int* dst = gid == 0 ? d0  : (gid == 1 ? d1  : d2);
  int E    = (gid == 2) ? E_UU : E_UI;
  int NB   = (gid == 0) ? NB0 : NB1;
  int boff = (gid == 0) ? 0 : (gid == 1 ? NB0 : NB0 + NB1);
  __shared__ int cur[NB0];
  for (int b = threadIdx.x; b < NB; b += 256) cur[b] = mscan[(boff + b) * 256 + g];
  __syncthreads();
  int chunk = (E + 255) >> 8;
  int lo = g * chunk, hi = min(lo + chunk, E);
  for (int i = lo + threadIdx.x; i < hi; i += 256) {
    int d = dst[i], s = src[i];
    int pos = atomicAdd(&cur[d >> 8], 1);
    pairs[pos] = ((unsigned)(d & 255) << 24) | (unsigned)s;
  }
}

// ---------------- bucket finalize ----------------

__global__ __launch_bounds__(256) void bucket_finalize(const unsigned int* __restrict__ pairs,
                                                       const int* __restrict__ mscan,
                                                       int* __restrict__ rp, int* __restrict__ col) {
  int gb = blockIdx.x;
  int t  = threadIdx.x;
  int gid  = (gb < NB0) ? 0 : (gb < NB0 + NB1 ? 1 : 2);
  int boff = (gid == 0) ? 0 : (gid == 1 ? NB0 : NB0 + NB1);
  int node_goff = (gid == 0) ? 0 : (gid == 1 ? N_ITEM : N_ITEM + N_USER);
  int n    = (gid == 0) ? N_ITEM : N_USER;
  int b_local = gb - boff;
  int bs = mscan[gb * 256];
  int be = (gb + 1 < NBTOT) ? mscan[(gb + 1) * 256] : E_TOT;

  __shared__ int cnt[256];
  __shared__ int curb[256];
  __shared__ int wsum[4];
  cnt[t] = 0;
  __syncthreads();
  for (int i = bs + t; i < be; i += 256)
    atomicAdd(&cnt[pairs[i] >> 24], 1);
  __syncthreads();

  int v = cnt[t];
  int lane = t & 63, wv = t >> 6;
  int inc = v;
  #pragma unroll
  for (int off = 1; off < 64; off <<= 1) {
    int u = __shfl_up(inc, off);
    if (lane >= off) inc += u;
  }
  if (lane == 63) wsum[wv] = inc;
  __syncthreads();
  int woff = 0;
  for (int i = 0; i < wv; ++i) woff += wsum[i];
  int base = bs + woff + (inc - v);

  int node_local = b_local * 256 + t;
  if (node_local < n) rp[node_goff + node_local] = base;
  if (gb == NBTOT - 1 && t == 255) rp[N_ITEM + 2 * N_USER] = E_TOT;
  curb[t] = base;
  __syncthreads();

  for (int i = bs + t; i < be; i += 256) {
    unsigned u = pairs[i];
    int p = atomicAdd(&curb[u >> 24], 1);
    col[p] = (int)(u & 0xFFFFFFu);
  }
}

// ---------------- GEMM building blocks (LDS-staged X) ----------------

__device__ __forceinline__ void load_xtile(const float* __restrict__ X, float* Xs, int base, int N) {
  #pragma unroll
  for (int i = 0; i < 4; ++i) {
    int idx = threadIdx.x * 4 + i * 1024;
    int row = idx >> 6, colc = idx & 63;
    int grow = base + row;
    const float* src = X + (size_t)(grow < N ? grow : N - 1) * 64 + colc;
    *(float4*)(Xs + row * XS_STRIDE + colc) = *(const float4*)src;
  }
}

__device__ __forceinline__ void gemm_phase(const float* __restrict__ Wsrc, float* Ws,
                                           const float* x0, const float* x1,
                                           const float* x2, const float* x3, int c4,
                                           float4& acc0, float4& acc1, float4& acc2, float4& acc3) {
  __syncthreads();
  #pragma unroll
  for (int i = 0; i < 4; ++i) {
    int idx = threadIdx.x * 4 + i * 1024;
    *(float4*)(Ws + idx) = *(const float4*)(Wsrc + idx);
  }
  __syncthreads();
  acc0 = make_float4(0.f, 0.f, 0.f, 0.f);
  acc1 = acc0; acc2 = acc0; acc3 = acc0;
  #pragma unroll
  for (int k4 = 0; k4 < 64; k4 += 4) {
    float4 xa = *(const float4*)(x0 + k4);
    float4 xb = *(const float4*)(x1 + k4);
    float4 xc = *(const float4*)(x2 + k4);
    float4 xd = *(const float4*)(x3 + k4);
    #pragma unroll
    for (int kk = 0; kk < 4; ++kk) {
      float4 w = *(const float4*)(Ws + (k4 + kk) * 64 + c4);
      float sa = (&xa.x)[kk], sb = (&xb.x)[kk], sc = (&xc.x)[kk], sd = (&xd.x)[kk];
      acc0.x = fmaf(sa, w.x, acc0.x); acc0.y = fmaf(sa, w.y, acc0.y);
      acc0.z = fmaf(sa, w.z, acc0.z); acc0.w = fmaf(sa, w.w, acc0.w);
      acc1.x = fmaf(sb, w.x, acc1.x); acc1.y = fmaf(sb, w.y, acc1.y);
      acc1.z = fmaf(sb, w.z, acc1.z); acc1.w = fmaf(sb, w.w, acc1.w);
      acc2.x = fmaf(sc, w.x, acc2.x); acc2.y = fmaf(sc, w.y, acc2.y);
      acc2.z = fmaf(sc, w.z, acc2.z); acc2.w = fmaf(sc, w.w, acc2.w);
      acc3.x = fmaf(sd, w.x, acc3.x); acc3.y = fmaf(sd, w.y, acc3.y);
      acc3.z = fmaf(sd, w.z, acc3.z); acc3.w = fmaf(sd, w.w, acc3.w);
    }
  }
}

__device__ __forceinline__ void store4_f32(float* __restrict__ Y, int r0, int r1, int r2, int r3,
                                           int N, int c4,
                                           const float4& a0, const float4& a1,
                                           const float4& a2, const float4& a3) {
  if (r0 < N) *(float4*)(Y + (size_t)r0 * 64 + c4) = a0;
  if (r1 < N) *(float4*)(Y + (size_t)r1 * 64 + c4) = a1;
  if (r2 < N) *(float4*)(Y + (size_t)r2 * 64 + c4) = a2;
  if (r3 < N) *(float4*)(Y + (size_t)r3 * 64 + c4) = a3;
}

__device__ __forceinline__ void store4_f16(__half* __restrict__ Y, int r0, int r1, int r2, int r3,
                                           int N, int c4,
                                           const float4& a0, const float4& a1,
                                           const float4& a2, const float4& a3) {
  uint2 st;
  if (r0 < N) {
    st.x = __builtin_bit_cast(unsigned int, __floats2half2_rn(a0.x, a0.y));
    st.y = __builtin_bit_cast(unsigned int, __floats2half2_rn(a0.z, a0.w));
    *(uint2*)(Y + (size_t)r0 * 64 + c4) = st;
  }
  if (r1 < N) {
    st.x = __builtin_bit_cast(unsigned int, __floats2half2_rn(a1.x, a1.y));
    st.y = __builtin_bit_cast(unsigned int, __floats2half2_rn(a1.z, a1.w));
    *(uint2*)(Y + (size_t)r1 * 64 + c4) = st;
  }
  if (r2 < N) {
    st.x = __builtin_bit_cast(unsigned int, __floats2half2_rn(a2.x, a2.y));
    st.y = __builtin_bit_cast(unsigned int, __floats2half2_rn(a2.z, a2.w));
    *(uint2*)(Y + (size_t)r2 * 64 + c4) = st;
  }
  if (r3 < N) {
    st.x = __builtin_bit_cast(unsigned int, __floats2half2_rn(a3.x, a3.y));
    st.y = __builtin_bit_cast(unsigned int, __floats2half2_rn(a3.z, a3.w));
    *(uint2*)(Y + (size_t)r3 * 64 + c4) = st;
  }
}

// unified user4 + item2 GEMM (block-range split)
__global__ __launch_bounds__(256) void gemm_nodes(
    const float* __restrict__ Xu,
    const float* __restrict__ Wu0, const float* __restrict__ Wu1,
    const float* __restrict__ Wu2, const float* __restrict__ Wu3,
    __half* __restrict__ Yu0h, float* __restrict__ Yu1,
    float* __restrict__ Yu2, float* __restrict__ Yu3, int NU, int nbU,
    const float* __restrict__ Xi,
    const float* __restrict__ Wi0, const float* __restrict__ Wi1,
    float* __restrict__ Yi0, __half* __restrict__ Yi1h, int NI) {
  __shared__ float Xs[64 * XS_STRIDE];
  __shared__ float Ws[64 * 64];
  int c4 = (threadIdx.x & 15) * 4;
  int rl = threadIdx.x >> 4;
  if ((int)blockIdx.x < nbU) {
    int base = blockIdx.x * 64;
    load_xtile(Xu, Xs, base, NU);
    int r0 = base + rl, r1 = r0 + 16, r2 = r0 + 32, r3 = r0 + 48;
    const float* x0 = Xs + (rl +  0) * XS_STRIDE;
    const float* x1 = Xs + (rl + 16) * XS_STRIDE;
    const float* x2 = Xs + (rl + 32) * XS_STRIDE;
    const float* x3 = Xs + (rl + 48) * XS_STRIDE;
    float4 a0, a1, a2, a3;
    gemm_phase(Wu0, Ws, x0, x1, x2, x3, c4, a0, a1, a2, a3);
    store4_f16(Yu0h, r0, r1, r2, r3, NU, c4, a0, a1, a2, a3);
    gemm_phase(Wu1, Ws, x0, x1, x2, x3, c4, a0, a1, a2, a3);
    store4_f32(Yu1, r0, r1, r2, r3, NU, c4, a0, a1, a2, a3);
    gemm_phase(Wu2, Ws, x0, x1, x2, x3, c4, a0, a1, a2, a3);
    store4_f32(Yu2, r0, r1, r2, r3, NU, c4, a0, a1, a2, a3);
    gemm_phase(Wu3, Ws, x0, x1, x2, x3, c4, a0, a1, a2, a3);
    store4_f32(Yu3, r0, r1, r2, r3, NU, c4, a0, a1, a2, a3);
  } else {
    int base = (blockIdx.x - nbU) * 64;
    load_xtile(Xi, Xs, base, NI);
    int r0 = base + rl, r1 = r0 + 16, r2 = r0 + 32, r3 = r0 + 48;
    const float* x0 = Xs + (rl +  0) * XS_STRIDE;
    const float* x1 = Xs + (rl + 16) * XS_STRIDE;
    const float* x2 = Xs + (rl + 32) * XS_STRIDE;
    const float* x3 = Xs + (rl + 48) * XS_STRIDE;
    float4 a0, a1, a2, a3;
    gemm_phase(Wi0, Ws, x0, x1, x2, x3, c4, a0, a1, a2, a3);
    store4_f32(Yi0, r0, r1, r2, r3, NI, c4, a0, a1, a2, a3);
    gemm_phase(Wi1, Ws, x0, x1, x2, x3, c4, a0, a1, a2, a3);
    store4_f16(Yi1h, r0, r1, r2, r3, NI, c4, a0, a1, a2, a3);
  }
}

// two independent f16-output GEMMs in one dispatch (single phase, X direct)
__global__ __launch_bounds__(256) void gemm_mid2x(const float* __restrict__ XA, const float* __restrict__ WA,
                                                  __half* __restrict__ YA, int NA, int nbA,
                                                  const float* __restrict__ XB, const float* __restrict__ WB,
                                                  __half* __restrict__ YB, int NB_) {
  __shared__ float Ws[64 * 64];
  const float* X; const float* W; __half* Y; int N; int base;
  if ((int)blockIdx.x < nbA) {
    X = XA; W = WA; Y = YA; N = NA; base = blockIdx.x * 64;
  } else {
    X = XB; W = WB; Y = YB; N = NB_; base = (blockIdx.x - nbA) * 64;
  }
  int c4 = (threadIdx.x & 15) * 4;
  int rl = threadIdx.x >> 4;
  int r0 = base + rl, r1 = r0 + 16, r2 = r0 + 32, r3 = r0 + 48;
  const float* x0 = X + (size_t)(r0 < N ? r0 : N - 1) * 64;
  const float* x1 = X + (size_t)(r1 < N ? r1 : N - 1) * 64;
  const float* x2 = X + (size_t)(r2 < N ? r2 : N - 1) * 64;
  const float* x3 = X + (size_t)(r3 < N ? r3 : N - 1) * 64;
  float4 a0, a1, a2, a3;
  gemm_phase(W, Ws, x0, x1, x2, x3, c4, a0, a1, a2, a3);
  store4_f16(Y, r0, r1, r2, r3, N, c4, a0, a1, a2, a3);
}

// ---------------- fused GATv2 v2: 4x16 lanes, 4 edges/group/iter, paired-fdot2 PV ----------------

__global__ __launch_bounds__(256) void gat2x_kernel(
    const __half* __restrict__ hsA, const float* __restrict__ hdAp,
    const int* __restrict__ rpA, const float* __restrict__ attnA, const float* __restrict__ biasA,
    float* __restrict__ outA, int NdA,
    const __half* __restrict__ hsB, const float* __restrict__ hdBp,
    const int* __restrict__ rpB, const float* __restrict__ attnB, const float* __restrict__ biasB,
    float* __restrict__ outB, int NdB,
    const int* __restrict__ col) {
  int wid = (blockIdx.x * blockDim.x + threadIdx.x) >> 6;
  int lane = threadIdx.x & 63;
  int g = lane >> 4;        // edge group 0..3
  int sl = lane & 15;       // dims sl*4 .. sl*4+3
  const __half* hs; const float* hd; const int* rp;
  const float* attn; const float* bias; float* outp; int node;
  if (wid < NdA) {
    hs = hsA; hd = hdAp; rp = rpA; attn = attnA; bias = biasA; outp = outA; node = wid;
  } else {
    if (wid >= NdA + NdB) return;
    hs = hsB; hd = hdBp; rp = rpB; attn = attnB; bias = biasB; outp = outB; node = wid - NdA;
  }
  int s0 = rp[node], s1 = rp[node + 1];

  float4 hdf = *(const float4*)(hd + (size_t)node * 64 + sl * 4);
  float4 af  = *(const float4*)(attn + sl * 4);
  __half2 hd2a = __floats2half2_rn(hdf.x, hdf.y);
  __half2 hd2b = __floats2half2_rn(hdf.z, hdf.w);
  __half2 a2a = __floats2half2_rn(af.x, af.y);
  __half2 a2b = __floats2half2_rn(af.z, af.w);
  const __half2 C02 = __floats2half2_rn(NEG_SLOPE, NEG_SLOPE);
  const __half2 Z   = __floats2half2_rn(0.f, 0.f);

  float m = -1e30f, den = 0.f;
  float n0 = 0.f, n1 = 0.f, n2 = 0.f, n3 = 0.f;

  for (int e = s0 + g; e < s1; e += 16) {
    int e1 = e + 4, e2 = e + 8, e3 = e + 12;
    bool h1 = e1 < s1, h2c = e2 < s1, h3 = e3 < s1;
    int sa = col[e];
    int sb = col[h1 ? e1 : e];
    int sc = col[h2c ? e2 : e];
    int sd = col[h3 ? e3 : e];
    uint2 ra = *(const uint2*)(hs + (size_t)sa * 64 + sl * 4);
    uint2 rb = *(const uint2*)(hs + (size_t)sb * 64 + sl * 4);
    uint2 rc = *(const uint2*)(hs + (size_t)sc * 64 + sl * 4);
    uint2 rd = *(const uint2*)(hs + (size_t)sd * 64 + sl * 4);

    // scores (4 independent chains)
    __half2 xa0 = __hadd2(__builtin_bit_cast(__half2, ra.x), hd2a);
    __half2 xa1 = __hadd2(__builtin_bit_cast(__half2, ra.y), hd2b);
    __half2 xb0 = __hadd2(__builtin_bit_cast(__half2, rb.x), hd2a);
    __half2 xb1 = __hadd2(__builtin_bit_cast(__half2, rb.y), hd2b);
    __half2 xc0 = __hadd2(__builtin_bit_cast(__half2, rc.x), hd2a);
    __half2 xc1 = __hadd2(__builtin_bit_cast(__half2, rc.y), hd2b);
    __half2 xd0 = __hadd2(__builtin_bit_cast(__half2, rd.x), hd2a);
    __half2 xd1 = __hadd2(__builtin_bit_cast(__half2, rd.y), hd2b);
    __half2 la0 = __hfma2(C02, h2min(xa0, Z), h2max(xa0, Z));
    __half2 la1 = __hfma2(C02, h2min(xa1, Z), h2max(xa1, Z));
    __half2 lb0 = __hfma2(C02, h2min(xb0, Z), h2max(xb0, Z));
    __half2 lb1 = __hfma2(C02, h2min(xb1, Z), h2max(xb1, Z));
    __half2 lc0 = __hfma2(C02, h2min(xc0, Z), h2max(xc0, Z));
    __half2 lc1 = __hfma2(C02, h2min(xc1, Z), h2max(xc1, Z));
    __half2 ld0 = __hfma2(C02, h2min(xd0, Z), h2max(xd0, Z));
    __half2 ld1 = __hfma2(C02, h2min(xd1, Z), h2max(xd1, Z));
    float ta = fdot2acc(a2b, la1, fdot2acc(a2a, la0, 0.f));
    float tb = fdot2acc(a2b, lb1, fdot2acc(a2a, lb0, 0.f));
    float tc = fdot2acc(a2b, lc1, fdot2acc(a2a, lc0, 0.f));
    float td = fdot2acc(a2b, ld1, fdot2acc(a2a, ld0, 0.f));
    #pragma unroll
    for (int off = 1; off < 16; off <<= 1) {
      ta += __shfl_xor(ta, off);
      tb += __shfl_xor(tb, off);
      tc += __shfl_xor(tc, off);
      td += __shfl_xor(td, off);
    }
    if (!h1)  tb = -1e30f;
    if (!h2c) tc = -1e30f;
    if (!h3)  td = -1e30f;

    float tp = fmaxf(fmaxf(ta, tb), fmaxf(tc, td));
    float dd = tp - m;
    if (dd > 8.f) {
      float sc0 = __expf(-dd);
      den *= sc0; n0 *= sc0; n1 *= sc0; n2 *= sc0; n3 *= sc0;
      m = tp;
    }
    float pa = __expf(ta - m);
    float pb = __expf(tb - m);
    float pc = __expf(tc - m);
    float pd = __expf(td - m);
    den += (pa + pb) + (pc + pd);
    __half2 pab = __floats2half2_rn(pa, pb);
    __half2 pcd = __floats2half2_rn(pc, pd);

    // pair transposes: half2(edgeX.dim_k, edgeY.dim_k)
    unsigned lo_ab_x = (ra.x & 0xFFFFu) | (rb.x << 16);
    unsigned hi_ab_x = (ra.x >> 16) | (rb.x & 0xFFFF0000u);
    unsigned lo_ab_y = (ra.y & 0xFFFFu) | (rb.y << 16);
    unsigned hi_ab_y = (ra.y >> 16) | (rb.y & 0xFFFF0000u);
    unsigned lo_cd_x = (rc.x & 0xFFFFu) | (rd.x << 16);
    unsigned hi_cd_x = (rc.x >> 16) | (rd.x & 0xFFFF0000u);
    unsigned lo_cd_y = (rc.y & 0xFFFFu) | (rd.y << 16);
    unsigned hi_cd_y = (rc.y >> 16) | (rd.y & 0xFFFF0000u);

    n0 = fdot2acc(pcd, __builtin_bit_cast(__half2, lo_cd_x),
         fdot2acc(pab, __builtin_bit_cast(__half2, lo_ab_x), n0));
    n1 = fdot2acc(pcd, __builtin_bit_cast(__half2, hi_cd_x),
         fdot2acc(pab, __builtin_bit_cast(__half2, hi_ab_x), n1));
    n2 = fdot2acc(pcd, __builtin_bit_cast(__half2, lo_cd_y),
         fdot2acc(pab, __builtin_bit_cast(__half2, lo_ab_y), n2));
    n3 = fdot2acc(pcd, __builtin_bit_cast(__half2, hi_cd_y),
         fdot2acc(pab, __builtin_bit_cast(__half2, hi_ab_y), n3));
  }

  // merge 4 groups (flash-combine with equality guards)
  #pragma unroll
  for (int off = 16; off <= 32; off <<= 1) {
    float m2  = __shfl_xor(m, off);
    float den2 = __shfl_xor(den, off);
    float q0 = __shfl_xor(n0, off);
    float q1 = __shfl_xor(n1, off);
    float q2 = __shfl_xor(n2, off);
    float q3 = __shfl_xor(n3, off);
    float mn = fmaxf(m, m2);
    float sA = (m == mn) ? 1.f : __expf(m - mn);
    float sB = (m2 == mn) ? 1.f : __expf(m2 - mn);
    den = den * sA + den2 * sB;
    n0 = n0 * sA + q0 * sB;
    n1 = n1 * sA + q1 * sB;
    n2 = n2 * sA + q2 * sB;
    n3 = n3 * sA + q3 * sB;
    m = mn;
  }

  if (g == 0) {
    float inv = 1.f / fmaxf(den, 1e-9f);
    float4 b4 = *(const float4*)(bias + sl * 4);
    float4 o;
    o.x = fmaf(n0, inv, b4.x);
    o.y = fmaf(n1, inv, b4.y);
    o.z = fmaf(n2, inv, b4.z);
    o.w = fmaf(n3, inv, b4.w);
    *(float4*)(outp + (size_t)node * 64 + sl * 4) = o;
  }
}

// ---------------- final: out = [A|B] @ Wout + bout ----------------

__global__ __launch_bounds__(256) void final_kernel(const float* __restrict__ A, const float* __restrict__ B,
                                                    const float* __restrict__ W, const float* __restrict__ bias,
                                                    float* __restrict__ Y, int N) {
  __shared__ float Ws[128 * 64];
  #pragma unroll
  for (int i = 0; i < 8; ++i) {
    int idx = threadIdx.x * 4 + i * 1024;
    *(float4*)(Ws + idx) = *(const float4*)(W + idx);
  }
  __syncthreads();
  int c4 = (threadIdx.x & 15) * 4;
  int rl = threadIdx.x >> 4;
  int base = blockIdx.x * 64;

  float4 b4 = *(const float4*)(bias + c4);

  #pragma unroll
  for (int rr = 0; rr < 4; ++rr) {
    int row = base + rr * 16 + rl;
    if (row >= N) continue;
    const float* ar = A + (size_t)row * 64;
    const float* br = B + (size_t)row * 64;
    float4 acc = b4;
    #pragma unroll
    for (int k4 = 0; k4 < 64; k4 += 4) {
      float4 xa = *(const float4*)(ar + k4);
      float4 xb = *(const float4*)(br + k4);
      #pragma unroll
      for (int kk = 0; kk < 4; ++kk) {
        float4 wa = *(const float4*)(Ws + (k4 + kk) * 64 + c4);
        float4 wb = *(const float4*)(Ws + (64 + k4 + kk) * 64 + c4);
        float xsa = (&xa.x)[kk], xsb = (&xb.x)[kk];
        acc.x = fmaf(xsa, wa.x, acc.x); acc.x = fmaf(xsb, wb.x, acc.x);
        acc.y = fmaf(xsa, wa.y, acc.y); acc.y = fmaf(xsb, wb.y, acc.y);
        acc.z = fmaf(xsa, wa.z, acc.z); acc.z = fmaf(xsb, wb.z, acc.z);
        acc.w = fmaf(xsa, wa.w, acc.w); acc.w = fmaf(xsb, wb.w, acc.w);
      }
    }
    *(float4*)(Y + (size_t)row * 64 + c4) = acc;
  }
}

// ---------------- launch ----------------

extern "C" void kernel_launch(void* const* d_in, const int* in_sizes, int n_in,
                              void* d_out, int out_size, void* d_ws, size_t ws_size,
                              hipStream_t stream) {
  const float* h_user   = (const float*)d_in[0];
  const float* h_item   = (const float*)d_in[1];
  const int* rate_src   = (const int*)d_in[2];
  const int* rate_dst   = (const int*)d_in[3];
  const int* rb_src     = (const int*)d_in[4];
  const int* rb_dst     = (const int*)d_in[5];
  const int* link_src   = (const int*)d_in[6];
  const int* link_dst   = (const int*)d_in[7];
  const float* w_src_r1  = (const float*)d_in[8];
  const float* w_dst_r1  = (const float*)d_in[9];
  const float* a_r1      = (const float*)d_in[10];
  const float* b_r1      = (const float*)d_in[11];
  const float* w_src_rb1 = (const float*)d_in[12];
  const float* w_dst_rb1 = (const float*)d_in[13];
  const float* a_rb1     = (const float*)d_in[14];
  const float* b_rb1     = (const float*)d_in[15];
  const float* w_src_rb2 = (const float*)d_in[16];
  const float* w_dst_rb2 = (const float*)d_in[17];
  const float* a_rb2     = (const float*)d_in[18];
  const float* b_rb2     = (const float*)d_in[19];
  const float* w_src_l2  = (const float*)d_in[20];
  const float* w_dst_l2  = (const float*)d_in[21];
  const float* a_l2      = (const float*)d_in[22];
  const float* b_l2      = (const float*)d_in[23];
  const float* w_out     = (const float*)d_in[24];
  const float* b_out     = (const float*)d_in[25];
  float* out = (float*)d_out;

  char* ws = (char*)d_ws;
  size_t off = 0;
  auto alloc = [&](size_t bytes) -> void* {
    void* p = ws + off;
    off += (bytes + 255) & ~(size_t)255;
    return p;
  };

  float* u1 = (float*)alloc((size_t)N_USER * 64 * 4);
  float* u2 = (float*)alloc((size_t)N_USER * 64 * 4);
  float* u3 = (float*)alloc((size_t)N_USER * 64 * 4);
  float* i0 = (float*)alloc((size_t)N_ITEM * 64 * 4);
  __half* uh0 = (__half*)alloc((size_t)N_USER * 64 * 2);
  __half* ih1 = (__half*)alloc((size_t)N_ITEM * 64 * 2);

  int* mat     = (int*)alloc((size_t)MATN * 4);
  int* mscan   = (int*)alloc((size_t)MATN * 4);
  int* partials= (int*)alloc(256 * 4);
  int* grp     = (int*)alloc((size_t)(N_ITEM + 2 * N_USER + 1) * 4);
  unsigned int* pairs = (unsigned int*)alloc((size_t)E_TOT * 4);
  int* col_all = (int*)alloc((size_t)E_TOT * 4);

  // ---- bucketed CSR build ----
  bucket_hist<<<3 * GPB, 256, 0, stream>>>(rate_dst, rb_dst, link_dst, mat);
  partial_kernel<<<NBP, 256, 0, stream>>>(mat, MATN, partials);
  scan_apply_fused<<<NBP, 256, 0, stream>>>(mat, MATN, partials, NBP, mscan);
  bucket_scatter<<<3 * GPB, 256, 0, stream>>>(rate_src, rate_dst, rb_src, rb_dst,
                                              link_src, link_dst, mscan, pairs);
  bucket_finalize<<<NBTOT, 256, 0, stream>>>(pairs, mscan, grp, col_all);

  int* rp_rate = grp;
  int* rp_rb   = grp + N_ITEM;
  int* rp_link = grp + N_ITEM + N_USER;

  // ---- fused node GEMMs (one dispatch) ----
  {
    int nbU = (N_USER + 63) / 64;
    int nbI = (N_ITEM + 63) / 64;
    gemm_nodes<<<nbU + nbI, 256, 0, stream>>>(
        h_user, w_src_r1, w_dst_rb1, w_dst_rb2, w_dst_l2, uh0, u1, u2, u3, N_USER, nbU,
        h_item, w_dst_r1, w_src_rb1, i0, ih1, N_ITEM);
  }

  // ---- layer1: rate (user->item) || rated-by (item->user), fused ----
  {
    int waves = N_ITEM + N_USER;
    gat2x_kernel<<<(waves + 3) / 4, 256, 0, stream>>>(
        uh0, i0, rp_rate, a_r1,  b_r1,  i0, N_ITEM,
        ih1, u1, rp_rb,   a_rb1, b_rb1, u1, N_USER,
        col_all);
  }

  // ---- layer2 src transforms (fused pair) ----
  {
    int nbA = (N_ITEM + 63) / 64;
    int nbB = (N_USER + 63) / 64;
    gemm_mid2x<<<nbA + nbB, 256, 0, stream>>>(
        i0, w_src_rb2, ih1, N_ITEM, nbA,
        u1, w_src_l2,  uh0, N_USER);
  }

  // ---- layer2: rated-by (item->user) || link (user->user), fused ----
  {
    int waves = N_USER + N_USER;
    gat2x_kernel<<<(waves + 3) / 4, 256, 0, stream>>>(
        ih1, u2, rp_rb,   a_rb2, b_rb2, u2, N_USER,
        uh0, u3, rp_link, a_l2,  b_l2,  u3, N_USER,
        col_all);
  }

  // ---- output projection ----
  final_kernel<<<(N_USER + 63) / 64, 256, 0, stream>>>(u2, u3, w_out, b_out, out, N_USER);
}